// Round 9
// baseline (617.380 us; speedup 1.0000x reference)
//
#include <hip/hip_runtime.h>
#include <math.h>

#define B_   4
#define T_   2048
#define D_   512
#define TOK  (B_*T_)      // 8192 tokens
#define TL_  2045         // N_BLOCKS*(T//N_BLOCKS) = 5*409
#define GATE 0.2f         // softmax(...).mean(-1) over same axis == 1/5
#define QSCALE 0.18033688011112043f   // 0.125 * log2(e): S in log2 domain
#define MSPLIT 4096

typedef unsigned short u16;
typedef __attribute__((ext_vector_type(8))) short short8;   // 8 bf16 = 4 VGPRs
typedef __attribute__((ext_vector_type(4))) float f32x4;

static __device__ __forceinline__ u16 f2u(float f){      // fp32 -> bf16 (RNE)
    union { float f; unsigned u; } a; a.f = f;
    unsigned r = a.u + 0x7fffu + ((a.u >> 16) & 1u);
    return (u16)(r >> 16);
}
static __device__ __forceinline__ u16 f2u_t(float f){    // truncating (P >= 0)
    return (u16)(__float_as_uint(f) >> 16);
}
static __device__ __forceinline__ float u2f(u16 u){
    union { unsigned u; float f; } a; a.u = ((unsigned)u) << 16;
    return a.f;
}
static __device__ __forceinline__ f32x4 mfma16(short8 a, short8 b, f32x4 c){
    return __builtin_amdgcn_mfma_f32_16x16x32_bf16(a, b, c, 0, 0, 0);
}
static __device__ __forceinline__ void glds16(const u16* g, u16* l){
    __builtin_amdgcn_global_load_lds((const __attribute__((address_space(1))) void*)g,
                                     (__attribute__((address_space(3))) void*)l, 16, 0, 0);
}
// fast GELU (tanh form): hw v_exp_f32 + v_rcp_f32 (no precise-divide sequence).
static __device__ __forceinline__ float fgelu(float x){
    float u = x * (1.f + 0.044715f * x * x);
    return x * __builtin_amdgcn_rcpf(1.f + exp2f(-2.3021193f * u));
}
static __device__ __forceinline__ float fsigm(float x){  // sigmoid via rcp
    return __builtin_amdgcn_rcpf(1.f + __expf(-x));
}

// ------------------------------------------------------------------
// gate + pool fused: XFcat[:,0:512]=bf16(0.2*x masked), XFcat[:,512:]=bf16(pool)
__global__ __launch_bounds__(256) void gatepool_kernel(
    const float* __restrict__ x, u16* __restrict__ xfcat)
{
    int idx = blockIdx.x*256 + threadIdx.x;
    int d = idx & 511, g = idx >> 9;
    int b = g >> 7, t0 = (g & 127) << 4;
    const float* xp = x + ((size_t)b*2048)*512 + d;
    float v[30];
    #pragma unroll
    for (int j = 0; j < 30; ++j){
        int u = t0 - 7 + j;
        v[j] = (u >= 0 && u < TL_) ? xp[(size_t)u*512] : 0.f;
    }
    float p[31]; p[0] = 0.f;
    #pragma unroll
    for (int j = 0; j < 30; ++j) p[j+1] = p[j] + v[j];
    u16* xc = xfcat + ((size_t)(b*2048 + t0))*1024 + d;
    #pragma unroll
    for (int i = 0; i < 16; ++i){
        int t = t0 + i;
        float sum = p[i+15] - p[i];                 // u in [t-7, t+7]
        int lo = t-7; if (lo < 0) lo = 0;
        int hi = t+7; if (hi > 2047) hi = 2047;
        xc[(size_t)i*1024]       = f2u((t < TL_) ? GATE*v[i+7] : 0.f);
        xc[(size_t)i*1024 + 512] = f2u(GATE * sum / (float)(hi - lo + 1));
    }
}

// ------------------------------------------------------------------
// batched transpose+convert: src fp32 [K,N] -> dst[n*ldout+coloff+k]=bf16(scale*src)
struct TJob { const float* src; u16* dst; int K, N, ldout, coloff, tiles; float scale; };
struct TJobs { TJob j[13]; int n; };

__global__ __launch_bounds__(256) void tconv_all_kernel(TJobs JJ){
    __shared__ float t[32][33];
    int idx = blockIdx.x;
    int jb = 0;
    while (jb < JJ.n - 1 && idx >= JJ.j[jb].tiles){ idx -= JJ.j[jb].tiles; ++jb; }
    TJob J = JJ.j[jb];
    int tX = J.N >> 5;
    int k0 = (idx / tX) * 32, n0 = (idx % tX) * 32;
    int tx = threadIdx.x & 31, ty = threadIdx.x >> 5;
    #pragma unroll
    for (int i = 0; i < 32; i += 8)
        t[ty+i][tx] = J.src[(size_t)(k0+ty+i)*J.N + n0+tx];
    __syncthreads();
    #pragma unroll
    for (int i = 0; i < 32; i += 8)
        J.dst[(size_t)(n0+ty+i)*J.ldout + J.coloff + k0+tx] = f2u(J.scale * t[tx][ty+i]);
}

// fp32 -> bf16 plain convert
__global__ void convert_kernel(const float* __restrict__ in, u16* __restrict__ out){
    int idx = blockIdx.x*256 + threadIdx.x;
    out[idx] = f2u(in[idx]);
}

// fubias[n] = fu_b[n] + sum_d mp_b[d] * fu_w[512+d][n]
__global__ __launch_bounds__(256) void biasfold_kernel(
    const float* __restrict__ fu_b, const float* __restrict__ mp_b,
    const float* __restrict__ fu_w, float* __restrict__ out)
{
    int n = blockIdx.x, tid = threadIdx.x;
    float s = mp_b[tid]*fu_w[(size_t)(512+tid)*512 + n]
            + mp_b[tid+256]*fu_w[(size_t)(768+tid)*512 + n];
    for (int off = 32; off; off >>= 1) s += __shfl_down(s, off);
    __shared__ float ws[4];
    if ((tid & 63) == 0) ws[tid >> 6] = s;
    __syncthreads();
    if (tid == 0) out[n] = fu_b[n] + ws[0]+ws[1]+ws[2]+ws[3];
}

// qkvbias[n] = sum_d fubias[d] * wqkvT[n][d]
__global__ __launch_bounds__(256) void qkvbias_kernel(
    const float* __restrict__ fubias, const u16* __restrict__ wqkvT,
    float* __restrict__ out)
{
    int n = blockIdx.x, tid = threadIdx.x;
    const u16* wp = wqkvT + (size_t)n*512;
    float s = fubias[tid]*u2f(wp[tid]) + fubias[tid+256]*u2f(wp[tid+256]);
    for (int off = 32; off; off >>= 1) s += __shfl_down(s, off);
    __shared__ float ws[4];
    if ((tid & 63) == 0) ws[tid >> 6] = s;
    __syncthreads();
    if (tid == 0) out[n] = ws[0]+ws[1]+ws[2]+ws[3];
}

// small fp32 GEMM, N=512, writes bf16 TRANSPOSED: dstT[n*512 + m] = (A@B)[m][n]
__global__ __launch_bounds__(256) void sgemm_kernel(const float* __restrict__ A,
    const float* __restrict__ B, u16* __restrict__ dstT, int K){
    __shared__ float As[16][65];
    __shared__ float Bs[16][65];
    int tid = threadIdx.x;
    int tx = tid & 15, ty = tid >> 4;
    int m0 = blockIdx.y*64, n0 = blockIdx.x*64;
    int arow = tid >> 2, akq = (tid & 3) * 4;
    int bk = tid >> 4, bn = (tid & 15) * 4;
    float acc[4][4] = {};
    for (int k0 = 0; k0 < K; k0 += 16){
        const float* Ap = A + (size_t)(m0+arow)*K + k0 + akq;
        As[akq+0][arow]=Ap[0]; As[akq+1][arow]=Ap[1];
        As[akq+2][arow]=Ap[2]; As[akq+3][arow]=Ap[3];
        const float* Bp = B + (size_t)(k0+bk)*512 + n0 + bn;
        Bs[bk][bn+0]=Bp[0]; Bs[bk][bn+1]=Bp[1];
        Bs[bk][bn+2]=Bp[2]; Bs[bk][bn+3]=Bp[3];
        __syncthreads();
        #pragma unroll
        for (int kk = 0; kk < 16; ++kk){
            float av[4], bv[4];
            #pragma unroll
            for (int i=0;i<4;++i) av[i]=As[kk][ty*4+i];
            #pragma unroll
            for (int j=0;j<4;++j) bv[j]=Bs[kk][tx*4+j];
            #pragma unroll
            for (int i=0;i<4;++i)
                #pragma unroll
                for (int j=0;j<4;++j) acc[i][j] += av[i]*bv[j];
        }
        __syncthreads();
    }
    #pragma unroll
    for (int i=0;i<4;++i)
        #pragma unroll
        for (int j=0;j<4;++j)
            dstT[(size_t)(n0+tx*4+j)*512 + m0+ty*4+i] = f2u(acc[i][j]);
}

// ------------------------------------------------------------------
// bf16 MFMA GEMM: legacy 2-barrier structure (small-workspace fallback only)
#define GF_GELU   1
#define GF_ACCUM  2
#define GF_RSCOL  4
#define GF_GLU    8
#define GF_F32OUT 16
#define GF_QKV    32

template<int MT>
__global__ __launch_bounds__(256) void mgemm_kernel(
    const u16* __restrict__ A, const u16* __restrict__ A2, int lda,
    const u16* __restrict__ Bt, int ldb,
    const float* __restrict__ bias, const float* __restrict__ rs,
    const u16* __restrict__ glu, void* __restrict__ Cp, void* __restrict__ CpB,
    int ldc, u16* __restrict__ Cp2, int K, int flags)
{
    constexpr int MI = MT/32;            // m-tiles per wave (16 rows each)
    __shared__ u16 As[MT*64];
    __shared__ u16 Bs[128*64];
    int tid = threadIdx.x;
    int wave = tid >> 6, lane = tid & 63;
    int n16 = lane & 15, quad = lane >> 4;
    int m0 = blockIdx.y * MT, n0 = blockIdx.x * 128;
    int wr = (wave >> 1) * (MT/2), wc = (wave & 1) * 64;

    f32x4 acc[MI][4] = {};

    for (int k0 = 0; k0 < K; k0 += 64){
        #pragma unroll
        for (int i = 0; i < MT/32; ++i){
            int s = i*256 + tid;
            int row = s >> 3, g = (s & 7) ^ (row & 7);
            int rg = m0 + row;
            const u16* Ap = (rg < MSPLIT) ? A + (size_t)rg*lda
                                          : A2 + (size_t)(rg - MSPLIT)*lda;
            glds16(Ap + k0 + g*8, As + (size_t)s*8);
        }
        #pragma unroll
        for (int i = 0; i < 4; ++i){
            int s = i*256 + tid;
            int row = s >> 3, g = (s & 7) ^ (row & 7);
            glds16(Bt + (size_t)(n0+row)*ldb + k0 + g*8, Bs + (size_t)s*8);
        }
        __syncthreads();
        #pragma unroll
        for (int ks = 0; ks < 2; ++ks){
            short8 af[MI], bf[4];
            #pragma unroll
            for (int mi = 0; mi < MI; ++mi){
                int row = wr + mi*16 + n16;
                int g = (ks*4 + quad) ^ (row & 7);
                af[mi] = *(const short8*)&As[row*64 + g*8];
            }
            #pragma unroll
            for (int ni = 0; ni < 4; ++ni){
                int row = wc + ni*16 + n16;
                int g = (ks*4 + quad) ^ (row & 7);
                bf[ni] = *(const short8*)&Bs[row*64 + g*8];
            }
            #pragma unroll
            for (int mi = 0; mi < MI; ++mi)
                #pragma unroll
                for (int ni = 0; ni < 4; ++ni)
                    acc[mi][ni] = mfma16(af[mi], bf[ni], acc[mi][ni]);
        }
        __syncthreads();
    }

    if ((flags & GF_QKV) && n0 >= 1024){
        #pragma unroll
        for (int mi = 0; mi < MI; ++mi){
            int row0 = m0 + wr + mi*16 + quad*4;
            #pragma unroll
            for (int ni = 0; ni < 4; ++ni){
                int col = n0 + wc + ni*16 + n16;
                float bb = bias[col];
                ushort4 h4;
                h4.x = f2u(acc[mi][ni][0] + bb); h4.y = f2u(acc[mi][ni][1] + bb);
                h4.z = f2u(acc[mi][ni][2] + bb); h4.w = f2u(acc[mi][ni][3] + bb);
                *(ushort4*)&Cp2[(size_t)(col-1024)*8192 + row0] = h4;
            }
        }
        return;
    }

    #pragma unroll
    for (int mi = 0; mi < MI; ++mi){
        #pragma unroll
        for (int reg = 0; reg < 4; ++reg){
            int row = m0 + wr + mi*16 + quad*4 + reg;
            void*  cb = (row < MSPLIT) ? Cp : CpB;
            size_t rr = (row < MSPLIT) ? row : row - MSPLIT;
            #pragma unroll
            for (int ni = 0; ni < 4; ++ni){
                int col = n0 + wc + ni*16 + n16;
                float v = acc[mi][ni][reg];
                if (bias) v += bias[col];
                if (flags & GF_GELU)  v = fgelu(v);
                if (flags & GF_GLU)   v = u2f(glu[(size_t)row*512 + col]) * fsigm(v);
                if (flags & GF_RSCOL) v *= rs[(size_t)row*4 + (col >> 10)];
                size_t ci = rr*ldc + col;
                if (flags & GF_ACCUM)       ((float*)cb)[ci] += v;
                else if (flags & GF_F32OUT) ((float*)cb)[ci]  = v;
                else                        ((u16*)cb)[ci]    = f2u(v);
            }
        }
    }
}

// ------------------------------------------------------------------
// 256x256-tile pipelined bf16 GEMM, counted-vmcnt (T3+T4) + XCD swizzle (T1).
// Round-9: BK=32 -> 64 KiB dbuf LDS -> 2 blocks/CU co-resident (4 waves/SIMD);
// same tile so arithmetic intensity / FETCH unchanged.  LDS packs two 32-elem
// K-rows per 64-u16 row, swizzle g = quad ^ (rr&3) (conflict-free: each
// 8-lane service group covers all 32 banks once).
// EPI=0: bias+fgelu+rscol -> bf16 C (w1).
template<int EPI>
__global__ __launch_bounds__(512, 4) void gemm256_kernel(
    const u16* __restrict__ A, int lda,
    const u16* __restrict__ Bt, int ldb,
    const float* __restrict__ bias, const float* __restrict__ rs,
    u16* __restrict__ C, int ldc, u16* __restrict__ C2, int K)
{
    __shared__ u16 As[2][256*32];
    __shared__ u16 Bs[2][256*32];
    int tid = threadIdx.x;
    int wave = tid >> 6, lane = tid & 63;
    int n16 = lane & 15, quad = lane >> 4;
    int D = blockIdx.y * gridDim.x + blockIdx.x;
    int nwg = gridDim.x * gridDim.y;
    int T = (D & 7) * (nwg >> 3) + (D >> 3);
    int m0 = (T / gridDim.x) * 256, n0 = (T % gridDim.x) * 256;
    int wm = wave >> 2, wn = wave & 3;        // 2 x 4 wave grid, wave tile 128x64

    f32x4 acc[8][4] = {};

    // staging: s = i*512+tid indexes LDS flat; rr = s>>3 selects the 64-u16
    // LDS row (holds A-tile rows 2rr, 2rr+1), gg = s&7 the 8-u16 group.
    // group gg -> tile row 2rr + (gg>>2), k-group (gg&3)^(rr&3) (inverse swz).
    const u16* ga[2]; const u16* gb[2]; int sa[2];
    #pragma unroll
    for (int i = 0; i < 2; ++i){
        int s = i*512 + tid;
        int rr = s >> 3, gg = s & 7;
        int h = gg >> 2, gw = (gg & 3) ^ (rr & 3);
        ga[i] = A  + (size_t)(m0 + 2*rr + h)*lda + gw*8;
        gb[i] = Bt + (size_t)(n0 + 2*rr + h)*ldb + gw*8;
        sa[i] = s*8;
    }
    auto stage = [&](int slot, int k0){       // 4 glds16 per thread
        #pragma unroll
        for (int i = 0; i < 2; ++i) glds16(ga[i] + k0, &As[slot][sa[i]]);
        #pragma unroll
        for (int i = 0; i < 2; ++i) glds16(gb[i] + k0, &Bs[slot][sa[i]]);
    };

    // read offsets: tile row R lives at LDS row R>>1, half (R&1)*32;
    // lane's k-group is quad, stored at position quad^(rr&3).
    int aoff[8], boff[4];
    #pragma unroll
    for (int mi = 0; mi < 8; ++mi){
        int R = wm*128 + mi*16 + n16, rr = R >> 1;
        aoff[mi] = rr*64 + (R & 1)*32 + ((quad ^ (rr & 3))*8);
    }
    #pragma unroll
    for (int ni = 0; ni < 4; ++ni){
        int R = wn*64 + ni*16 + n16, rr = R >> 1;
        boff[ni] = rr*64 + (R & 1)*32 + ((quad ^ (rr & 3))*8);
    }

    stage(0, 0);
    int NT = K >> 5;
    for (int t = 0; t < NT; ++t){
        int cur = t & 1;
        if (t + 1 < NT){
            stage(cur ^ 1, (t+1)*32);                       // prefetch next tile
            asm volatile("s_waitcnt vmcnt(4)" ::: "memory");// previous batch only
        } else {
            asm volatile("s_waitcnt vmcnt(0)" ::: "memory");
        }
        __builtin_amdgcn_s_barrier();                       // slot cur complete for all
        __builtin_amdgcn_s_setprio(1);
        short8 af[8], bf[4];
        #pragma unroll
        for (int mi = 0; mi < 8; ++mi)
            af[mi] = *(const short8*)&As[cur][aoff[mi]];
        #pragma unroll
        for (int ni = 0; ni < 4; ++ni)
            bf[ni] = *(const short8*)&Bs[cur][boff[ni]];
        #pragma unroll
        for (int mi = 0; mi < 8; ++mi)
            #pragma unroll
            for (int ni = 0; ni < 4; ++ni)
                acc[mi][ni] = mfma16(af[mi], bf[ni], acc[mi][ni]);
        __builtin_amdgcn_s_setprio(0);
        asm volatile("s_waitcnt lgkmcnt(0)" ::: "memory");  // ds_reads of cur done
        __builtin_amdgcn_s_barrier();                       // safe to overwrite cur
    }

    float bb[4];
    #pragma unroll
    for (int ni = 0; ni < 4; ++ni)
        bb[ni] = bias ? bias[n0 + wn*64 + ni*16 + n16] : 0.f;

    int e = n0 >> 10;   // expert id (EPI=0); tile never crosses a 1024 boundary
    #pragma unroll
    for (int mi = 0; mi < 8; ++mi){
        #pragma unroll
        for (int reg = 0; reg < 4; ++reg){
            int row = m0 + wm*128 + mi*16 + quad*4 + reg;
            float rv = (EPI == 0) ? rs[(size_t)row*4 + e] : 0.f;
            #pragma unroll
            for (int ni = 0; ni < 4; ++ni){
                int col = n0 + wn*64 + ni*16 + n16;
                float v = acc[mi][ni][reg] + bb[ni];
                if (EPI == 0){
                    v = fgelu(v) * rv;
                }
                C[(size_t)row*ldc + col] = f2u(v);
            }
        }
    }
}

// ------------------------------------------------------------------
// 128x128-tile pipelined bf16 GEMM, counted-vmcnt + XCD swizzle, hoisted addrs.
// EPI=0: (+bias) bf16 (prepass / generic).
// EPI=1: QKV (n0<1024: bias bf16 -> C; n0>=1024: bias + transpose -> C2).
template<int EPI>
__global__ __launch_bounds__(256, 2) void g128_kernel(
    const u16* __restrict__ A, int lda,
    const u16* __restrict__ Bt, int ldb,
    const float* __restrict__ bias, const float* __restrict__ rs,
    u16* __restrict__ C, int ldc, u16* __restrict__ C2, int K)
{
    __shared__ u16 As[2][128*64];
    __shared__ u16 Bs[2][128*64];
    int tid = threadIdx.x;
    int wave = tid >> 6, lane = tid & 63;
    int n16 = lane & 15, quad = lane >> 4;
    int D = blockIdx.y * gridDim.x + blockIdx.x;
    int nwg = gridDim.x * gridDim.y;
    int T = (nwg % 8 == 0) ? ((D & 7) * (nwg >> 3) + (D >> 3)) : D;
    int m0 = (T / gridDim.x) * 128, n0 = (T % gridDim.x) * 128;
    int wm = wave >> 1, wn = wave & 1;

    f32x4 acc[4][4] = {};

    const u16* ga[4]; const u16* gb[4]; int sa[4];
    #pragma unroll
    for (int i = 0; i < 4; ++i){
        int s = i*256 + tid;
        int row = s >> 3, g = (s & 7) ^ (row & 7);
        ga[i] = A  + (size_t)(m0+row)*lda + g*8;
        gb[i] = Bt + (size_t)(n0+row)*ldb + g*8;
        sa[i] = s*8;
    }
    auto stage = [&](int slot, int k0){       // 8 glds16 per thread
        #pragma unroll
        for (int i = 0; i < 4; ++i) glds16(ga[i] + k0, &As[slot][sa[i]]);
        #pragma unroll
        for (int i = 0; i < 4; ++i) glds16(gb[i] + k0, &Bs[slot][sa[i]]);
    };

    int aoff[2][4], boff[2][4];
    #pragma unroll
    for (int ks = 0; ks < 2; ++ks){
        #pragma unroll
        for (int mi = 0; mi < 4; ++mi){
            int row = wm*64 + mi*16 + n16;
            aoff[ks][mi] = row*64 + (((ks*4 + quad) ^ (row & 7))*8);
        }
        #pragma unroll
        for (int ni = 0; ni < 4; ++ni){
            int row = wn*64 + ni*16 + n16;
            boff[ks][ni] = row*64 + (((ks*4 + quad) ^ (row & 7))*8);
        }
    }

    stage(0, 0);
    int NT = K >> 6;
    for (int t = 0; t < NT; ++t){
        int cur = t & 1;
        if (t + 1 < NT){
            stage(cur ^ 1, (t+1)*64);                       // prefetch next tile
            asm volatile("s_waitcnt vmcnt(8)" ::: "memory");// previous batch only
        } else {
            asm volatile("s_waitcnt vmcnt(0)" ::: "memory");
        }
        __builtin_amdgcn_s_barrier();
        __builtin_amdgcn_s_setprio(1);
        #pragma unroll
        for (int ks = 0; ks < 2; ++ks){
            short8 af[4], bf[4];
            #pragma unroll
            for (int mi = 0; mi < 4; ++mi)
                af[mi] = *(const short8*)&As[cur][aoff[ks][mi]];
            #pragma unroll
            for (int ni = 0; ni < 4; ++ni)
                bf[ni] = *(const short8*)&Bs[cur][boff[ks][ni]];
            #pragma unroll
            for (int mi = 0; mi < 4; ++mi)
                #pragma unroll
                for (int ni = 0; ni < 4; ++ni)
                    acc[mi][ni] = mfma16(af[mi], bf[ni], acc[mi][ni]);
        }
        __builtin_amdgcn_s_setprio(0);
        asm volatile("s_waitcnt lgkmcnt(0)" ::: "memory");
        __builtin_amdgcn_s_barrier();
    }

    if (EPI == 1 && n0 >= 1024){
        #pragma unroll
        for (int mi = 0; mi < 4; ++mi){
            int row0 = m0 + wm*64 + mi*16 + quad*4;
            #pragma unroll
            for (int ni = 0; ni < 4; ++ni){
                int col = n0 + wn*64 + ni*16 + n16;
                float bb = bias[col];
                ushort4 h4;
                h4.x = f2u(acc[mi][ni][0] + bb); h4.y = f2u(acc[mi][ni][1] + bb);
                h4.z = f2u(acc[mi][ni][2] + bb); h4.w = f2u(acc[mi][ni][3] + bb);
                *(ushort4*)&C2[(size_t)(col-1024)*8192 + row0] = h4;
            }
        }
        return;
    }

    float bb[4];
    #pragma unroll
    for (int ni = 0; ni < 4; ++ni)
        bb[ni] = bias ? bias[n0 + wn*64 + ni*16 + n16] : 0.f;

    #pragma unroll
    for (int mi = 0; mi < 4; ++mi){
        #pragma unroll
        for (int reg = 0; reg < 4; ++reg){
            int row = m0 + wm*64 + mi*16 + quad*4 + reg;
            #pragma unroll
            for (int ni = 0; ni < 4; ++ni){
                int col = n0 + wn*64 + ni*16 + n16;
                float v = acc[mi][ni][reg] + bb[ni];
                C[(size_t)row*ldc + col] = f2u(v);
            }
        }
    }
}

// ------------------------------------------------------------------
// 64x128-tile pipelined bf16 GEMM, counted-vmcnt + XCD swizzle, hoisted addrs.
// EPI=0: plain bf16 out (wo).  EPI=1: bias+GLU -> bf16 (wg).  EPI=2: fp32 (w2).
template<int EPI>
__global__ __launch_bounds__(256, 2) void gemm64p_kernel(
    const u16* __restrict__ A, int lda,
    const u16* __restrict__ Bt, int ldb,
    const float* __restrict__ bias, const u16* __restrict__ glu,
    void* __restrict__ C, int ldc, int K)
{
    __shared__ u16 As[2][64*64];
    __shared__ u16 Bs[2][128*64];
    int tid = threadIdx.x;
    int wave = tid >> 6, lane = tid & 63;
    int n16 = lane & 15, quad = lane >> 4;
    int D = blockIdx.y * gridDim.x + blockIdx.x;
    int nwg = gridDim.x * gridDim.y;
    int T = (D & 7) * (nwg >> 3) + (D >> 3);
    int m0 = (T / gridDim.x) * 64, n0 = (T % gridDim.x) * 128;
    int wm = wave >> 1, wn = wave & 1;

    f32x4 acc[2][4] = {};

    const u16* ga[2]; const u16* gb[4]; int sa[2], sb[4];
    #pragma unroll
    for (int i = 0; i < 2; ++i){
        int s = i*256 + tid;
        int row = s >> 3, g = (s & 7) ^ (row & 7);
        ga[i] = A + (size_t)(m0+row)*lda + g*8;
        sa[i] = s*8;
    }
    #pragma unroll
    for (int i = 0; i < 4; ++i){
        int s = i*256 + tid;
        int row = s >> 3, g = (s & 7) ^ (row & 7);
        gb[i] = Bt + (size_t)(n0+row)*ldb + g*8;
        sb[i] = s*8;
    }
    auto stage = [&](int slot, int k0){       // 6 glds16 per thread
        #pragma unroll
        for (int i = 0; i < 2; ++i) glds16(ga[i] + k0, &As[slot][sa[i]]);
        #pragma unroll
        for (int i = 0; i < 4; ++i) glds16(gb[i] + k0, &Bs[slot][sb[i]]);
    };

    int aoff[2][2], boff[2][4];
    #pragma unroll
    for (int ks = 0; ks < 2; ++ks){
        #pragma unroll
        for (int mi = 0; mi < 2; ++mi){
            int row = wm*32 + mi*16 + n16;
            aoff[ks][mi] = row*64 + (((ks*4 + quad) ^ (row & 7))*8);
        }
        #pragma unroll
        for (int ni = 0; ni < 4; ++ni){
            int row = wn*64 + ni*16 + n16;
            boff[ks][ni] = row*64 + (((ks*4 + quad) ^ (row & 7))*8);
        }
    }

    stage(0, 0);
    int NT = K >> 6;
    for (int t = 0; t < NT; ++t){
        int cur = t & 1;
        if (t + 1 < NT){
            stage(cur ^ 1, (t+1)*64);
            asm volatile("s_waitcnt vmcnt(6)" ::: "memory");
        } else {
            asm volatile("s_waitcnt vmcnt(0)" ::: "memory");
        }
        __builtin_amdgcn_s_barrier();
        __builtin_amdgcn_s_setprio(1);
        #pragma unroll
        for (int ks = 0; ks < 2; ++ks){
            short8 af[2], bf[4];
            #pragma unroll
            for (int mi = 0; mi < 2; ++mi)
                af[mi] = *(const short8*)&As[cur][aoff[ks][mi]];
            #pragma unroll
            for (int ni = 0; ni < 4; ++ni)
                bf[ni] = *(const short8*)&Bs[cur][boff[ks][ni]];
            #pragma unroll
            for (int mi = 0; mi < 2; ++mi)
                #pragma unroll
                for (int ni = 0; ni < 4; ++ni)
                    acc[mi][ni] = mfma16(af[mi], bf[ni], acc[mi][ni]);
        }
        __builtin_amdgcn_s_setprio(0);
        asm volatile("s_waitcnt lgkmcnt(0)" ::: "memory");
        __builtin_amdgcn_s_barrier();
    }

    #pragma unroll
    for (int mi = 0; mi < 2; ++mi){
        #pragma unroll
        for (int reg = 0; reg < 4; ++reg){
            int row = m0 + wm*32 + mi*16 + quad*4 + reg;
            #pragma unroll
            for (int ni = 0; ni < 4; ++ni){
                int col = n0 + wn*64 + ni*16 + n16;
                float v = acc[mi][ni][reg];
                if (bias) v += bias[col];
                if (EPI == 1) v = u2f(glu[(size_t)row*512 + col]) * fsigm(v);
                if (EPI == 2) ((float*)C)[(size_t)row*ldc + col] = v;
                else          ((u16*)C)[(size_t)row*ldc + col]  = f2u(v);
            }
        }
    }
}

// ------------------------------------------------------------------
// MFMA flash attention (S^T form), causal, dh=64, 8 heads.  PAIRED 64-row
// Q-tiles (qt = 31-p then p).  Double-buffered K/V LDS + async reg-staging,
// l via all-ones MFMA column, defer-max (THR=8, log2 domain).
__global__ __launch_bounds__(256) void flash_kernel(
    const u16* __restrict__ QK,   // [8192,1024]: cols 0..511 Q', 512..1023 K
    const u16* __restrict__ VT,   // [512,8192]
    u16* __restrict__ O)          // [8192,512]
{
    int bid = blockIdx.x;
    int p = bid >> 5;                  // 0..15
    int bh = bid & 31;
    int h = bh & 7, b = bh >> 3;
    __shared__ u16 Ks[2][64*64];
    __shared__ u16 Vt[2][64*64];
    __shared__ u16 Ps[4][16*64];
    int tid = threadIdx.x;
    int wave = tid >> 6, lane = tid & 63;
    int n16 = lane & 15, quad = lane >> 4;
    size_t btok = (size_t)b*2048;
    int r = tid >> 2;
    int g0 = (tid & 3) * 2;
    const short8 ones8 = {0x3F80,0x3F80,0x3F80,0x3F80,0x3F80,0x3F80,0x3F80,0x3F80};

    uint4 ka, kb, va, vb;              // in-flight K/V registers
    auto loadKV = [&](int kt){
        const uint4* kp = (const uint4*)&QK[(btok + kt*64 + r)*1024 + 512 + h*64 + g0*8];
        ka = kp[0]; kb = kp[1];
        const uint4* vp = (const uint4*)&VT[(size_t)(h*64 + r)*8192 + btok + kt*64 + g0*8];
        va = vp[0]; vb = vp[1];
    };
    auto writeKV = [&](int s){         // compiler inserts vmcnt wait (data dep)
        *(uint4*)&Ks[s][r*64 + ((g0  ) ^ (r&7))*8] = ka;
        *(uint4*)&Ks[s][r*64 + ((g0+1) ^ (r&7))*8] = kb;
        *(uint4*)&Vt[s][r*64 + ((g0  ) ^ (r&7))*8] = va;
        *(uint4*)&Vt[s][r*64 + ((g0+1) ^ (r&7))*8] = vb;
    };

    for (int ph = 0; ph < 2; ++ph){
        int qt = ph ? p : (31 - p);
        size_t tok0 = btok + qt*64;
        short8 qf[2];
        #pragma unroll
        for (int ks = 0; ks < 2; ++ks)
            qf[ks] = *(const short8*)&QK[(tok0 + wave*16 + n16)*1024
                                         + h*64 + ks*32 + quad*8];
        int qrow = qt*64 + wave*16 + n16;
        float m_st = -3.0e38f;
        f32x4 ov[5] = {};              // [0..3]=O accum, [4]=row-sum (l) accum

        loadKV(0);
        __syncthreads();               // prior ph's readers done with LDS
        writeKV(0);
        __syncthreads();               // slot 0 visible to all waves

        for (int kt = 0; kt <= qt; ++kt){
            int cur = kt & 1;
            if (kt < qt) loadKV(kt+1);         // issue early; lands under compute

            f32x4 st[4];
            #pragma unroll
            for (int ct = 0; ct < 4; ++ct){
                f32x4 a = {};
                #pragma unroll
                for (int ks = 0; ks < 2; ++ks){
                    short8 kf = *(const short8*)&Ks[cur][(ct*16+n16)*64 + (((ks*4+quad) ^ (n16&7))*8)];
                    a = mfma16(kf, qf[ks], a);
                }
                st[ct] = a;
            }
            if (kt == qt){                 // diagonal: causal mask
                #pragma unroll
                for (int ct = 0; ct < 4; ++ct){
                    int kb0 = kt*64 + ct*16 + quad*4;
                    #pragma unroll
                    for (int r4 = 0; r4 < 4; ++r4)
                        if (kb0 + r4 > qrow) st[ct][r4] = -3.0e38f;
                }
            }
            float mx = -3.0e38f;
            #pragma unroll
            for (int ct = 0; ct < 4; ++ct)
                #pragma unroll
                for (int r4 = 0; r4 < 4; ++r4) mx = fmaxf(mx, st[ct][r4]);
            mx = fmaxf(mx, __shfl_xor(mx, 16));
            mx = fmaxf(mx, __shfl_xor(mx, 32));
            // defer-max: only rescale when some row's max grew past the slack
            if (!__all(mx <= m_st + 8.f)){
                float mn = fmaxf(m_st, mx);
                float al = exp2f(m_st - mn);
                m_st = mn;
                #pragma unroll
                for (int r4 = 0; r4 < 4; ++r4){
                    float aa = __shfl(al, quad*4 + r4);
                    #pragma unroll
                    for (int dt = 0; dt < 5; ++dt) ov[dt][r4] *= aa;
                }
            }
            #pragma unroll
            for (int ct = 0; ct < 4; ++ct)
                #pragma unroll
                for (int r4 = 0; r4 < 4; ++r4)
                    st[ct][r4] = exp2f(st[ct][r4] - m_st);   // bounded by 2^8
            // P store: q-major rows (q = n16), packed b64, truncating cvt
            #pragma unroll
            for (int ct = 0; ct < 4; ++ct){
                ushort4 h4;
                h4.x = f2u_t(st[ct][0]); h4.y = f2u_t(st[ct][1]);
                h4.z = f2u_t(st[ct][2]); h4.w = f2u_t(st[ct][3]);
                int goff = ct*2 + (quad >> 1);
                *(ushort4*)&Ps[wave][n16*64 + ((goff ^ (n16&7))*8) + (quad&1)*4] = h4;
            }
            // O += P V ; l += P @ 1  (same-wave LDS write->read, program order)
            short8 ap[2];
            #pragma unroll
            for (int ks = 0; ks < 2; ++ks)
                ap[ks] = *(const short8*)&Ps[wave][n16*64 + (((ks*4+quad) ^ (n16&7))*8)];
            #pragma unroll
            for (int dt = 0; dt < 4; ++dt)
                #pragma unroll
                for (int ks = 0; ks < 2; ++ks){
                    short8 bv = *(const short8*)&Vt[cur][(dt*16+n16)*64 + (((ks*4+quad) ^ (n16&7))*8)];
                    ov[dt] = mfma16(ap[ks], bv, ov[dt]);
                }
            #pragma unroll
            for (int ks = 0; ks < 2; ++ks)
                ov[4] = mfma16(ap[ks], ones8, ov[4]);

            if (kt < qt) writeKV(cur ^ 1);     // vmcnt wait here, hidden by compute
            __syncthreads();                   // single barrier per k-tile
        }
        #pragma unroll
        for (int r4 = 0; r4 < 4; ++r4){
            float inv = __builtin_amdgcn_rcpf(ov[4][r4]);   // l in output-row layout
            size_t row = tok0 + wave*16 + quad*4 + r4;
            #pragma unroll
            for (int dt = 0; dt < 4; ++dt)
                O[row*512 + h*64 + dt*16 + n16] = f2u(ov[dt][r4] * inv);
        }
    }
}

// ------------------------------------------------------------------
// x1h = bf16( rmsnorm(x + y_bf16) * scale )
__global__ __launch_bounds__(256) void rmsnorm_kernel(
    const float* __restrict__ x, const u16* __restrict__ y,
    const float* __restrict__ scale, u16* __restrict__ out)
{
    int tok = blockIdx.x, tid = threadIdx.x;
    size_t base = (size_t)tok * 512;
    float v0 = x[base+tid]     + u2f(y[base+tid]);
    float v1 = x[base+tid+256] + u2f(y[base+tid+256]);
    float ss = v0*v0 + v1*v1;
    for (int off = 32; off; off >>= 1) ss += __shfl_down(ss, off);
    __shared__ float ws[4];
    if ((tid & 63) == 0) ws[tid >> 6] = ss;
    __syncthreads();
    float rstd = rsqrtf((ws[0]+ws[1]+ws[2]+ws[3])*(1.f/512.f) + 1e-6f);
    out[base+tid]     = f2u(scale[tid]     * v0 * rstd);
    out[base+tid+256] = f2u(scale[tid+256] * v1 * rstd);
}

// out_fp32 = rmsnorm(x1h + moe_f32 + ROUT@b2) * scale
__global__ __launch_bounds__(256) void final_kernel(
    const u16* __restrict__ x1, const float* __restrict__ moe,
    const float* __restrict__ rout, const float* __restrict__ b2,
    const float* __restrict__ scale, float* __restrict__ out)
{
    int tok = blockIdx.x, tid = threadIdx.x;
    size_t base = (size_t)tok * 512;
    float r0 = rout[tok*4+0], r1 = rout[tok*4+1], r2 = rout[tok*4+2], r3 = rout[tok*4+3];
    float bb0 = r0*b2[tid]     + r1*b2[512+tid]     + r2*b2[1024+tid]     + r3*b2[1536+tid];
    float bb1 = r0*b2[tid+256] + r1*b2[768+tid]     + r2*b2[1280+tid]     + r3*b2[1792+tid];
    float v0 = u2f(x1[base+tid])     + moe[base+tid]     + bb0;
    float v1 = u2f(x1[base+tid+256]) + moe[base+tid+256] + bb1;
    float ss = v0*v0 + v1*v1;
    for (int off = 32; off; off >>= 1) ss += __shfl_down(ss, off);
    __shared__ float ws[4];
    if ((tid & 63) == 0) ws[tid >> 6] = ss;
    __syncthreads();
    float rstd = rsqrtf((ws[0]+ws[1]+ws[2]+ws[3])*(1.f/512.f) + 1e-6f);
    out[base+tid]     = scale[tid]     * v0 * rstd;
    out[base+tid+256] = scale[tid+256] * v1 * rstd;
}

// router: softmax(x1h @ wr + br), one wave per token
__global__ __launch_bounds__(256) void router_kernel(
    const u16* __restrict__ x1, const float* __restrict__ wr,
    const float* __restrict__ br, float* __restrict__ rout)
{
    int wid = threadIdx.x >> 6, lane = threadIdx.x & 63;
    int tok = blockIdx.x*4 + wid;
    const u16* xp = x1 + (size_t)tok*512;
    float p0=0.f, p1=0.f, p2=0.f, p3=0.f;
    for (int d = lane; d < 512; d += 64){
        float xv = u2f(xp[d]);
        p0 += xv*wr[d*4+0]; p1 += xv*wr[d*4+1];
        p2 += xv*wr[d*4+2]; p3 += xv*wr[d*4+3];
    }
    for (int off = 32; off; off >>= 1){
        p0 += __shfl_down(p0,off); p1 += __shfl_down(p1,off);
        p2 += __shfl_down(p2,off); p3 += __shfl_down(p3,off);
    }
    if (lane == 0){
        p0 += br[0]; p1 += br[1]; p2 += br[2]; p3 += br[3];
        float mx = fmaxf(fmaxf(p0,p1), fmaxf(p2,p3));
        float e0=__expf(p0-mx), e1=__expf(p1-mx), e2=__expf(p2-mx), e3=__expf(p3-mx);
        float inv = 1.f/(e0+e1+e2+e3);
        rout[tok*4+0]=e0*inv; rout[tok*4+1]=e1*inv;
        rout[tok*4+2]=e2*inv; rout[tok*4+3]=e3*inv;
    }
}

// ------------------------------------------------------------------
extern "C" void kernel_launch(void* const* d_in, const int* in_sizes, int n_in,
                              void* d_out, int out_size, void* d_ws, size_t ws_size,
                              hipStream_t stream)
{
    const float* x    = (const float*)d_in[0];
    const float* mp_w = (const float*)d_in[3];
    const float* mp_b = (const float*)d_in[4];
    const float* fu_w = (const float*)d_in[5];
    const float* fu_b = (const float*)d_in[6];
    const float* wc   = (const float*)d_in[7];
    const float* wk   = (const float*)d_in[8];
    const float* wv   = (const float*)d_in[9];
    const float* wq   = (const float*)d_in[10];
    const float* wo   = (const float*)d_in[11];
    const float* s1   = (const float*)d_in[12];
    const float* s2   = (const float*)d_in[13];
    const float* wr   = (const float*)d_in[14];
    const float* br   = (const float*)d_in[15];
    const float* wg   = (const float*)d_in[16];
    const float* bg   = (const float*)d_in[17];
    const float* w1   = (const float*)d_in[18];
    const float* b1   = (const float*)d_in[19];
    const float* w2   = (const float*)d_in[20];
    const float* b2   = (const float*)d_in[21];

    char* wsb = (char*)d_ws;
    const size_t MB = 1024*1024;
    // persistent weights (0..12.3 MB)
    u16*   WqkvC  = (u16*)(wsb + 0);                 // [1536,1024]
    u16*   woT    = (u16*)(wsb + 3*MB);              // [512,512]
    u16*   wgT    = (u16*)(wsb + 3*MB + 512*1024);   // [512,512]
    u16*   w1T    = (u16*)(wsb + 4*MB);              // [4096,512]
    u16*   w2Ts   = (u16*)(wsb + 8*MB);              // [512,4096]
    float* fubias = (float*)(wsb + 12*MB);           // 512
    float* qkvbias= (float*)(wsb + 12*MB + 8192);    // 1536
    float* ROUT   = (float*)(wsb + 12*MB + 32768);   // 8192x4 (128 KB)
    // prepass scratch (dead before gatepool)
    u16*   wqkvT  = (u16*)(wsb + 12*MB + 512*1024);  // [1536,512] 12.5-14
    u16*   fuBT   = (u16*)(wsb + 16*MB);             // [512,512]
    u16*   mp_wB  = (u16*)(wsb + 16*MB + 512*1024);  // [512,512]
    u16*   WfuBF  = (u16*)(wsb + 17*MB);             // [1024,512]
    // rotating big buffers
    u16*   x1h   = (u16*)(wsb + 14*MB);              // 14-22, live till final
    u16*   XFcat = (u16*)(wsb + 16*MB);              // 16-32, dead after QKV
    u16*   XG    = (u16*)(wsb + 22*MB);              // 22-30, live through w1
    u16*   S3    = (u16*)(wsb + 24*MB);              // 24-32, dead after rmsnorm
    u16*   QKb   = (u16*)(wsb + 32*MB);              // 32-48, dead after flash
    float* MOE   = (float*)(wsb + 32*MB);            // 32-48 fp32 (MoE phase)
    u16*   VbT   = (u16*)(wsb + 48*MB);              // 48-56, dead after flash
    u16*   ATT   = (u16*)(wsb + 56*MB);              // 56-64, dead after wo
    u16*   Hb    = (u16*)(wsb + 48*MB);              // 48-112 contiguous [8192,4096] (MoE, big)
    u16*   HbA   = (u16*)(wsb + 48*MB);              // fallback path
    bool big = ws_size >= (size_t)112*MB;

    auto mg128 = [&](const u16* A, const u16* A2, int lda, const u16* Bt, int ldb,
                     const float* bias, const float* rs, const u16* glu,
                     void* C, void* CB, int ldc, u16* C2, int M, int N, int K, int flags){
        dim3 g(N/128, M/128);
        mgemm_kernel<128><<<g, 256, 0, stream>>>(A, A2, lda, Bt, ldb, bias, rs, glu,
                                                 C, CB, ldc, C2, K, flags);
    };
    auto mg64 = [&](const u16* A, const u16* A2, int lda, const u16* Bt, int ldb,
                    const float* bias, const float* rs, const u16* glu,
                    void* C, void* CB, int ldc, u16* C2, int M, int N, int K, int flags){
        dim3 g(N/128, M/64);
        mgemm_kernel<64><<<g, 256, 0, stream>>>(A, A2, lda, Bt, ldb, bias, rs, glu,
                                                C, CB, ldc, C2, K, flags);
    };

    // ---- prepass (re-run every call)
    TJobs JJ; JJ.n = 12;
    auto setj = [&](int i, const float* src, u16* dst, int K, int N, int ldout,
                    int coloff, float scale){
        JJ.j[i] = TJob{src, dst, K, N, ldout, coloff, (K/32)*(N/32), scale};
    };
    setj(0, wq,            wqkvT, 512,  512,  512, 0, QSCALE);   // Q' = wq*0.125*log2e
    setj(1, wo,            woT,   512,  512,  512, 0, 1.f);
    setj(2, wg,            wgT,   512,  512,  512, 0, 1.f);
    setj(3, fu_w + 512*512,fuBT,  512,  512,  512, 0, 1.f);      // fuB^T
    for (int e = 0; e < 4; ++e){
        setj(4+e, w1 + (size_t)e*512*1024, w1T + (size_t)e*1024*512, 512, 1024, 512, 0, 1.f);
        setj(8+e, w2 + (size_t)e*1024*512, w2Ts + (size_t)e*1024, 1024, 512, 4096, 0, 1.f);
    }
    int nt = 4*256 + 8*512;
    tconv_all_kernel<<<nt, 256, 0, stream>>>(JJ);
    convert_kernel<<<512*512/256, 256, 0, stream>>>(mp_w, mp_wB);
    convert_kernel<<<512*512/256, 256, 0, stream>>>(fu_w, WfuBF);            // fuA rows 0..511
    sgemm_kernel<<<dim3(8,8), 256, 0, stream>>>(wc, wk, wqkvT + 512*512, 32);  // Wck^T
    sgemm_kernel<<<dim3(8,8), 256, 0, stream>>>(wc, wv, wqkvT + 1024*512, 32); // Wcv^T
    biasfold_kernel<<<512, 256, 0, stream>>>(fu_b, mp_b, fu_w, fubias);
    qkvbias_kernel<<<1536, 256, 0, stream>>>(fubias, wqkvT, qkvbias);
    // F1 = mp_w @ fuB -> WfuBF rows 512..1023 (row-major bf16).  16 blocks.
    g128_kernel<0><<<dim3(4, 4), 256, 0, stream>>>(
        mp_wB, 512, fuBT, 512, nullptr, nullptr, WfuBF + 512*512, 512, nullptr, 512);
    // Combined: WqkvC[1536,1024] = wqkvT[1536,512] @ WfuBF[1024,512]^T.  96 blocks.
    g128_kernel<0><<<dim3(8, 12), 256, 0, stream>>>(
        wqkvT, 512, WfuBF, 512, nullptr, nullptr, WqkvC, 1024, nullptr, 512);

    // ---- main pipeline
    gatepool_kernel<<<(TOK/16)*512/256, 256, 0, stream>>>(x, XFcat);
    // QKV from XFcat (xfu folded): Q'|K -> QKb, V^T -> VbT.  768 blocks, 2/CU.
    g128_kernel<1><<<dim3(12, 64), 256, 0, stream>>>(
        XFcat, 1024, WqkvC, 1024, qkvbias, nullptr, QKb, 1024, VbT, 1024);
    flash_kernel<<<512, 256, 0, stream>>>(QKb, VbT, ATT);
    // attn@wo: 64x128 pipelined, 512 blocks
    gemm64p_kernel<0><<<dim3(4, 128), 256, 0, stream>>>(
        ATT, 512, woT, 512, nullptr, nullptr, S3, 512, 512);
    rmsnorm_kernel<<<TOK, 256, 0, stream>>>(x, S3, s1, x1h);                 // x1
    router_kernel<<<TOK/4, 256, 0, stream>>>(x1h, wr, br, ROUT);
    // xg = x1h * sigmoid(x1h@wg+bg): 64x128 pipelined
    gemm64p_kernel<1><<<dim3(4, 128), 256, 0, stream>>>(
        x1h, 512, wgT, 512, bg, x1h, XG, 512, 512);
    if (big){
        // w1: 256^2 pipelined BK=32, M=8192, N=4096, K=512.  512 blocks, 2/CU.
        gemm256_kernel<0><<<dim3(16, 32), 512, 0, stream>>>(
            XG, 512, w1T, 512, b1, ROUT, Hb, 4096, nullptr, 512);
        // w2: 64x128 pipelined, M=8192, N=512, K=4096.  512 blocks.
        gemm64p_kernel<2><<<dim3(4, 128), 256, 0, stream>>>(
            Hb, 4096, w2Ts, 4096, nullptr, nullptr, MOE, 512, 4096);
    } else {
        // fallback (r6 structure): pairwise experts, Hb = HbA [8192,2048]
        for (int p = 0; p < 2; ++p){
            mg128(XG, XG + (size_t)MSPLIT*512, 512, w1T + (size_t)p*2048*512, 512,
                  b1 + p*2048, ROUT + p*2, 0,
                  HbA, HbA + (size_t)MSPLIT*2048, 2048, 0,
                  TOK, 2048, 512, GF_GELU | GF_RSCOL);
            mg64 (HbA, HbA + (size_t)MSPLIT*2048, 2048, w2Ts + p*2048, 4096, 0, 0, 0,
                  MOE, (float*)MOE + (size_t)MSPLIT*512, 512, 0,
                  TOK, 512, 2048, p ? GF_ACCUM : GF_F32OUT);
        }
    }
    final_kernel<<<TOK, 256, 0, stream>>>(x1h, MOE, ROUT, b2, s2, (float*)d_out);
}

// Round 10
// 416.087 us; speedup vs baseline: 1.4838x; 1.4838x over previous
//
#include <hip/hip_runtime.h>
#include <math.h>

#define B_   4
#define T_   2048
#define D_   512
#define TOK  (B_*T_)      // 8192 tokens
#define TL_  2045         // N_BLOCKS*(T//N_BLOCKS) = 5*409
#define GATE 0.2f         // softmax(...).mean(-1) over same axis == 1/5
#define QSCALE 0.18033688011112043f   // 0.125 * log2(e): S in log2 domain
#define MSPLIT 4096

typedef unsigned short u16;
typedef __attribute__((ext_vector_type(8))) short short8;   // 8 bf16 = 4 VGPRs
typedef __attribute__((ext_vector_type(4))) float f32x4;

static __device__ __forceinline__ u16 f2u(float f){      // fp32 -> bf16 (RNE)
    union { float f; unsigned u; } a; a.f = f;
    unsigned r = a.u + 0x7fffu + ((a.u >> 16) & 1u);
    return (u16)(r >> 16);
}
static __device__ __forceinline__ u16 f2u_t(float f){    // truncating (P >= 0)
    return (u16)(__float_as_uint(f) >> 16);
}
static __device__ __forceinline__ float u2f(u16 u){
    union { unsigned u; float f; } a; a.u = ((unsigned)u) << 16;
    return a.f;
}
static __device__ __forceinline__ f32x4 mfma16(short8 a, short8 b, f32x4 c){
    return __builtin_amdgcn_mfma_f32_16x16x32_bf16(a, b, c, 0, 0, 0);
}
static __device__ __forceinline__ void glds16(const u16* g, u16* l){
    __builtin_amdgcn_global_load_lds((const __attribute__((address_space(1))) void*)g,
                                     (__attribute__((address_space(3))) void*)l, 16, 0, 0);
}
// fast GELU (tanh form): hw v_exp_f32 + v_rcp_f32 (no precise-divide sequence).
static __device__ __forceinline__ float fgelu(float x){
    float u = x * (1.f + 0.044715f * x * x);
    return x * __builtin_amdgcn_rcpf(1.f + exp2f(-2.3021193f * u));
}
static __device__ __forceinline__ float fsigm(float x){  // sigmoid via rcp
    return __builtin_amdgcn_rcpf(1.f + __expf(-x));
}

// ------------------------------------------------------------------
// gate + pool fused: XFcat[:,0:512]=bf16(0.2*x masked), XFcat[:,512:]=bf16(pool)
__global__ __launch_bounds__(256) void gatepool_kernel(
    const float* __restrict__ x, u16* __restrict__ xfcat)
{
    int idx = blockIdx.x*256 + threadIdx.x;
    int d = idx & 511, g = idx >> 9;
    int b = g >> 7, t0 = (g & 127) << 4;
    const float* xp = x + ((size_t)b*2048)*512 + d;
    float v[30];
    #pragma unroll
    for (int j = 0; j < 30; ++j){
        int u = t0 - 7 + j;
        v[j] = (u >= 0 && u < TL_) ? xp[(size_t)u*512] : 0.f;
    }
    float p[31]; p[0] = 0.f;
    #pragma unroll
    for (int j = 0; j < 30; ++j) p[j+1] = p[j] + v[j];
    u16* xc = xfcat + ((size_t)(b*2048 + t0))*1024 + d;
    #pragma unroll
    for (int i = 0; i < 16; ++i){
        int t = t0 + i;
        float sum = p[i+15] - p[i];                 // u in [t-7, t+7]
        int lo = t-7; if (lo < 0) lo = 0;
        int hi = t+7; if (hi > 2047) hi = 2047;
        xc[(size_t)i*1024]       = f2u((t < TL_) ? GATE*v[i+7] : 0.f);
        xc[(size_t)i*1024 + 512] = f2u(GATE * sum / (float)(hi - lo + 1));
    }
}

// ------------------------------------------------------------------
// batched transpose+convert: src fp32 [K,N] -> dst[n*ldout+coloff+k]=bf16(scale*src)
struct TJob { const float* src; u16* dst; int K, N, ldout, coloff, tiles; float scale; };
struct TJobs { TJob j[13]; int n; };

__global__ __launch_bounds__(256) void tconv_all_kernel(TJobs JJ){
    __shared__ float t[32][33];
    int idx = blockIdx.x;
    int jb = 0;
    while (jb < JJ.n - 1 && idx >= JJ.j[jb].tiles){ idx -= JJ.j[jb].tiles; ++jb; }
    TJob J = JJ.j[jb];
    int tX = J.N >> 5;
    int k0 = (idx / tX) * 32, n0 = (idx % tX) * 32;
    int tx = threadIdx.x & 31, ty = threadIdx.x >> 5;
    #pragma unroll
    for (int i = 0; i < 32; i += 8)
        t[ty+i][tx] = J.src[(size_t)(k0+ty+i)*J.N + n0+tx];
    __syncthreads();
    #pragma unroll
    for (int i = 0; i < 32; i += 8)
        J.dst[(size_t)(n0+ty+i)*J.ldout + J.coloff + k0+tx] = f2u(J.scale * t[tx][ty+i]);
}

// fp32 -> bf16 plain convert
__global__ void convert_kernel(const float* __restrict__ in, u16* __restrict__ out){
    int idx = blockIdx.x*256 + threadIdx.x;
    out[idx] = f2u(in[idx]);
}

// fubias[n] = fu_b[n] + sum_d mp_b[d] * fu_w[512+d][n]
__global__ __launch_bounds__(256) void biasfold_kernel(
    const float* __restrict__ fu_b, const float* __restrict__ mp_b,
    const float* __restrict__ fu_w, float* __restrict__ out)
{
    int n = blockIdx.x, tid = threadIdx.x;
    float s = mp_b[tid]*fu_w[(size_t)(512+tid)*512 + n]
            + mp_b[tid+256]*fu_w[(size_t)(768+tid)*512 + n];
    for (int off = 32; off; off >>= 1) s += __shfl_down(s, off);
    __shared__ float ws[4];
    if ((tid & 63) == 0) ws[tid >> 6] = s;
    __syncthreads();
    if (tid == 0) out[n] = fu_b[n] + ws[0]+ws[1]+ws[2]+ws[3];
}

// qkvbias[n] = sum_d fubias[d] * wqkvT[n][d]
__global__ __launch_bounds__(256) void qkvbias_kernel(
    const float* __restrict__ fubias, const u16* __restrict__ wqkvT,
    float* __restrict__ out)
{
    int n = blockIdx.x, tid = threadIdx.x;
    const u16* wp = wqkvT + (size_t)n*512;
    float s = fubias[tid]*u2f(wp[tid]) + fubias[tid+256]*u2f(wp[tid+256]);
    for (int off = 32; off; off >>= 1) s += __shfl_down(s, off);
    __shared__ float ws[4];
    if ((tid & 63) == 0) ws[tid >> 6] = s;
    __syncthreads();
    if (tid == 0) out[n] = ws[0]+ws[1]+ws[2]+ws[3];
}

// small fp32 GEMM, N=512, writes bf16 TRANSPOSED: dstT[n*512 + m] = (A@B)[m][n]
__global__ __launch_bounds__(256) void sgemm_kernel(const float* __restrict__ A,
    const float* __restrict__ B, u16* __restrict__ dstT, int K){
    __shared__ float As[16][65];
    __shared__ float Bs[16][65];
    int tid = threadIdx.x;
    int tx = tid & 15, ty = tid >> 4;
    int m0 = blockIdx.y*64, n0 = blockIdx.x*64;
    int arow = tid >> 2, akq = (tid & 3) * 4;
    int bk = tid >> 4, bn = (tid & 15) * 4;
    float acc[4][4] = {};
    for (int k0 = 0; k0 < K; k0 += 16){
        const float* Ap = A + (size_t)(m0+arow)*K + k0 + akq;
        As[akq+0][arow]=Ap[0]; As[akq+1][arow]=Ap[1];
        As[akq+2][arow]=Ap[2]; As[akq+3][arow]=Ap[3];
        const float* Bp = B + (size_t)(k0+bk)*512 + n0 + bn;
        Bs[bk][bn+0]=Bp[0]; Bs[bk][bn+1]=Bp[1];
        Bs[bk][bn+2]=Bp[2]; Bs[bk][bn+3]=Bp[3];
        __syncthreads();
        #pragma unroll
        for (int kk = 0; kk < 16; ++kk){
            float av[4], bv[4];
            #pragma unroll
            for (int i=0;i<4;++i) av[i]=As[kk][ty*4+i];
            #pragma unroll
            for (int j=0;j<4;++j) bv[j]=Bs[kk][tx*4+j];
            #pragma unroll
            for (int i=0;i<4;++i)
                #pragma unroll
                for (int j=0;j<4;++j) acc[i][j] += av[i]*bv[j];
        }
        __syncthreads();
    }
    #pragma unroll
    for (int i=0;i<4;++i)
        #pragma unroll
        for (int j=0;j<4;++j)
            dstT[(size_t)(n0+tx*4+j)*512 + m0+ty*4+i] = f2u(acc[i][j]);
}

// ------------------------------------------------------------------
// bf16 MFMA GEMM: legacy 2-barrier structure (small-workspace fallback only)
#define GF_GELU   1
#define GF_ACCUM  2
#define GF_RSCOL  4
#define GF_GLU    8
#define GF_F32OUT 16
#define GF_QKV    32

template<int MT>
__global__ __launch_bounds__(256) void mgemm_kernel(
    const u16* __restrict__ A, const u16* __restrict__ A2, int lda,
    const u16* __restrict__ Bt, int ldb,
    const float* __restrict__ bias, const float* __restrict__ rs,
    const u16* __restrict__ glu, void* __restrict__ Cp, void* __restrict__ CpB,
    int ldc, u16* __restrict__ Cp2, int K, int flags)
{
    constexpr int MI = MT/32;            // m-tiles per wave (16 rows each)
    __shared__ u16 As[MT*64];
    __shared__ u16 Bs[128*64];
    int tid = threadIdx.x;
    int wave = tid >> 6, lane = tid & 63;
    int n16 = lane & 15, quad = lane >> 4;
    int m0 = blockIdx.y * MT, n0 = blockIdx.x * 128;
    int wr = (wave >> 1) * (MT/2), wc = (wave & 1) * 64;

    f32x4 acc[MI][4] = {};

    for (int k0 = 0; k0 < K; k0 += 64){
        #pragma unroll
        for (int i = 0; i < MT/32; ++i){
            int s = i*256 + tid;
            int row = s >> 3, g = (s & 7) ^ (row & 7);
            int rg = m0 + row;
            const u16* Ap = (rg < MSPLIT) ? A + (size_t)rg*lda
                                          : A2 + (size_t)(rg - MSPLIT)*lda;
            glds16(Ap + k0 + g*8, As + (size_t)s*8);
        }
        #pragma unroll
        for (int i = 0; i < 4; ++i){
            int s = i*256 + tid;
            int row = s >> 3, g = (s & 7) ^ (row & 7);
            glds16(Bt + (size_t)(n0+row)*ldb + k0 + g*8, Bs + (size_t)s*8);
        }
        __syncthreads();
        #pragma unroll
        for (int ks = 0; ks < 2; ++ks){
            short8 af[MI], bf[4];
            #pragma unroll
            for (int mi = 0; mi < MI; ++mi){
                int row = wr + mi*16 + n16;
                int g = (ks*4 + quad) ^ (row & 7);
                af[mi] = *(const short8*)&As[row*64 + g*8];
            }
            #pragma unroll
            for (int ni = 0; ni < 4; ++ni){
                int row = wc + ni*16 + n16;
                int g = (ks*4 + quad) ^ (row & 7);
                bf[ni] = *(const short8*)&Bs[row*64 + g*8];
            }
            #pragma unroll
            for (int mi = 0; mi < MI; ++mi)
                #pragma unroll
                for (int ni = 0; ni < 4; ++ni)
                    acc[mi][ni] = mfma16(af[mi], bf[ni], acc[mi][ni]);
        }
        __syncthreads();
    }

    if ((flags & GF_QKV) && n0 >= 1024){
        #pragma unroll
        for (int mi = 0; mi < MI; ++mi){
            int row0 = m0 + wr + mi*16 + quad*4;
            #pragma unroll
            for (int ni = 0; ni < 4; ++ni){
                int col = n0 + wc + ni*16 + n16;
                float bb = bias[col];
                ushort4 h4;
                h4.x = f2u(acc[mi][ni][0] + bb); h4.y = f2u(acc[mi][ni][1] + bb);
                h4.z = f2u(acc[mi][ni][2] + bb); h4.w = f2u(acc[mi][ni][3] + bb);
                *(ushort4*)&Cp2[(size_t)(col-1024)*8192 + row0] = h4;
            }
        }
        return;
    }

    #pragma unroll
    for (int mi = 0; mi < MI; ++mi){
        #pragma unroll
        for (int reg = 0; reg < 4; ++reg){
            int row = m0 + wr + mi*16 + quad*4 + reg;
            void*  cb = (row < MSPLIT) ? Cp : CpB;
            size_t rr = (row < MSPLIT) ? row : row - MSPLIT;
            #pragma unroll
            for (int ni = 0; ni < 4; ++ni){
                int col = n0 + wc + ni*16 + n16;
                float v = acc[mi][ni][reg];
                if (bias) v += bias[col];
                if (flags & GF_GELU)  v = fgelu(v);
                if (flags & GF_GLU)   v = u2f(glu[(size_t)row*512 + col]) * fsigm(v);
                if (flags & GF_RSCOL) v *= rs[(size_t)row*4 + (col >> 10)];
                size_t ci = rr*ldc + col;
                if (flags & GF_ACCUM)       ((float*)cb)[ci] += v;
                else if (flags & GF_F32OUT) ((float*)cb)[ci]  = v;
                else                        ((u16*)cb)[ci]    = f2u(v);
            }
        }
    }
}

// ------------------------------------------------------------------
// 256x256-tile pipelined bf16 GEMM (w1), counted-vmcnt (T3+T4) + XCD swizzle.
// BK=64, 8 waves, 128 KiB dbuf LDS (r8-verified loop).  NEW: LDS-bounce
// epilogue — bf16 results bounce through a wave-private padded LDS slab
// (stride 72 u16, 2-way-conflict-free) and are stored as 2x16B dwordx4 per
// lane instead of 128 scalar 2B stores.  Wave-private slabs: no barriers.
__global__ __launch_bounds__(512, 2) void gemm256_kernel(
    const u16* __restrict__ A, int lda,
    const u16* __restrict__ Bt, int ldb,
    const float* __restrict__ bias, const float* __restrict__ rs,
    u16* __restrict__ C, int ldc, int K)
{
    __shared__ u16 As[2][256*64];
    __shared__ u16 Bs[2][256*64];
    int tid = threadIdx.x;
    int wave = tid >> 6, lane = tid & 63;
    int n16 = lane & 15, quad = lane >> 4;
    int D = blockIdx.y * gridDim.x + blockIdx.x;
    int nwg = gridDim.x * gridDim.y;
    int T = (D & 7) * (nwg >> 3) + (D >> 3);
    int m0 = (T / gridDim.x) * 256, n0 = (T % gridDim.x) * 256;
    int wm = wave >> 2, wn = wave & 3;        // 2 x 4 wave grid, wave tile 128x64

    f32x4 acc[8][4] = {};

    const u16* ga[4]; const u16* gb[4]; int sa[4];
    #pragma unroll
    for (int i = 0; i < 4; ++i){
        int s = i*512 + tid;
        int row = s >> 3, g = (s & 7) ^ (row & 7);
        ga[i] = A  + (size_t)(m0+row)*lda + g*8;
        gb[i] = Bt + (size_t)(n0+row)*ldb + g*8;
        sa[i] = s*8;
    }
    auto stage = [&](int slot, int k0){       // 8 glds16 per thread
        #pragma unroll
        for (int i = 0; i < 4; ++i) glds16(ga[i] + k0, &As[slot][sa[i]]);
        #pragma unroll
        for (int i = 0; i < 4; ++i) glds16(gb[i] + k0, &Bs[slot][sa[i]]);
    };

    int aoff[2][8], boff[2][4];
    #pragma unroll
    for (int ks = 0; ks < 2; ++ks){
        #pragma unroll
        for (int mi = 0; mi < 8; ++mi){
            int row = wm*128 + mi*16 + n16;
            aoff[ks][mi] = row*64 + (((ks*4 + quad) ^ (row & 7))*8);
        }
        #pragma unroll
        for (int ni = 0; ni < 4; ++ni){
            int row = wn*64 + ni*16 + n16;
            boff[ks][ni] = row*64 + (((ks*4 + quad) ^ (row & 7))*8);
        }
    }

    stage(0, 0);
    int NT = K >> 6;
    for (int t = 0; t < NT; ++t){
        int cur = t & 1;
        if (t + 1 < NT){
            stage(cur ^ 1, (t+1)*64);                       // prefetch next tile
            asm volatile("s_waitcnt vmcnt(8)" ::: "memory");// previous batch only
        } else {
            asm volatile("s_waitcnt vmcnt(0)" ::: "memory");
        }
        __builtin_amdgcn_s_barrier();                       // slot cur complete for all
        __builtin_amdgcn_s_setprio(1);
        #pragma unroll
        for (int ks = 0; ks < 2; ++ks){
            short8 af[8], bf[4];
            #pragma unroll
            for (int mi = 0; mi < 8; ++mi)
                af[mi] = *(const short8*)&As[cur][aoff[ks][mi]];
            #pragma unroll
            for (int ni = 0; ni < 4; ++ni)
                bf[ni] = *(const short8*)&Bs[cur][boff[ks][ni]];
            #pragma unroll
            for (int mi = 0; mi < 8; ++mi)
                #pragma unroll
                for (int ni = 0; ni < 4; ++ni)
                    acc[mi][ni] = mfma16(af[mi], bf[ni], acc[mi][ni]);
        }
        __builtin_amdgcn_s_setprio(0);
        asm volatile("s_waitcnt lgkmcnt(0)" ::: "memory");  // ds_reads of cur done
        __builtin_amdgcn_s_barrier();                       // safe to overwrite cur
    }
    // after final barrier all waves are done with As/Bs -> reuse as bounce.

    float bb[4];
    #pragma unroll
    for (int ni = 0; ni < 4; ++ni)
        bb[ni] = bias ? bias[n0 + wn*64 + ni*16 + n16] : 0.f;

    int e = n0 >> 10;   // expert id; 256-tile never crosses a 1024 boundary
    u16* bounce = &As[0][0];
    int bbase = wave * 2432;             // per-wave private: 2 slots x 1216 u16
    int wrow = lane >> 2, wseg = lane & 3;

    #pragma unroll
    for (int mi = 0; mi < 8; ++mi){
        int sl = bbase + (mi & 1) * 1216;
        #pragma unroll
        for (int reg = 0; reg < 4; ++reg){
            int row = m0 + wm*128 + mi*16 + quad*4 + reg;
            float rv = rs[(size_t)row*4 + e];
            #pragma unroll
            for (int ni = 0; ni < 4; ++ni){
                float v = acc[mi][ni][reg] + bb[ni];
                v = fgelu(v) * rv;
                bounce[sl + (quad*4 + reg)*72 + ni*16 + n16] = f2u(v);
            }
        }
        // read back row-major (stride-72 pad -> 2-way conflicts only) and
        // store 2x16B per lane; 4 lanes cover a 128B contiguous row chunk.
        const uint4* srcp = (const uint4*)&bounce[sl + wrow*72 + wseg*16];
        uint4 lo = srcp[0], hi = srcp[1];
        size_t crow = (size_t)(m0 + wm*128 + mi*16 + wrow) * ldc
                    + n0 + wn*64 + wseg*16;
        *(uint4*)&C[crow]     = lo;
        *(uint4*)&C[crow + 8] = hi;
    }
}

// ------------------------------------------------------------------
// 128x128-tile pipelined bf16 GEMM, counted-vmcnt + XCD swizzle, hoisted addrs.
// EPI=0: (+bias) bf16 (prepass / generic).
// EPI=1: QKV (n0<1024: bias bf16 -> C; n0>=1024: bias + transpose -> C2).
template<int EPI>
__global__ __launch_bounds__(256, 2) void g128_kernel(
    const u16* __restrict__ A, int lda,
    const u16* __restrict__ Bt, int ldb,
    const float* __restrict__ bias, const float* __restrict__ rs,
    u16* __restrict__ C, int ldc, u16* __restrict__ C2, int K)
{
    __shared__ u16 As[2][128*64];
    __shared__ u16 Bs[2][128*64];
    int tid = threadIdx.x;
    int wave = tid >> 6, lane = tid & 63;
    int n16 = lane & 15, quad = lane >> 4;
    int D = blockIdx.y * gridDim.x + blockIdx.x;
    int nwg = gridDim.x * gridDim.y;
    int T = (nwg % 8 == 0) ? ((D & 7) * (nwg >> 3) + (D >> 3)) : D;
    int m0 = (T / gridDim.x) * 128, n0 = (T % gridDim.x) * 128;
    int wm = wave >> 1, wn = wave & 1;

    f32x4 acc[4][4] = {};

    const u16* ga[4]; const u16* gb[4]; int sa[4];
    #pragma unroll
    for (int i = 0; i < 4; ++i){
        int s = i*256 + tid;
        int row = s >> 3, g = (s & 7) ^ (row & 7);
        ga[i] = A  + (size_t)(m0+row)*lda + g*8;
        gb[i] = Bt + (size_t)(n0+row)*ldb + g*8;
        sa[i] = s*8;
    }
    auto stage = [&](int slot, int k0){       // 8 glds16 per thread
        #pragma unroll
        for (int i = 0; i < 4; ++i) glds16(ga[i] + k0, &As[slot][sa[i]]);
        #pragma unroll
        for (int i = 0; i < 4; ++i) glds16(gb[i] + k0, &Bs[slot][sa[i]]);
    };

    int aoff[2][4], boff[2][4];
    #pragma unroll
    for (int ks = 0; ks < 2; ++ks){
        #pragma unroll
        for (int mi = 0; mi < 4; ++mi){
            int row = wm*64 + mi*16 + n16;
            aoff[ks][mi] = row*64 + (((ks*4 + quad) ^ (row & 7))*8);
        }
        #pragma unroll
        for (int ni = 0; ni < 4; ++ni){
            int row = wn*64 + ni*16 + n16;
            boff[ks][ni] = row*64 + (((ks*4 + quad) ^ (row & 7))*8);
        }
    }

    stage(0, 0);
    int NT = K >> 6;
    for (int t = 0; t < NT; ++t){
        int cur = t & 1;
        if (t + 1 < NT){
            stage(cur ^ 1, (t+1)*64);                       // prefetch next tile
            asm volatile("s_waitcnt vmcnt(8)" ::: "memory");// previous batch only
        } else {
            asm volatile("s_waitcnt vmcnt(0)" ::: "memory");
        }
        __builtin_amdgcn_s_barrier();
        __builtin_amdgcn_s_setprio(1);
        #pragma unroll
        for (int ks = 0; ks < 2; ++ks){
            short8 af[4], bf[4];
            #pragma unroll
            for (int mi = 0; mi < 4; ++mi)
                af[mi] = *(const short8*)&As[cur][aoff[ks][mi]];
            #pragma unroll
            for (int ni = 0; ni < 4; ++ni)
                bf[ni] = *(const short8*)&Bs[cur][boff[ks][ni]];
            #pragma unroll
            for (int mi = 0; mi < 4; ++mi)
                #pragma unroll
                for (int ni = 0; ni < 4; ++ni)
                    acc[mi][ni] = mfma16(af[mi], bf[ni], acc[mi][ni]);
        }
        __builtin_amdgcn_s_setprio(0);
        asm volatile("s_waitcnt lgkmcnt(0)" ::: "memory");
        __builtin_amdgcn_s_barrier();
    }

    if (EPI == 1 && n0 >= 1024){
        #pragma unroll
        for (int mi = 0; mi < 4; ++mi){
            int row0 = m0 + wm*64 + mi*16 + quad*4;
            #pragma unroll
            for (int ni = 0; ni < 4; ++ni){
                int col = n0 + wn*64 + ni*16 + n16;
                float bb = bias[col];
                ushort4 h4;
                h4.x = f2u(acc[mi][ni][0] + bb); h4.y = f2u(acc[mi][ni][1] + bb);
                h4.z = f2u(acc[mi][ni][2] + bb); h4.w = f2u(acc[mi][ni][3] + bb);
                *(ushort4*)&C2[(size_t)(col-1024)*8192 + row0] = h4;
            }
        }
        return;
    }

    float bb[4];
    #pragma unroll
    for (int ni = 0; ni < 4; ++ni)
        bb[ni] = bias ? bias[n0 + wn*64 + ni*16 + n16] : 0.f;

    #pragma unroll
    for (int mi = 0; mi < 4; ++mi){
        #pragma unroll
        for (int reg = 0; reg < 4; ++reg){
            int row = m0 + wm*64 + mi*16 + quad*4 + reg;
            #pragma unroll
            for (int ni = 0; ni < 4; ++ni){
                int col = n0 + wn*64 + ni*16 + n16;
                float v = acc[mi][ni][reg] + bb[ni];
                C[(size_t)row*ldc + col] = f2u(v);
            }
        }
    }
}

// ------------------------------------------------------------------
// 64x128-tile pipelined bf16 GEMM, counted-vmcnt + XCD swizzle, hoisted addrs.
// EPI=0: plain bf16 out (wo).  EPI=1: bias+GLU -> bf16 (wg).  EPI=2: fp32 (w2).
template<int EPI>
__global__ __launch_bounds__(256, 2) void gemm64p_kernel(
    const u16* __restrict__ A, int lda,
    const u16* __restrict__ Bt, int ldb,
    const float* __restrict__ bias, const u16* __restrict__ glu,
    void* __restrict__ C, int ldc, int K)
{
    __shared__ u16 As[2][64*64];
    __shared__ u16 Bs[2][128*64];
    int tid = threadIdx.x;
    int wave = tid >> 6, lane = tid & 63;
    int n16 = lane & 15, quad = lane >> 4;
    int D = blockIdx.y * gridDim.x + blockIdx.x;
    int nwg = gridDim.x * gridDim.y;
    int T = (D & 7) * (nwg >> 3) + (D >> 3);
    int m0 = (T / gridDim.x) * 64, n0 = (T % gridDim.x) * 128;
    int wm = wave >> 1, wn = wave & 1;

    f32x4 acc[2][4] = {};

    const u16* ga[2]; const u16* gb[4]; int sa[2], sb[4];
    #pragma unroll
    for (int i = 0; i < 2; ++i){
        int s = i*256 + tid;
        int row = s >> 3, g = (s & 7) ^ (row & 7);
        ga[i] = A + (size_t)(m0+row)*lda + g*8;
        sa[i] = s*8;
    }
    #pragma unroll
    for (int i = 0; i < 4; ++i){
        int s = i*256 + tid;
        int row = s >> 3, g = (s & 7) ^ (row & 7);
        gb[i] = Bt + (size_t)(n0+row)*ldb + g*8;
        sb[i] = s*8;
    }
    auto stage = [&](int slot, int k0){       // 6 glds16 per thread
        #pragma unroll
        for (int i = 0; i < 2; ++i) glds16(ga[i] + k0, &As[slot][sa[i]]);
        #pragma unroll
        for (int i = 0; i < 4; ++i) glds16(gb[i] + k0, &Bs[slot][sb[i]]);
    };

    int aoff[2][2], boff[2][4];
    #pragma unroll
    for (int ks = 0; ks < 2; ++ks){
        #pragma unroll
        for (int mi = 0; mi < 2; ++mi){
            int row = wm*32 + mi*16 + n16;
            aoff[ks][mi] = row*64 + (((ks*4 + quad) ^ (row & 7))*8);
        }
        #pragma unroll
        for (int ni = 0; ni < 4; ++ni){
            int row = wn*64 + ni*16 + n16;
            boff[ks][ni] = row*64 + (((ks*4 + quad) ^ (row & 7))*8);
        }
    }

    stage(0, 0);
    int NT = K >> 6;
    for (int t = 0; t < NT; ++t){
        int cur = t & 1;
        if (t + 1 < NT){
            stage(cur ^ 1, (t+1)*64);
            asm volatile("s_waitcnt vmcnt(6)" ::: "memory");
        } else {
            asm volatile("s_waitcnt vmcnt(0)" ::: "memory");
        }
        __builtin_amdgcn_s_barrier();
        __builtin_amdgcn_s_setprio(1);
        #pragma unroll
        for (int ks = 0; ks < 2; ++ks){
            short8 af[2], bf[4];
            #pragma unroll
            for (int mi = 0; mi < 2; ++mi)
                af[mi] = *(const short8*)&As[cur][aoff[ks][mi]];
            #pragma unroll
            for (int ni = 0; ni < 4; ++ni)
                bf[ni] = *(const short8*)&Bs[cur][boff[ks][ni]];
            #pragma unroll
            for (int mi = 0; mi < 2; ++mi)
                #pragma unroll
                for (int ni = 0; ni < 4; ++ni)
                    acc[mi][ni] = mfma16(af[mi], bf[ni], acc[mi][ni]);
        }
        __builtin_amdgcn_s_setprio(0);
        asm volatile("s_waitcnt lgkmcnt(0)" ::: "memory");
        __builtin_amdgcn_s_barrier();
    }

    #pragma unroll
    for (int mi = 0; mi < 2; ++mi){
        #pragma unroll
        for (int reg = 0; reg < 4; ++reg){
            int row = m0 + wm*32 + mi*16 + quad*4 + reg;
            #pragma unroll
            for (int ni = 0; ni < 4; ++ni){
                int col = n0 + wn*64 + ni*16 + n16;
                float v = acc[mi][ni][reg];
                if (bias) v += bias[col];
                if (EPI == 1) v = u2f(glu[(size_t)row*512 + col]) * fsigm(v);
                if (EPI == 2) ((float*)C)[(size_t)row*ldc + col] = v;
                else          ((u16*)C)[(size_t)row*ldc + col]  = f2u(v);
            }
        }
    }
}

// ------------------------------------------------------------------
// MFMA flash attention (S^T form), causal, dh=64, 8 heads.  PAIRED 64-row
// Q-tiles (qt = 31-p then p).  Double-buffered K/V LDS + async reg-staging,
// l via all-ones MFMA column, defer-max (THR=8, log2 domain).
__global__ __launch_bounds__(256) void flash_kernel(
    const u16* __restrict__ QK,   // [8192,1024]: cols 0..511 Q', 512..1023 K
    const u16* __restrict__ VT,   // [512,8192]
    u16* __restrict__ O)          // [8192,512]
{
    int bid = blockIdx.x;
    int p = bid >> 5;                  // 0..15
    int bh = bid & 31;
    int h = bh & 7, b = bh >> 3;
    __shared__ u16 Ks[2][64*64];
    __shared__ u16 Vt[2][64*64];
    __shared__ u16 Ps[4][16*64];
    int tid = threadIdx.x;
    int wave = tid >> 6, lane = tid & 63;
    int n16 = lane & 15, quad = lane >> 4;
    size_t btok = (size_t)b*2048;
    int r = tid >> 2;
    int g0 = (tid & 3) * 2;
    const short8 ones8 = {0x3F80,0x3F80,0x3F80,0x3F80,0x3F80,0x3F80,0x3F80,0x3F80};

    uint4 ka, kb, va, vb;              // in-flight K/V registers
    auto loadKV = [&](int kt){
        const uint4* kp = (const uint4*)&QK[(btok + kt*64 + r)*1024 + 512 + h*64 + g0*8];
        ka = kp[0]; kb = kp[1];
        const uint4* vp = (const uint4*)&VT[(size_t)(h*64 + r)*8192 + btok + kt*64 + g0*8];
        va = vp[0]; vb = vp[1];
    };
    auto writeKV = [&](int s){         // compiler inserts vmcnt wait (data dep)
        *(uint4*)&Ks[s][r*64 + ((g0  ) ^ (r&7))*8] = ka;
        *(uint4*)&Ks[s][r*64 + ((g0+1) ^ (r&7))*8] = kb;
        *(uint4*)&Vt[s][r*64 + ((g0  ) ^ (r&7))*8] = va;
        *(uint4*)&Vt[s][r*64 + ((g0+1) ^ (r&7))*8] = vb;
    };

    for (int ph = 0; ph < 2; ++ph){
        int qt = ph ? p : (31 - p);
        size_t tok0 = btok + qt*64;
        short8 qf[2];
        #pragma unroll
        for (int ks = 0; ks < 2; ++ks)
            qf[ks] = *(const short8*)&QK[(tok0 + wave*16 + n16)*1024
                                         + h*64 + ks*32 + quad*8];
        int qrow = qt*64 + wave*16 + n16;
        float m_st = -3.0e38f;
        f32x4 ov[5] = {};              // [0..3]=O accum, [4]=row-sum (l) accum

        loadKV(0);
        __syncthreads();               // prior ph's readers done with LDS
        writeKV(0);
        __syncthreads();               // slot 0 visible to all waves

        for (int kt = 0; kt <= qt; ++kt){
            int cur = kt & 1;
            if (kt < qt) loadKV(kt+1);         // issue early; lands under compute

            f32x4 st[4];
            #pragma unroll
            for (int ct = 0; ct < 4; ++ct){
                f32x4 a = {};
                #pragma unroll
                for (int ks = 0; ks < 2; ++ks){
                    short8 kf = *(const short8*)&Ks[cur][(ct*16+n16)*64 + (((ks*4+quad) ^ (n16&7))*8)];
                    a = mfma16(kf, qf[ks], a);
                }
                st[ct] = a;
            }
            if (kt == qt){                 // diagonal: causal mask
                #pragma unroll
                for (int ct = 0; ct < 4; ++ct){
                    int kb0 = kt*64 + ct*16 + quad*4;
                    #pragma unroll
                    for (int r4 = 0; r4 < 4; ++r4)
                        if (kb0 + r4 > qrow) st[ct][r4] = -3.0e38f;
                }
            }
            float mx = -3.0e38f;
            #pragma unroll
            for (int ct = 0; ct < 4; ++ct)
                #pragma unroll
                for (int r4 = 0; r4 < 4; ++r4) mx = fmaxf(mx, st[ct][r4]);
            mx = fmaxf(mx, __shfl_xor(mx, 16));
            mx = fmaxf(mx, __shfl_xor(mx, 32));
            // defer-max: only rescale when some row's max grew past the slack
            if (!__all(mx <= m_st + 8.f)){
                float mn = fmaxf(m_st, mx);
                float al = exp2f(m_st - mn);
                m_st = mn;
                #pragma unroll
                for (int r4 = 0; r4 < 4; ++r4){
                    float aa = __shfl(al, quad*4 + r4);
                    #pragma unroll
                    for (int dt = 0; dt < 5; ++dt) ov[dt][r4] *= aa;
                }
            }
            #pragma unroll
            for (int ct = 0; ct < 4; ++ct)
                #pragma unroll
                for (int r4 = 0; r4 < 4; ++r4)
                    st[ct][r4] = exp2f(st[ct][r4] - m_st);   // bounded by 2^8
            // P store: q-major rows (q = n16), packed b64, truncating cvt
            #pragma unroll
            for (int ct = 0; ct < 4; ++ct){
                ushort4 h4;
                h4.x = f2u_t(st[ct][0]); h4.y = f2u_t(st[ct][1]);
                h4.z = f2u_t(st[ct][2]); h4.w = f2u_t(st[ct][3]);
                int goff = ct*2 + (quad >> 1);
                *(ushort4*)&Ps[wave][n16*64 + ((goff ^ (n16&7))*8) + (quad&1)*4] = h4;
            }
            // O += P V ; l += P @ 1  (same-wave LDS write->read, program order)
            short8 ap[2];
            #pragma unroll
            for (int ks = 0; ks < 2; ++ks)
                ap[ks] = *(const short8*)&Ps[wave][n16*64 + (((ks*4+quad) ^ (n16&7))*8)];
            #pragma unroll
            for (int dt = 0; dt < 4; ++dt)
                #pragma unroll
                for (int ks = 0; ks < 2; ++ks){
                    short8 bv = *(const short8*)&Vt[cur][(dt*16+n16)*64 + (((ks*4+quad) ^ (n16&7))*8)];
                    ov[dt] = mfma16(ap[ks], bv, ov[dt]);
                }
            #pragma unroll
            for (int ks = 0; ks < 2; ++ks)
                ov[4] = mfma16(ap[ks], ones8, ov[4]);

            if (kt < qt) writeKV(cur ^ 1);     // vmcnt wait here, hidden by compute
            __syncthreads();                   // single barrier per k-tile
        }
        #pragma unroll
        for (int r4 = 0; r4 < 4; ++r4){
            float inv = __builtin_amdgcn_rcpf(ov[4][r4]);   // l in output-row layout
            size_t row = tok0 + wave*16 + quad*4 + r4;
            #pragma unroll
            for (int dt = 0; dt < 4; ++dt)
                O[row*512 + h*64 + dt*16 + n16] = f2u(ov[dt][r4] * inv);
        }
    }
}

// ------------------------------------------------------------------
// x1h = bf16( rmsnorm(x + y_bf16) * scale )
__global__ __launch_bounds__(256) void rmsnorm_kernel(
    const float* __restrict__ x, const u16* __restrict__ y,
    const float* __restrict__ scale, u16* __restrict__ out)
{
    int tok = blockIdx.x, tid = threadIdx.x;
    size_t base = (size_t)tok * 512;
    float v0 = x[base+tid]     + u2f(y[base+tid]);
    float v1 = x[base+tid+256] + u2f(y[base+tid+256]);
    float ss = v0*v0 + v1*v1;
    for (int off = 32; off; off >>= 1) ss += __shfl_down(ss, off);
    __shared__ float ws[4];
    if ((tid & 63) == 0) ws[tid >> 6] = ss;
    __syncthreads();
    float rstd = rsqrtf((ws[0]+ws[1]+ws[2]+ws[3])*(1.f/512.f) + 1e-6f);
    out[base+tid]     = f2u(scale[tid]     * v0 * rstd);
    out[base+tid+256] = f2u(scale[tid+256] * v1 * rstd);
}

// out_fp32 = rmsnorm(x1h + moe_f32 + ROUT@b2) * scale
__global__ __launch_bounds__(256) void final_kernel(
    const u16* __restrict__ x1, const float* __restrict__ moe,
    const float* __restrict__ rout, const float* __restrict__ b2,
    const float* __restrict__ scale, float* __restrict__ out)
{
    int tok = blockIdx.x, tid = threadIdx.x;
    size_t base = (size_t)tok * 512;
    float r0 = rout[tok*4+0], r1 = rout[tok*4+1], r2 = rout[tok*4+2], r3 = rout[tok*4+3];
    float bb0 = r0*b2[tid]     + r1*b2[512+tid]     + r2*b2[1024+tid]     + r3*b2[1536+tid];
    float bb1 = r0*b2[tid+256] + r1*b2[768+tid]     + r2*b2[1280+tid]     + r3*b2[1792+tid];
    float v0 = u2f(x1[base+tid])     + moe[base+tid]     + bb0;
    float v1 = u2f(x1[base+tid+256]) + moe[base+tid+256] + bb1;
    float ss = v0*v0 + v1*v1;
    for (int off = 32; off; off >>= 1) ss += __shfl_down(ss, off);
    __shared__ float ws[4];
    if ((tid & 63) == 0) ws[tid >> 6] = ss;
    __syncthreads();
    float rstd = rsqrtf((ws[0]+ws[1]+ws[2]+ws[3])*(1.f/512.f) + 1e-6f);
    out[base+tid]     = scale[tid]     * v0 * rstd;
    out[base+tid+256] = scale[tid+256] * v1 * rstd;
}

// router: softmax(x1h @ wr + br), one wave per token
__global__ __launch_bounds__(256) void router_kernel(
    const u16* __restrict__ x1, const float* __restrict__ wr,
    const float* __restrict__ br, float* __restrict__ rout)
{
    int wid = threadIdx.x >> 6, lane = threadIdx.x & 63;
    int tok = blockIdx.x*4 + wid;
    const u16* xp = x1 + (size_t)tok*512;
    float p0=0.f, p1=0.f, p2=0.f, p3=0.f;
    for (int d = lane; d < 512; d += 64){
        float xv = u2f(xp[d]);
        p0 += xv*wr[d*4+0]; p1 += xv*wr[d*4+1];
        p2 += xv*wr[d*4+2]; p3 += xv*wr[d*4+3];
    }
    for (int off = 32; off; off >>= 1){
        p0 += __shfl_down(p0,off); p1 += __shfl_down(p1,off);
        p2 += __shfl_down(p2,off); p3 += __shfl_down(p3,off);
    }
    if (lane == 0){
        p0 += br[0]; p1 += br[1]; p2 += br[2]; p3 += br[3];
        float mx = fmaxf(fmaxf(p0,p1), fmaxf(p2,p3));
        float e0=__expf(p0-mx), e1=__expf(p1-mx), e2=__expf(p2-mx), e3=__expf(p3-mx);
        float inv = 1.f/(e0+e1+e2+e3);
        rout[tok*4+0]=e0*inv; rout[tok*4+1]=e1*inv;
        rout[tok*4+2]=e2*inv; rout[tok*4+3]=e3*inv;
    }
}

// ------------------------------------------------------------------
extern "C" void kernel_launch(void* const* d_in, const int* in_sizes, int n_in,
                              void* d_out, int out_size, void* d_ws, size_t ws_size,
                              hipStream_t stream)
{
    const float* x    = (const float*)d_in[0];
    const float* mp_w = (const float*)d_in[3];
    const float* mp_b = (const float*)d_in[4];
    const float* fu_w = (const float*)d_in[5];
    const float* fu_b = (const float*)d_in[6];
    const float* wc   = (const float*)d_in[7];
    const float* wk   = (const float*)d_in[8];
    const float* wv   = (const float*)d_in[9];
    const float* wq   = (const float*)d_in[10];
    const float* wo   = (const float*)d_in[11];
    const float* s1   = (const float*)d_in[12];
    const float* s2   = (const float*)d_in[13];
    const float* wr   = (const float*)d_in[14];
    const float* br   = (const float*)d_in[15];
    const float* wg   = (const float*)d_in[16];
    const float* bg   = (const float*)d_in[17];
    const float* w1   = (const float*)d_in[18];
    const float* b1   = (const float*)d_in[19];
    const float* w2   = (const float*)d_in[20];
    const float* b2   = (const float*)d_in[21];

    char* wsb = (char*)d_ws;
    const size_t MB = 1024*1024;
    // persistent weights (0..12.3 MB)
    u16*   WqkvC  = (u16*)(wsb + 0);                 // [1536,1024]
    u16*   woT    = (u16*)(wsb + 3*MB);              // [512,512]
    u16*   wgT    = (u16*)(wsb + 3*MB + 512*1024);   // [512,512]
    u16*   w1T    = (u16*)(wsb + 4*MB);              // [4096,512]
    u16*   w2Ts   = (u16*)(wsb + 8*MB);              // [512,4096]
    float* fubias = (float*)(wsb + 12*MB);           // 512
    float* qkvbias= (float*)(wsb + 12*MB + 8192);    // 1536
    float* ROUT   = (float*)(wsb + 12*MB + 32768);   // 8192x4 (128 KB)
    // prepass scratch (dead before gatepool)
    u16*   wqkvT  = (u16*)(wsb + 12*MB + 512*1024);  // [1536,512] 12.5-14
    u16*   fuBT   = (u16*)(wsb + 16*MB);             // [512,512]
    u16*   mp_wB  = (u16*)(wsb + 16*MB + 512*1024);  // [512,512]
    u16*   WfuBF  = (u16*)(wsb + 17*MB);             // [1024,512]
    // rotating big buffers
    u16*   x1h   = (u16*)(wsb + 14*MB);              // 14-22, live till final
    u16*   XFcat = (u16*)(wsb + 16*MB);              // 16-32, dead after QKV
    u16*   XG    = (u16*)(wsb + 22*MB);              // 22-30, live through w1
    u16*   S3    = (u16*)(wsb + 24*MB);              // 24-32, dead after rmsnorm
    u16*   QKb   = (u16*)(wsb + 32*MB);              // 32-48, dead after flash
    float* MOE   = (float*)(wsb + 32*MB);            // 32-48 fp32 (MoE phase)
    u16*   VbT   = (u16*)(wsb + 48*MB);              // 48-56, dead after flash
    u16*   ATT   = (u16*)(wsb + 56*MB);              // 56-64, dead after wo
    u16*   Hb    = (u16*)(wsb + 48*MB);              // 48-112 contiguous [8192,4096] (MoE, big)
    u16*   HbA   = (u16*)(wsb + 48*MB);              // fallback path
    bool big = ws_size >= (size_t)112*MB;

    auto mg128 = [&](const u16* A, const u16* A2, int lda, const u16* Bt, int ldb,
                     const float* bias, const float* rs, const u16* glu,
                     void* C, void* CB, int ldc, u16* C2, int M, int N, int K, int flags){
        dim3 g(N/128, M/128);
        mgemm_kernel<128><<<g, 256, 0, stream>>>(A, A2, lda, Bt, ldb, bias, rs, glu,
                                                 C, CB, ldc, C2, K, flags);
    };
    auto mg64 = [&](const u16* A, const u16* A2, int lda, const u16* Bt, int ldb,
                    const float* bias, const float* rs, const u16* glu,
                    void* C, void* CB, int ldc, u16* C2, int M, int N, int K, int flags){
        dim3 g(N/128, M/64);
        mgemm_kernel<64><<<g, 256, 0, stream>>>(A, A2, lda, Bt, ldb, bias, rs, glu,
                                                C, CB, ldc, C2, K, flags);
    };

    // ---- prepass (re-run every call)
    TJobs JJ; JJ.n = 12;
    auto setj = [&](int i, const float* src, u16* dst, int K, int N, int ldout,
                    int coloff, float scale){
        JJ.j[i] = TJob{src, dst, K, N, ldout, coloff, (K/32)*(N/32), scale};
    };
    setj(0, wq,            wqkvT, 512,  512,  512, 0, QSCALE);   // Q' = wq*0.125*log2e
    setj(1, wo,            woT,   512,  512,  512, 0, 1.f);
    setj(2, wg,            wgT,   512,  512,  512, 0, 1.f);
    setj(3, fu_w + 512*512,fuBT,  512,  512,  512, 0, 1.f);      // fuB^T
    for (int e = 0; e < 4; ++e){
        setj(4+e, w1 + (size_t)e*512*1024, w1T + (size_t)e*1024*512, 512, 1024, 512, 0, 1.f);
        setj(8+e, w2 + (size_t)e*1024*512, w2Ts + (size_t)e*1024, 1024, 512, 4096, 0, 1.f);
    }
    int nt = 4*256 + 8*512;
    tconv_all_kernel<<<nt, 256, 0, stream>>>(JJ);
    convert_kernel<<<512*512/256, 256, 0, stream>>>(mp_w, mp_wB);
    convert_kernel<<<512*512/256, 256, 0, stream>>>(fu_w, WfuBF);            // fuA rows 0..511
    sgemm_kernel<<<dim3(8,8), 256, 0, stream>>>(wc, wk, wqkvT + 512*512, 32);  // Wck^T
    sgemm_kernel<<<dim3(8,8), 256, 0, stream>>>(wc, wv, wqkvT + 1024*512, 32); // Wcv^T
    biasfold_kernel<<<512, 256, 0, stream>>>(fu_b, mp_b, fu_w, fubias);
    qkvbias_kernel<<<1536, 256, 0, stream>>>(fubias, wqkvT, qkvbias);
    // F1 = mp_w @ fuB -> WfuBF rows 512..1023 (row-major bf16).  16 blocks.
    g128_kernel<0><<<dim3(4, 4), 256, 0, stream>>>(
        mp_wB, 512, fuBT, 512, nullptr, nullptr, WfuBF + 512*512, 512, nullptr, 512);
    // Combined: WqkvC[1536,1024] = wqkvT[1536,512] @ WfuBF[1024,512]^T.  96 blocks.
    g128_kernel<0><<<dim3(8, 12), 256, 0, stream>>>(
        wqkvT, 512, WfuBF, 512, nullptr, nullptr, WqkvC, 1024, nullptr, 512);

    // ---- main pipeline
    gatepool_kernel<<<(TOK/16)*512/256, 256, 0, stream>>>(x, XFcat);
    // QKV from XFcat (xfu folded): Q'|K -> QKb, V^T -> VbT.  768 blocks, 2/CU.
    g128_kernel<1><<<dim3(12, 64), 256, 0, stream>>>(
        XFcat, 1024, WqkvC, 1024, qkvbias, nullptr, QKb, 1024, VbT, 1024);
    flash_kernel<<<512, 256, 0, stream>>>(QKb, VbT, ATT);
    // attn@wo: 64x128 pipelined, 512 blocks
    gemm64p_kernel<0><<<dim3(4, 128), 256, 0, stream>>>(
        ATT, 512, woT, 512, nullptr, nullptr, S3, 512, 512);
    rmsnorm_kernel<<<TOK, 256, 0, stream>>>(x, S3, s1, x1h);                 // x1
    router_kernel<<<TOK/4, 256, 0, stream>>>(x1h, wr, br, ROUT);
    // xg = x1h * sigmoid(x1h@wg+bg): 64x128 pipelined
    gemm64p_kernel<1><<<dim3(4, 128), 256, 0, stream>>>(
        x1h, 512, wgT, 512, bg, x1h, XG, 512, 512);
    if (big){
        // w1: 256^2 pipelined BK=64 (r8 loop) + LDS-bounce epilogue.  512 blocks.
        gemm256_kernel<<<dim3(16, 32), 512, 0, stream>>>(
            XG, 512, w1T, 512, b1, ROUT, Hb, 4096, 512);
        // w2: 64x128 pipelined, M=8192, N=512, K=4096.  512 blocks.
        gemm64p_kernel<2><<<dim3(4, 128), 256, 0, stream>>>(
            Hb, 4096, w2Ts, 4096, nullptr, nullptr, MOE, 512, 4096);
    } else {
        // fallback (r6 structure): pairwise experts, Hb = HbA [8192,2048]
        for (int p = 0; p < 2; ++p){
            mg128(XG, XG + (size_t)MSPLIT*512, 512, w1T + (size_t)p*2048*512, 512,
                  b1 + p*2048, ROUT + p*2, 0,
                  HbA, HbA + (size_t)MSPLIT*2048, 2048, 0,
                  TOK, 2048, 512, GF_GELU | GF_RSCOL);
            mg64 (HbA, HbA + (size_t)MSPLIT*2048, 2048, w2Ts + p*2048, 4096, 0, 0, 0,
                  MOE, (float*)MOE + (size_t)MSPLIT*512, 512, 0,
                  TOK, 512, 2048, p ? GF_ACCUM : GF_F32OUT);
        }
    }
    final_kernel<<<TOK, 256, 0, stream>>>(x1h, MOE, ROUT, b2, s2, (float*)d_out);
}

// Round 11
// 414.329 us; speedup vs baseline: 1.4901x; 1.0042x over previous
//
#include <hip/hip_runtime.h>
#include <math.h>

#define B_   4
#define T_   2048
#define D_   512
#define TOK  (B_*T_)      // 8192 tokens
#define TL_  2045         // N_BLOCKS*(T//N_BLOCKS) = 5*409
#define GATE 0.2f         // softmax(...).mean(-1) over same axis == 1/5
#define QSCALE 0.18033688011112043f   // 0.125 * log2(e): S in log2 domain
#define MSPLIT 4096

typedef unsigned short u16;
typedef __attribute__((ext_vector_type(8))) short short8;   // 8 bf16 = 4 VGPRs
typedef __attribute__((ext_vector_type(4))) float f32x4;

static __device__ __forceinline__ u16 f2u(float f){      // fp32 -> bf16 (RNE)
    union { float f; unsigned u; } a; a.f = f;
    unsigned r = a.u + 0x7fffu + ((a.u >> 16) & 1u);
    return (u16)(r >> 16);
}
static __device__ __forceinline__ u16 f2u_t(float f){    // truncating (P >= 0)
    return (u16)(__float_as_uint(f) >> 16);
}
static __device__ __forceinline__ float u2f(u16 u){
    union { unsigned u; float f; } a; a.u = ((unsigned)u) << 16;
    return a.f;
}
static __device__ __forceinline__ f32x4 mfma16(short8 a, short8 b, f32x4 c){
    return __builtin_amdgcn_mfma_f32_16x16x32_bf16(a, b, c, 0, 0, 0);
}
static __device__ __forceinline__ void glds16(const u16* g, u16* l){
    __builtin_amdgcn_global_load_lds((const __attribute__((address_space(1))) void*)g,
                                     (__attribute__((address_space(3))) void*)l, 16, 0, 0);
}
// fast GELU (tanh form): hw v_exp_f32 + v_rcp_f32 (no precise-divide sequence).
static __device__ __forceinline__ float fgelu(float x){
    float u = x * (1.f + 0.044715f * x * x);
    return x * __builtin_amdgcn_rcpf(1.f + exp2f(-2.3021193f * u));
}
static __device__ __forceinline__ float fsigm(float x){  // sigmoid via rcp
    return __builtin_amdgcn_rcpf(1.f + __expf(-x));
}

// ------------------------------------------------------------------
// gate + pool fused: XFcat[:,0:512]=bf16(0.2*x masked), XFcat[:,512:]=bf16(pool)
__global__ __launch_bounds__(256) void gatepool_kernel(
    const float* __restrict__ x, u16* __restrict__ xfcat)
{
    int idx = blockIdx.x*256 + threadIdx.x;
    int d = idx & 511, g = idx >> 9;
    int b = g >> 7, t0 = (g & 127) << 4;
    const float* xp = x + ((size_t)b*2048)*512 + d;
    float v[30];
    #pragma unroll
    for (int j = 0; j < 30; ++j){
        int u = t0 - 7 + j;
        v[j] = (u >= 0 && u < TL_) ? xp[(size_t)u*512] : 0.f;
    }
    float p[31]; p[0] = 0.f;
    #pragma unroll
    for (int j = 0; j < 30; ++j) p[j+1] = p[j] + v[j];
    u16* xc = xfcat + ((size_t)(b*2048 + t0))*1024 + d;
    #pragma unroll
    for (int i = 0; i < 16; ++i){
        int t = t0 + i;
        float sum = p[i+15] - p[i];                 // u in [t-7, t+7]
        int lo = t-7; if (lo < 0) lo = 0;
        int hi = t+7; if (hi > 2047) hi = 2047;
        xc[(size_t)i*1024]       = f2u((t < TL_) ? GATE*v[i+7] : 0.f);
        xc[(size_t)i*1024 + 512] = f2u(GATE * sum / (float)(hi - lo + 1));
    }
}

// ------------------------------------------------------------------
// batched transpose+convert: src fp32 [K,N] -> dst[n*ldout+coloff+k]=bf16(scale*src)
struct TJob { const float* src; u16* dst; int K, N, ldout, coloff, tiles; float scale; };
struct TJobs { TJob j[13]; int n; };

__global__ __launch_bounds__(256) void tconv_all_kernel(TJobs JJ){
    __shared__ float t[32][33];
    int idx = blockIdx.x;
    int jb = 0;
    while (jb < JJ.n - 1 && idx >= JJ.j[jb].tiles){ idx -= JJ.j[jb].tiles; ++jb; }
    TJob J = JJ.j[jb];
    int tX = J.N >> 5;
    int k0 = (idx / tX) * 32, n0 = (idx % tX) * 32;
    int tx = threadIdx.x & 31, ty = threadIdx.x >> 5;
    #pragma unroll
    for (int i = 0; i < 32; i += 8)
        t[ty+i][tx] = J.src[(size_t)(k0+ty+i)*J.N + n0+tx];
    __syncthreads();
    #pragma unroll
    for (int i = 0; i < 32; i += 8)
        J.dst[(size_t)(n0+ty+i)*J.ldout + J.coloff + k0+tx] = f2u(J.scale * t[tx][ty+i]);
}

// fp32 -> bf16 plain convert
__global__ void convert_kernel(const float* __restrict__ in, u16* __restrict__ out){
    int idx = blockIdx.x*256 + threadIdx.x;
    out[idx] = f2u(in[idx]);
}

// fubias[n] = fu_b[n] + sum_d mp_b[d] * fu_w[512+d][n]
__global__ __launch_bounds__(256) void biasfold_kernel(
    const float* __restrict__ fu_b, const float* __restrict__ mp_b,
    const float* __restrict__ fu_w, float* __restrict__ out)
{
    int n = blockIdx.x, tid = threadIdx.x;
    float s = mp_b[tid]*fu_w[(size_t)(512+tid)*512 + n]
            + mp_b[tid+256]*fu_w[(size_t)(768+tid)*512 + n];
    for (int off = 32; off; off >>= 1) s += __shfl_down(s, off);
    __shared__ float ws[4];
    if ((tid & 63) == 0) ws[tid >> 6] = s;
    __syncthreads();
    if (tid == 0) out[n] = fu_b[n] + ws[0]+ws[1]+ws[2]+ws[3];
}

// qkvbias[n] = sum_d fubias[d] * wqkvT[n][d]
__global__ __launch_bounds__(256) void qkvbias_kernel(
    const float* __restrict__ fubias, const u16* __restrict__ wqkvT,
    float* __restrict__ out)
{
    int n = blockIdx.x, tid = threadIdx.x;
    const u16* wp = wqkvT + (size_t)n*512;
    float s = fubias[tid]*u2f(wp[tid]) + fubias[tid+256]*u2f(wp[tid+256]);
    for (int off = 32; off; off >>= 1) s += __shfl_down(s, off);
    __shared__ float ws[4];
    if ((tid & 63) == 0) ws[tid >> 6] = s;
    __syncthreads();
    if (tid == 0) out[n] = ws[0]+ws[1]+ws[2]+ws[3];
}

// small fp32 GEMM, N=512, writes bf16 TRANSPOSED: dstT[n*512 + m] = (A@B)[m][n]
__global__ __launch_bounds__(256) void sgemm_kernel(const float* __restrict__ A,
    const float* __restrict__ B, u16* __restrict__ dstT, int K){
    __shared__ float As[16][65];
    __shared__ float Bs[16][65];
    int tid = threadIdx.x;
    int tx = tid & 15, ty = tid >> 4;
    int m0 = blockIdx.y*64, n0 = blockIdx.x*64;
    int arow = tid >> 2, akq = (tid & 3) * 4;
    int bk = tid >> 4, bn = (tid & 15) * 4;
    float acc[4][4] = {};
    for (int k0 = 0; k0 < K; k0 += 16){
        const float* Ap = A + (size_t)(m0+arow)*K + k0 + akq;
        As[akq+0][arow]=Ap[0]; As[akq+1][arow]=Ap[1];
        As[akq+2][arow]=Ap[2]; As[akq+3][arow]=Ap[3];
        const float* Bp = B + (size_t)(k0+bk)*512 + n0 + bn;
        Bs[bk][bn+0]=Bp[0]; Bs[bk][bn+1]=Bp[1];
        Bs[bk][bn+2]=Bp[2]; Bs[bk][bn+3]=Bp[3];
        __syncthreads();
        #pragma unroll
        for (int kk = 0; kk < 16; ++kk){
            float av[4], bv[4];
            #pragma unroll
            for (int i=0;i<4;++i) av[i]=As[kk][ty*4+i];
            #pragma unroll
            for (int j=0;j<4;++j) bv[j]=Bs[kk][tx*4+j];
            #pragma unroll
            for (int i=0;i<4;++i)
                #pragma unroll
                for (int j=0;j<4;++j) acc[i][j] += av[i]*bv[j];
        }
        __syncthreads();
    }
    #pragma unroll
    for (int i=0;i<4;++i)
        #pragma unroll
        for (int j=0;j<4;++j)
            dstT[(size_t)(n0+tx*4+j)*512 + m0+ty*4+i] = f2u(acc[i][j]);
}

// ------------------------------------------------------------------
// bf16 MFMA GEMM: legacy 2-barrier structure (small-workspace fallback only)
#define GF_GELU   1
#define GF_ACCUM  2
#define GF_RSCOL  4
#define GF_GLU    8
#define GF_F32OUT 16
#define GF_QKV    32

template<int MT>
__global__ __launch_bounds__(256) void mgemm_kernel(
    const u16* __restrict__ A, const u16* __restrict__ A2, int lda,
    const u16* __restrict__ Bt, int ldb,
    const float* __restrict__ bias, const float* __restrict__ rs,
    const u16* __restrict__ glu, void* __restrict__ Cp, void* __restrict__ CpB,
    int ldc, u16* __restrict__ Cp2, int K, int flags)
{
    constexpr int MI = MT/32;            // m-tiles per wave (16 rows each)
    __shared__ u16 As[MT*64];
    __shared__ u16 Bs[128*64];
    int tid = threadIdx.x;
    int wave = tid >> 6, lane = tid & 63;
    int n16 = lane & 15, quad = lane >> 4;
    int m0 = blockIdx.y * MT, n0 = blockIdx.x * 128;
    int wr = (wave >> 1) * (MT/2), wc = (wave & 1) * 64;

    f32x4 acc[MI][4] = {};

    for (int k0 = 0; k0 < K; k0 += 64){
        #pragma unroll
        for (int i = 0; i < MT/32; ++i){
            int s = i*256 + tid;
            int row = s >> 3, g = (s & 7) ^ (row & 7);
            int rg = m0 + row;
            const u16* Ap = (rg < MSPLIT) ? A + (size_t)rg*lda
                                          : A2 + (size_t)(rg - MSPLIT)*lda;
            glds16(Ap + k0 + g*8, As + (size_t)s*8);
        }
        #pragma unroll
        for (int i = 0; i < 4; ++i){
            int s = i*256 + tid;
            int row = s >> 3, g = (s & 7) ^ (row & 7);
            glds16(Bt + (size_t)(n0+row)*ldb + k0 + g*8, Bs + (size_t)s*8);
        }
        __syncthreads();
        #pragma unroll
        for (int ks = 0; ks < 2; ++ks){
            short8 af[MI], bf[4];
            #pragma unroll
            for (int mi = 0; mi < MI; ++mi){
                int row = wr + mi*16 + n16;
                int g = (ks*4 + quad) ^ (row & 7);
                af[mi] = *(const short8*)&As[row*64 + g*8];
            }
            #pragma unroll
            for (int ni = 0; ni < 4; ++ni){
                int row = wc + ni*16 + n16;
                int g = (ks*4 + quad) ^ (row & 7);
                bf[ni] = *(const short8*)&Bs[row*64 + g*8];
            }
            #pragma unroll
            for (int mi = 0; mi < MI; ++mi)
                #pragma unroll
                for (int ni = 0; ni < 4; ++ni)
                    acc[mi][ni] = mfma16(af[mi], bf[ni], acc[mi][ni]);
        }
        __syncthreads();
    }

    if ((flags & GF_QKV) && n0 >= 1024){
        #pragma unroll
        for (int mi = 0; mi < MI; ++mi){
            int row0 = m0 + wr + mi*16 + quad*4;
            #pragma unroll
            for (int ni = 0; ni < 4; ++ni){
                int col = n0 + wc + ni*16 + n16;
                float bb = bias[col];
                ushort4 h4;
                h4.x = f2u(acc[mi][ni][0] + bb); h4.y = f2u(acc[mi][ni][1] + bb);
                h4.z = f2u(acc[mi][ni][2] + bb); h4.w = f2u(acc[mi][ni][3] + bb);
                *(ushort4*)&Cp2[(size_t)(col-1024)*8192 + row0] = h4;
            }
        }
        return;
    }

    #pragma unroll
    for (int mi = 0; mi < MI; ++mi){
        #pragma unroll
        for (int reg = 0; reg < 4; ++reg){
            int row = m0 + wr + mi*16 + quad*4 + reg;
            void*  cb = (row < MSPLIT) ? Cp : CpB;
            size_t rr = (row < MSPLIT) ? row : row - MSPLIT;
            #pragma unroll
            for (int ni = 0; ni < 4; ++ni){
                int col = n0 + wc + ni*16 + n16;
                float v = acc[mi][ni][reg];
                if (bias) v += bias[col];
                if (flags & GF_GELU)  v = fgelu(v);
                if (flags & GF_GLU)   v = u2f(glu[(size_t)row*512 + col]) * fsigm(v);
                if (flags & GF_RSCOL) v *= rs[(size_t)row*4 + (col >> 10)];
                size_t ci = rr*ldc + col;
                if (flags & GF_ACCUM)       ((float*)cb)[ci] += v;
                else if (flags & GF_F32OUT) ((float*)cb)[ci]  = v;
                else                        ((u16*)cb)[ci]    = f2u(v);
            }
        }
    }
}

// ------------------------------------------------------------------
// 256x256-tile pipelined bf16 GEMM (w1), SINGLE-barrier counted loop + XCD
// swizzle.  Per K-step: vmcnt(0) [own slot loads] -> barrier [slot complete
// for all; prev readers retired] -> stage(next) -> ds_read+MFMA -> lgkmcnt(0).
// One barrier convergence per K-step instead of two (m233: stage+vmcnt+
// barrier is the dominant 2-phase overhead).  r8 scalar epilogue.
__global__ __launch_bounds__(512, 2) void gemm256_kernel(
    const u16* __restrict__ A, int lda,
    const u16* __restrict__ Bt, int ldb,
    const float* __restrict__ bias, const float* __restrict__ rs,
    u16* __restrict__ C, int ldc, int K)
{
    __shared__ u16 As[2][256*64];
    __shared__ u16 Bs[2][256*64];
    int tid = threadIdx.x;
    int wave = tid >> 6, lane = tid & 63;
    int n16 = lane & 15, quad = lane >> 4;
    int D = blockIdx.y * gridDim.x + blockIdx.x;
    int nwg = gridDim.x * gridDim.y;
    int T = (D & 7) * (nwg >> 3) + (D >> 3);
    int m0 = (T / gridDim.x) * 256, n0 = (T % gridDim.x) * 256;
    int wm = wave >> 2, wn = wave & 3;        // 2 x 4 wave grid, wave tile 128x64

    f32x4 acc[8][4] = {};

    const u16* ga[4]; const u16* gb[4]; int sa[4];
    #pragma unroll
    for (int i = 0; i < 4; ++i){
        int s = i*512 + tid;
        int row = s >> 3, g = (s & 7) ^ (row & 7);
        ga[i] = A  + (size_t)(m0+row)*lda + g*8;
        gb[i] = Bt + (size_t)(n0+row)*ldb + g*8;
        sa[i] = s*8;
    }
    auto stage = [&](int slot, int k0){       // 8 glds16 per thread
        #pragma unroll
        for (int i = 0; i < 4; ++i) glds16(ga[i] + k0, &As[slot][sa[i]]);
        #pragma unroll
        for (int i = 0; i < 4; ++i) glds16(gb[i] + k0, &Bs[slot][sa[i]]);
    };

    int aoff[2][8], boff[2][4];
    #pragma unroll
    for (int ks = 0; ks < 2; ++ks){
        #pragma unroll
        for (int mi = 0; mi < 8; ++mi){
            int row = wm*128 + mi*16 + n16;
            aoff[ks][mi] = row*64 + (((ks*4 + quad) ^ (row & 7))*8);
        }
        #pragma unroll
        for (int ni = 0; ni < 4; ++ni){
            int row = wn*64 + ni*16 + n16;
            boff[ks][ni] = row*64 + (((ks*4 + quad) ^ (row & 7))*8);
        }
    }

    stage(0, 0);
    int NT = K >> 6;
    for (int t = 0; t < NT; ++t){
        int cur = t & 1;
        asm volatile("s_waitcnt vmcnt(0)" ::: "memory");   // own loads of slot cur
        __builtin_amdgcn_s_barrier();                      // slot cur complete for all
        if (t + 1 < NT) stage(cur ^ 1, (t+1)*64);          // safe: prev readers retired
        __builtin_amdgcn_s_setprio(1);
        #pragma unroll
        for (int ks = 0; ks < 2; ++ks){
            short8 af[8], bf[4];
            #pragma unroll
            for (int mi = 0; mi < 8; ++mi)
                af[mi] = *(const short8*)&As[cur][aoff[ks][mi]];
            #pragma unroll
            for (int ni = 0; ni < 4; ++ni)
                bf[ni] = *(const short8*)&Bs[cur][boff[ks][ni]];
            #pragma unroll
            for (int mi = 0; mi < 8; ++mi)
                #pragma unroll
                for (int ni = 0; ni < 4; ++ni)
                    acc[mi][ni] = mfma16(af[mi], bf[ni], acc[mi][ni]);
        }
        __builtin_amdgcn_s_setprio(0);
        asm volatile("s_waitcnt lgkmcnt(0)" ::: "memory"); // reads retired pre-barrier
    }

    float bb[4];
    #pragma unroll
    for (int ni = 0; ni < 4; ++ni)
        bb[ni] = bias ? bias[n0 + wn*64 + ni*16 + n16] : 0.f;

    int e = n0 >> 10;   // expert id; 256-tile never crosses a 1024 boundary
    #pragma unroll
    for (int mi = 0; mi < 8; ++mi){
        #pragma unroll
        for (int reg = 0; reg < 4; ++reg){
            int row = m0 + wm*128 + mi*16 + quad*4 + reg;
            float rv = rs[(size_t)row*4 + e];
            #pragma unroll
            for (int ni = 0; ni < 4; ++ni){
                int col = n0 + wn*64 + ni*16 + n16;
                float v = acc[mi][ni][reg] + bb[ni];
                v = fgelu(v) * rv;
                C[(size_t)row*ldc + col] = f2u(v);
            }
        }
    }
}

// ------------------------------------------------------------------
// 128x128-tile pipelined bf16 GEMM, SINGLE-barrier counted loop + XCD swizzle.
// EPI=0: (+bias) bf16 (prepass / generic).
// EPI=1: QKV (n0<1024: bias bf16 -> C; n0>=1024: bias + transpose -> C2).
template<int EPI>
__global__ __launch_bounds__(256, 2) void g128_kernel(
    const u16* __restrict__ A, int lda,
    const u16* __restrict__ Bt, int ldb,
    const float* __restrict__ bias, const float* __restrict__ rs,
    u16* __restrict__ C, int ldc, u16* __restrict__ C2, int K)
{
    __shared__ u16 As[2][128*64];
    __shared__ u16 Bs[2][128*64];
    int tid = threadIdx.x;
    int wave = tid >> 6, lane = tid & 63;
    int n16 = lane & 15, quad = lane >> 4;
    int D = blockIdx.y * gridDim.x + blockIdx.x;
    int nwg = gridDim.x * gridDim.y;
    int T = (nwg % 8 == 0) ? ((D & 7) * (nwg >> 3) + (D >> 3)) : D;
    int m0 = (T / gridDim.x) * 128, n0 = (T % gridDim.x) * 128;
    int wm = wave >> 1, wn = wave & 1;

    f32x4 acc[4][4] = {};

    const u16* ga[4]; const u16* gb[4]; int sa[4];
    #pragma unroll
    for (int i = 0; i < 4; ++i){
        int s = i*256 + tid;
        int row = s >> 3, g = (s & 7) ^ (row & 7);
        ga[i] = A  + (size_t)(m0+row)*lda + g*8;
        gb[i] = Bt + (size_t)(n0+row)*ldb + g*8;
        sa[i] = s*8;
    }
    auto stage = [&](int slot, int k0){       // 8 glds16 per thread
        #pragma unroll
        for (int i = 0; i < 4; ++i) glds16(ga[i] + k0, &As[slot][sa[i]]);
        #pragma unroll
        for (int i = 0; i < 4; ++i) glds16(gb[i] + k0, &Bs[slot][sa[i]]);
    };

    int aoff[2][4], boff[2][4];
    #pragma unroll
    for (int ks = 0; ks < 2; ++ks){
        #pragma unroll
        for (int mi = 0; mi < 4; ++mi){
            int row = wm*64 + mi*16 + n16;
            aoff[ks][mi] = row*64 + (((ks*4 + quad) ^ (row & 7))*8);
        }
        #pragma unroll
        for (int ni = 0; ni < 4; ++ni){
            int row = wn*64 + ni*16 + n16;
            boff[ks][ni] = row*64 + (((ks*4 + quad) ^ (row & 7))*8);
        }
    }

    stage(0, 0);
    int NT = K >> 6;
    for (int t = 0; t < NT; ++t){
        int cur = t & 1;
        asm volatile("s_waitcnt vmcnt(0)" ::: "memory");
        __builtin_amdgcn_s_barrier();
        if (t + 1 < NT) stage(cur ^ 1, (t+1)*64);
        __builtin_amdgcn_s_setprio(1);
        #pragma unroll
        for (int ks = 0; ks < 2; ++ks){
            short8 af[4], bf[4];
            #pragma unroll
            for (int mi = 0; mi < 4; ++mi)
                af[mi] = *(const short8*)&As[cur][aoff[ks][mi]];
            #pragma unroll
            for (int ni = 0; ni < 4; ++ni)
                bf[ni] = *(const short8*)&Bs[cur][boff[ks][ni]];
            #pragma unroll
            for (int mi = 0; mi < 4; ++mi)
                #pragma unroll
                for (int ni = 0; ni < 4; ++ni)
                    acc[mi][ni] = mfma16(af[mi], bf[ni], acc[mi][ni]);
        }
        __builtin_amdgcn_s_setprio(0);
        asm volatile("s_waitcnt lgkmcnt(0)" ::: "memory");
    }

    if (EPI == 1 && n0 >= 1024){
        #pragma unroll
        for (int mi = 0; mi < 4; ++mi){
            int row0 = m0 + wm*64 + mi*16 + quad*4;
            #pragma unroll
            for (int ni = 0; ni < 4; ++ni){
                int col = n0 + wn*64 + ni*16 + n16;
                float bb = bias[col];
                ushort4 h4;
                h4.x = f2u(acc[mi][ni][0] + bb); h4.y = f2u(acc[mi][ni][1] + bb);
                h4.z = f2u(acc[mi][ni][2] + bb); h4.w = f2u(acc[mi][ni][3] + bb);
                *(ushort4*)&C2[(size_t)(col-1024)*8192 + row0] = h4;
            }
        }
        return;
    }

    float bb[4];
    #pragma unroll
    for (int ni = 0; ni < 4; ++ni)
        bb[ni] = bias ? bias[n0 + wn*64 + ni*16 + n16] : 0.f;

    #pragma unroll
    for (int mi = 0; mi < 4; ++mi){
        #pragma unroll
        for (int reg = 0; reg < 4; ++reg){
            int row = m0 + wm*64 + mi*16 + quad*4 + reg;
            #pragma unroll
            for (int ni = 0; ni < 4; ++ni){
                int col = n0 + wn*64 + ni*16 + n16;
                float v = acc[mi][ni][reg] + bb[ni];
                C[(size_t)row*ldc + col] = f2u(v);
            }
        }
    }
}

// ------------------------------------------------------------------
// 64x128-tile pipelined bf16 GEMM, SINGLE-barrier counted loop + XCD swizzle.
// EPI=0: plain bf16 out (wo).  EPI=1: bias+GLU -> bf16 (wg).  EPI=2: fp32 (w2).
template<int EPI>
__global__ __launch_bounds__(256, 2) void gemm64p_kernel(
    const u16* __restrict__ A, int lda,
    const u16* __restrict__ Bt, int ldb,
    const float* __restrict__ bias, const u16* __restrict__ glu,
    void* __restrict__ C, int ldc, int K)
{
    __shared__ u16 As[2][64*64];
    __shared__ u16 Bs[2][128*64];
    int tid = threadIdx.x;
    int wave = tid >> 6, lane = tid & 63;
    int n16 = lane & 15, quad = lane >> 4;
    int D = blockIdx.y * gridDim.x + blockIdx.x;
    int nwg = gridDim.x * gridDim.y;
    int T = (D & 7) * (nwg >> 3) + (D >> 3);
    int m0 = (T / gridDim.x) * 64, n0 = (T % gridDim.x) * 128;
    int wm = wave >> 1, wn = wave & 1;

    f32x4 acc[2][4] = {};

    const u16* ga[2]; const u16* gb[4]; int sa[2], sb[4];
    #pragma unroll
    for (int i = 0; i < 2; ++i){
        int s = i*256 + tid;
        int row = s >> 3, g = (s & 7) ^ (row & 7);
        ga[i] = A + (size_t)(m0+row)*lda + g*8;
        sa[i] = s*8;
    }
    #pragma unroll
    for (int i = 0; i < 4; ++i){
        int s = i*256 + tid;
        int row = s >> 3, g = (s & 7) ^ (row & 7);
        gb[i] = Bt + (size_t)(n0+row)*ldb + g*8;
        sb[i] = s*8;
    }
    auto stage = [&](int slot, int k0){       // 6 glds16 per thread
        #pragma unroll
        for (int i = 0; i < 2; ++i) glds16(ga[i] + k0, &As[slot][sa[i]]);
        #pragma unroll
        for (int i = 0; i < 4; ++i) glds16(gb[i] + k0, &Bs[slot][sb[i]]);
    };

    int aoff[2][2], boff[2][4];
    #pragma unroll
    for (int ks = 0; ks < 2; ++ks){
        #pragma unroll
        for (int mi = 0; mi < 2; ++mi){
            int row = wm*32 + mi*16 + n16;
            aoff[ks][mi] = row*64 + (((ks*4 + quad) ^ (row & 7))*8);
        }
        #pragma unroll
        for (int ni = 0; ni < 4; ++ni){
            int row = wn*64 + ni*16 + n16;
            boff[ks][ni] = row*64 + (((ks*4 + quad) ^ (row & 7))*8);
        }
    }

    stage(0, 0);
    int NT = K >> 6;
    for (int t = 0; t < NT; ++t){
        int cur = t & 1;
        asm volatile("s_waitcnt vmcnt(0)" ::: "memory");
        __builtin_amdgcn_s_barrier();
        if (t + 1 < NT) stage(cur ^ 1, (t+1)*64);
        __builtin_amdgcn_s_setprio(1);
        #pragma unroll
        for (int ks = 0; ks < 2; ++ks){
            short8 af[2], bf[4];
            #pragma unroll
            for (int mi = 0; mi < 2; ++mi)
                af[mi] = *(const short8*)&As[cur][aoff[ks][mi]];
            #pragma unroll
            for (int ni = 0; ni < 4; ++ni)
                bf[ni] = *(const short8*)&Bs[cur][boff[ks][ni]];
            #pragma unroll
            for (int mi = 0; mi < 2; ++mi)
                #pragma unroll
                for (int ni = 0; ni < 4; ++ni)
                    acc[mi][ni] = mfma16(af[mi], bf[ni], acc[mi][ni]);
        }
        __builtin_amdgcn_s_setprio(0);
        asm volatile("s_waitcnt lgkmcnt(0)" ::: "memory");
    }

    #pragma unroll
    for (int mi = 0; mi < 2; ++mi){
        #pragma unroll
        for (int reg = 0; reg < 4; ++reg){
            int row = m0 + wm*32 + mi*16 + quad*4 + reg;
            #pragma unroll
            for (int ni = 0; ni < 4; ++ni){
                int col = n0 + wn*64 + ni*16 + n16;
                float v = acc[mi][ni][reg];
                if (bias) v += bias[col];
                if (EPI == 1) v = u2f(glu[(size_t)row*512 + col]) * fsigm(v);
                if (EPI == 2) ((float*)C)[(size_t)row*ldc + col] = v;
                else          ((u16*)C)[(size_t)row*ldc + col]  = f2u(v);
            }
        }
    }
}

// ------------------------------------------------------------------
// MFMA flash attention (S^T form), causal, dh=64, 8 heads.  PAIRED 64-row
// Q-tiles (qt = 31-p then p).  Double-buffered K/V LDS + async reg-staging,
// l via all-ones MFMA column, defer-max (THR=8, log2 domain).
__global__ __launch_bounds__(256) void flash_kernel(
    const u16* __restrict__ QK,   // [8192,1024]: cols 0..511 Q', 512..1023 K
    const u16* __restrict__ VT,   // [512,8192]
    u16* __restrict__ O)          // [8192,512]
{
    int bid = blockIdx.x;
    int p = bid >> 5;                  // 0..15
    int bh = bid & 31;
    int h = bh & 7, b = bh >> 3;
    __shared__ u16 Ks[2][64*64];
    __shared__ u16 Vt[2][64*64];
    __shared__ u16 Ps[4][16*64];
    int tid = threadIdx.x;
    int wave = tid >> 6, lane = tid & 63;
    int n16 = lane & 15, quad = lane >> 4;
    size_t btok = (size_t)b*2048;
    int r = tid >> 2;
    int g0 = (tid & 3) * 2;
    const short8 ones8 = {0x3F80,0x3F80,0x3F80,0x3F80,0x3F80,0x3F80,0x3F80,0x3F80};

    uint4 ka, kb, va, vb;              // in-flight K/V registers
    auto loadKV = [&](int kt){
        const uint4* kp = (const uint4*)&QK[(btok + kt*64 + r)*1024 + 512 + h*64 + g0*8];
        ka = kp[0]; kb = kp[1];
        const uint4* vp = (const uint4*)&VT[(size_t)(h*64 + r)*8192 + btok + kt*64 + g0*8];
        va = vp[0]; vb = vp[1];
    };
    auto writeKV = [&](int s){         // compiler inserts vmcnt wait (data dep)
        *(uint4*)&Ks[s][r*64 + ((g0  ) ^ (r&7))*8] = ka;
        *(uint4*)&Ks[s][r*64 + ((g0+1) ^ (r&7))*8] = kb;
        *(uint4*)&Vt[s][r*64 + ((g0  ) ^ (r&7))*8] = va;
        *(uint4*)&Vt[s][r*64 + ((g0+1) ^ (r&7))*8] = vb;
    };

    for (int ph = 0; ph < 2; ++ph){
        int qt = ph ? p : (31 - p);
        size_t tok0 = btok + qt*64;
        short8 qf[2];
        #pragma unroll
        for (int ks = 0; ks < 2; ++ks)
            qf[ks] = *(const short8*)&QK[(tok0 + wave*16 + n16)*1024
                                         + h*64 + ks*32 + quad*8];
        int qrow = qt*64 + wave*16 + n16;
        float m_st = -3.0e38f;
        f32x4 ov[5] = {};              // [0..3]=O accum, [4]=row-sum (l) accum

        loadKV(0);
        __syncthreads();               // prior ph's readers done with LDS
        writeKV(0);
        __syncthreads();               // slot 0 visible to all waves

        for (int kt = 0; kt <= qt; ++kt){
            int cur = kt & 1;
            if (kt < qt) loadKV(kt+1);         // issue early; lands under compute

            f32x4 st[4];
            #pragma unroll
            for (int ct = 0; ct < 4; ++ct){
                f32x4 a = {};
                #pragma unroll
                for (int ks = 0; ks < 2; ++ks){
                    short8 kf = *(const short8*)&Ks[cur][(ct*16+n16)*64 + (((ks*4+quad) ^ (n16&7))*8)];
                    a = mfma16(kf, qf[ks], a);
                }
                st[ct] = a;
            }
            if (kt == qt){                 // diagonal: causal mask
                #pragma unroll
                for (int ct = 0; ct < 4; ++ct){
                    int kb0 = kt*64 + ct*16 + quad*4;
                    #pragma unroll
                    for (int r4 = 0; r4 < 4; ++r4)
                        if (kb0 + r4 > qrow) st[ct][r4] = -3.0e38f;
                }
            }
            float mx = -3.0e38f;
            #pragma unroll
            for (int ct = 0; ct < 4; ++ct)
                #pragma unroll
                for (int r4 = 0; r4 < 4; ++r4) mx = fmaxf(mx, st[ct][r4]);
            mx = fmaxf(mx, __shfl_xor(mx, 16));
            mx = fmaxf(mx, __shfl_xor(mx, 32));
            // defer-max: only rescale when some row's max grew past the slack
            if (!__all(mx <= m_st + 8.f)){
                float mn = fmaxf(m_st, mx);
                float al = exp2f(m_st - mn);
                m_st = mn;
                #pragma unroll
                for (int r4 = 0; r4 < 4; ++r4){
                    float aa = __shfl(al, quad*4 + r4);
                    #pragma unroll
                    for (int dt = 0; dt < 5; ++dt) ov[dt][r4] *= aa;
                }
            }
            #pragma unroll
            for (int ct = 0; ct < 4; ++ct)
                #pragma unroll
                for (int r4 = 0; r4 < 4; ++r4)
                    st[ct][r4] = exp2f(st[ct][r4] - m_st);   // bounded by 2^8
            // P store: q-major rows (q = n16), packed b64, truncating cvt
            #pragma unroll
            for (int ct = 0; ct < 4; ++ct){
                ushort4 h4;
                h4.x = f2u_t(st[ct][0]); h4.y = f2u_t(st[ct][1]);
                h4.z = f2u_t(st[ct][2]); h4.w = f2u_t(st[ct][3]);
                int goff = ct*2 + (quad >> 1);
                *(ushort4*)&Ps[wave][n16*64 + ((goff ^ (n16&7))*8) + (quad&1)*4] = h4;
            }
            #pragma unroll
            for (int ks = 0; ks < 2; ++ks){
                // O += P V ; l += P @ 1  (same-wave LDS write->read)
            }
            short8 ap[2];
            #pragma unroll
            for (int ks = 0; ks < 2; ++ks)
                ap[ks] = *(const short8*)&Ps[wave][n16*64 + (((ks*4+quad) ^ (n16&7))*8)];
            #pragma unroll
            for (int dt = 0; dt < 4; ++dt)
                #pragma unroll
                for (int ks = 0; ks < 2; ++ks){
                    short8 bv = *(const short8*)&Vt[cur][(dt*16+n16)*64 + (((ks*4+quad) ^ (n16&7))*8)];
                    ov[dt] = mfma16(ap[ks], bv, ov[dt]);
                }
            #pragma unroll
            for (int ks = 0; ks < 2; ++ks)
                ov[4] = mfma16(ap[ks], ones8, ov[4]);

            if (kt < qt) writeKV(cur ^ 1);     // vmcnt wait here, hidden by compute
            __syncthreads();                   // single barrier per k-tile
        }
        #pragma unroll
        for (int r4 = 0; r4 < 4; ++r4){
            float inv = __builtin_amdgcn_rcpf(ov[4][r4]);   // l in output-row layout
            size_t row = tok0 + wave*16 + quad*4 + r4;
            #pragma unroll
            for (int dt = 0; dt < 4; ++dt)
                O[row*512 + h*64 + dt*16 + n16] = f2u(ov[dt][r4] * inv);
        }
    }
}

// ------------------------------------------------------------------
// x1h = bf16( rmsnorm(x + y_bf16) * scale )
__global__ __launch_bounds__(256) void rmsnorm_kernel(
    const float* __restrict__ x, const u16* __restrict__ y,
    const float* __restrict__ scale, u16* __restrict__ out)
{
    int tok = blockIdx.x, tid = threadIdx.x;
    size_t base = (size_t)tok * 512;
    float v0 = x[base+tid]     + u2f(y[base+tid]);
    float v1 = x[base+tid+256] + u2f(y[base+tid+256]);
    float ss = v0*v0 + v1*v1;
    for (int off = 32; off; off >>= 1) ss += __shfl_down(ss, off);
    __shared__ float ws[4];
    if ((tid & 63) == 0) ws[tid >> 6] = ss;
    __syncthreads();
    float rstd = rsqrtf((ws[0]+ws[1]+ws[2]+ws[3])*(1.f/512.f) + 1e-6f);
    out[base+tid]     = f2u(scale[tid]     * v0 * rstd);
    out[base+tid+256] = f2u(scale[tid+256] * v1 * rstd);
}

// out_fp32 = rmsnorm(x1h + moe_f32 + ROUT@b2) * scale
__global__ __launch_bounds__(256) void final_kernel(
    const u16* __restrict__ x1, const float* __restrict__ moe,
    const float* __restrict__ rout, const float* __restrict__ b2,
    const float* __restrict__ scale, float* __restrict__ out)
{
    int tok = blockIdx.x, tid = threadIdx.x;
    size_t base = (size_t)tok * 512;
    float r0 = rout[tok*4+0], r1 = rout[tok*4+1], r2 = rout[tok*4+2], r3 = rout[tok*4+3];
    float bb0 = r0*b2[tid]     + r1*b2[512+tid]     + r2*b2[1024+tid]     + r3*b2[1536+tid];
    float bb1 = r0*b2[tid+256] + r1*b2[768+tid]     + r2*b2[1280+tid]     + r3*b2[1792+tid];
    float v0 = u2f(x1[base+tid])     + moe[base+tid]     + bb0;
    float v1 = u2f(x1[base+tid+256]) + moe[base+tid+256] + bb1;
    float ss = v0*v0 + v1*v1;
    for (int off = 32; off; off >>= 1) ss += __shfl_down(ss, off);
    __shared__ float ws[4];
    if ((tid & 63) == 0) ws[tid >> 6] = ss;
    __syncthreads();
    float rstd = rsqrtf((ws[0]+ws[1]+ws[2]+ws[3])*(1.f/512.f) + 1e-6f);
    out[base+tid]     = scale[tid]     * v0 * rstd;
    out[base+tid+256] = scale[tid+256] * v1 * rstd;
}

// router: softmax(x1h @ wr + br), one wave per token
__global__ __launch_bounds__(256) void router_kernel(
    const u16* __restrict__ x1, const float* __restrict__ wr,
    const float* __restrict__ br, float* __restrict__ rout)
{
    int wid = threadIdx.x >> 6, lane = threadIdx.x & 63;
    int tok = blockIdx.x*4 + wid;
    const u16* xp = x1 + (size_t)tok*512;
    float p0=0.f, p1=0.f, p2=0.f, p3=0.f;
    for (int d = lane; d < 512; d += 64){
        float xv = u2f(xp[d]);
        p0 += xv*wr[d*4+0]; p1 += xv*wr[d*4+1];
        p2 += xv*wr[d*4+2]; p3 += xv*wr[d*4+3];
    }
    for (int off = 32; off; off >>= 1){
        p0 += __shfl_down(p0,off); p1 += __shfl_down(p1,off);
        p2 += __shfl_down(p2,off); p3 += __shfl_down(p3,off);
    }
    if (lane == 0){
        p0 += br[0]; p1 += br[1]; p2 += br[2]; p3 += br[3];
        float mx = fmaxf(fmaxf(p0,p1), fmaxf(p2,p3));
        float e0=__expf(p0-mx), e1=__expf(p1-mx), e2=__expf(p2-mx), e3=__expf(p3-mx);
        float inv = 1.f/(e0+e1+e2+e3);
        rout[tok*4+0]=e0*inv; rout[tok*4+1]=e1*inv;
        rout[tok*4+2]=e2*inv; rout[tok*4+3]=e3*inv;
    }
}

// ------------------------------------------------------------------
extern "C" void kernel_launch(void* const* d_in, const int* in_sizes, int n_in,
                              void* d_out, int out_size, void* d_ws, size_t ws_size,
                              hipStream_t stream)
{
    const float* x    = (const float*)d_in[0];
    const float* mp_w = (const float*)d_in[3];
    const float* mp_b = (const float*)d_in[4];
    const float* fu_w = (const float*)d_in[5];
    const float* fu_b = (const float*)d_in[6];
    const float* wc   = (const float*)d_in[7];
    const float* wk   = (const float*)d_in[8];
    const float* wv   = (const float*)d_in[9];
    const float* wq   = (const float*)d_in[10];
    const float* wo   = (const float*)d_in[11];
    const float* s1   = (const float*)d_in[12];
    const float* s2   = (const float*)d_in[13];
    const float* wr   = (const float*)d_in[14];
    const float* br   = (const float*)d_in[15];
    const float* wg   = (const float*)d_in[16];
    const float* bg   = (const float*)d_in[17];
    const float* w1   = (const float*)d_in[18];
    const float* b1   = (const float*)d_in[19];
    const float* w2   = (const float*)d_in[20];
    const float* b2   = (const float*)d_in[21];

    char* wsb = (char*)d_ws;
    const size_t MB = 1024*1024;
    // persistent weights (0..12.3 MB)
    u16*   WqkvC  = (u16*)(wsb + 0);                 // [1536,1024]
    u16*   woT    = (u16*)(wsb + 3*MB);              // [512,512]
    u16*   wgT    = (u16*)(wsb + 3*MB + 512*1024);   // [512,512]
    u16*   w1T    = (u16*)(wsb + 4*MB);              // [4096,512]
    u16*   w2Ts   = (u16*)(wsb + 8*MB);              // [512,4096]
    float* fubias = (float*)(wsb + 12*MB);           // 512
    float* qkvbias= (float*)(wsb + 12*MB + 8192);    // 1536
    float* ROUT   = (float*)(wsb + 12*MB + 32768);   // 8192x4 (128 KB)
    // prepass scratch (dead before gatepool)
    u16*   wqkvT  = (u16*)(wsb + 12*MB + 512*1024);  // [1536,512] 12.5-14
    u16*   fuBT   = (u16*)(wsb + 16*MB);             // [512,512]
    u16*   mp_wB  = (u16*)(wsb + 16*MB + 512*1024);  // [512,512]
    u16*   WfuBF  = (u16*)(wsb + 17*MB);             // [1024,512]
    // rotating big buffers
    u16*   x1h   = (u16*)(wsb + 14*MB);              // 14-22, live till final
    u16*   XFcat = (u16*)(wsb + 16*MB);              // 16-32, dead after QKV
    u16*   XG    = (u16*)(wsb + 22*MB);              // 22-30, live through w1
    u16*   S3    = (u16*)(wsb + 24*MB);              // 24-32, dead after rmsnorm
    u16*   QKb   = (u16*)(wsb + 32*MB);              // 32-48, dead after flash
    float* MOE   = (float*)(wsb + 32*MB);            // 32-48 fp32 (MoE phase)
    u16*   VbT   = (u16*)(wsb + 48*MB);              // 48-56, dead after flash
    u16*   ATT   = (u16*)(wsb + 56*MB);              // 56-64, dead after wo
    u16*   Hb    = (u16*)(wsb + 48*MB);              // 48-112 contiguous [8192,4096] (MoE, big)
    u16*   HbA   = (u16*)(wsb + 48*MB);              // fallback path
    bool big = ws_size >= (size_t)112*MB;

    auto mg128 = [&](const u16* A, const u16* A2, int lda, const u16* Bt, int ldb,
                     const float* bias, const float* rs, const u16* glu,
                     void* C, void* CB, int ldc, u16* C2, int M, int N, int K, int flags){
        dim3 g(N/128, M/128);
        mgemm_kernel<128><<<g, 256, 0, stream>>>(A, A2, lda, Bt, ldb, bias, rs, glu,
                                                 C, CB, ldc, C2, K, flags);
    };
    auto mg64 = [&](const u16* A, const u16* A2, int lda, const u16* Bt, int ldb,
                    const float* bias, const float* rs, const u16* glu,
                    void* C, void* CB, int ldc, u16* C2, int M, int N, int K, int flags){
        dim3 g(N/128, M/64);
        mgemm_kernel<64><<<g, 256, 0, stream>>>(A, A2, lda, Bt, ldb, bias, rs, glu,
                                                C, CB, ldc, C2, K, flags);
    };

    // ---- prepass (re-run every call)
    TJobs JJ; JJ.n = 12;
    auto setj = [&](int i, const float* src, u16* dst, int K, int N, int ldout,
                    int coloff, float scale){
        JJ.j[i] = TJob{src, dst, K, N, ldout, coloff, (K/32)*(N/32), scale};
    };
    setj(0, wq,            wqkvT, 512,  512,  512, 0, QSCALE);   // Q' = wq*0.125*log2e
    setj(1, wo,            woT,   512,  512,  512, 0, 1.f);
    setj(2, wg,            wgT,   512,  512,  512, 0, 1.f);
    setj(3, fu_w + 512*512,fuBT,  512,  512,  512, 0, 1.f);      // fuB^T
    for (int e = 0; e < 4; ++e){
        setj(4+e, w1 + (size_t)e*512*1024, w1T + (size_t)e*1024*512, 512, 1024, 512, 0, 1.f);
        setj(8+e, w2 + (size_t)e*1024*512, w2Ts + (size_t)e*1024, 1024, 512, 4096, 0, 1.f);
    }
    int nt = 4*256 + 8*512;
    tconv_all_kernel<<<nt, 256, 0, stream>>>(JJ);
    convert_kernel<<<512*512/256, 256, 0, stream>>>(mp_w, mp_wB);
    convert_kernel<<<512*512/256, 256, 0, stream>>>(fu_w, WfuBF);            // fuA rows 0..511
    sgemm_kernel<<<dim3(8,8), 256, 0, stream>>>(wc, wk, wqkvT + 512*512, 32);  // Wck^T
    sgemm_kernel<<<dim3(8,8), 256, 0, stream>>>(wc, wv, wqkvT + 1024*512, 32); // Wcv^T
    biasfold_kernel<<<512, 256, 0, stream>>>(fu_b, mp_b, fu_w, fubias);
    qkvbias_kernel<<<1536, 256, 0, stream>>>(fubias, wqkvT, qkvbias);
    // F1 = mp_w @ fuB -> WfuBF rows 512..1023 (row-major bf16).  16 blocks.
    g128_kernel<0><<<dim3(4, 4), 256, 0, stream>>>(
        mp_wB, 512, fuBT, 512, nullptr, nullptr, WfuBF + 512*512, 512, nullptr, 512);
    // Combined: WqkvC[1536,1024] = wqkvT[1536,512] @ WfuBF[1024,512]^T.  96 blocks.
    g128_kernel<0><<<dim3(8, 12), 256, 0, stream>>>(
        wqkvT, 512, WfuBF, 512, nullptr, nullptr, WqkvC, 1024, nullptr, 512);

    // ---- main pipeline
    gatepool_kernel<<<(TOK/16)*512/256, 256, 0, stream>>>(x, XFcat);
    // QKV from XFcat (xfu folded): Q'|K -> QKb, V^T -> VbT.  768 blocks, 2/CU.
    g128_kernel<1><<<dim3(12, 64), 256, 0, stream>>>(
        XFcat, 1024, WqkvC, 1024, qkvbias, nullptr, QKb, 1024, VbT, 1024);
    flash_kernel<<<512, 256, 0, stream>>>(QKb, VbT, ATT);
    // attn@wo: 64x128 pipelined, 512 blocks
    gemm64p_kernel<0><<<dim3(4, 128), 256, 0, stream>>>(
        ATT, 512, woT, 512, nullptr, nullptr, S3, 512, 512);
    rmsnorm_kernel<<<TOK, 256, 0, stream>>>(x, S3, s1, x1h);                 // x1
    router_kernel<<<TOK/4, 256, 0, stream>>>(x1h, wr, br, ROUT);
    // xg = x1h * sigmoid(x1h@wg+bg): 64x128 pipelined
    gemm64p_kernel<1><<<dim3(4, 128), 256, 0, stream>>>(
        x1h, 512, wgT, 512, bg, x1h, XG, 512, 512);
    if (big){
        // w1: 256^2 single-barrier pipelined, M=8192, N=4096, K=512.  512 blocks.
        gemm256_kernel<<<dim3(16, 32), 512, 0, stream>>>(
            XG, 512, w1T, 512, b1, ROUT, Hb, 4096, 512);
        // w2: 64x128 pipelined, M=8192, N=512, K=4096.  512 blocks.
        gemm64p_kernel<2><<<dim3(4, 128), 256, 0, stream>>>(
            Hb, 4096, w2Ts, 4096, nullptr, nullptr, MOE, 512, 4096);
    } else {
        // fallback (r6 structure): pairwise experts, Hb = HbA [8192,2048]
        for (int p = 0; p < 2; ++p){
            mg128(XG, XG + (size_t)MSPLIT*512, 512, w1T + (size_t)p*2048*512, 512,
                  b1 + p*2048, ROUT + p*2, 0,
                  HbA, HbA + (size_t)MSPLIT*2048, 2048, 0,
                  TOK, 2048, 512, GF_GELU | GF_RSCOL);
            mg64 (HbA, HbA + (size_t)MSPLIT*2048, 2048, w2Ts + p*2048, 4096, 0, 0, 0,
                  MOE, (float*)MOE + (size_t)MSPLIT*512, 512, 0,
                  TOK, 512, 2048, p ? GF_ACCUM : GF_F32OUT);
        }
    }
    final_kernel<<<TOK, 256, 0, stream>>>(x1h, MOE, ROUT, b2, s2, (float*)d_out);
}

// Round 12
// 405.831 us; speedup vs baseline: 1.5213x; 1.0209x over previous
//
#include <hip/hip_runtime.h>
#include <math.h>

#define B_   4
#define T_   2048
#define D_   512
#define TOK  (B_*T_)      // 8192 tokens
#define TL_  2045         // N_BLOCKS*(T//N_BLOCKS) = 5*409
#define GATE 0.2f         // softmax(...).mean(-1) over same axis == 1/5
#define QSCALE 0.18033688011112043f   // 0.125 * log2(e): S in log2 domain
#define MSPLIT 4096

typedef unsigned short u16;
typedef __attribute__((ext_vector_type(8))) short short8;   // 8 bf16 = 4 VGPRs
typedef __attribute__((ext_vector_type(4))) float f32x4;

static __device__ __forceinline__ u16 f2u(float f){      // fp32 -> bf16 (RNE)
    union { float f; unsigned u; } a; a.f = f;
    unsigned r = a.u + 0x7fffu + ((a.u >> 16) & 1u);
    return (u16)(r >> 16);
}
static __device__ __forceinline__ u16 f2u_t(float f){    // truncating (P >= 0)
    return (u16)(__float_as_uint(f) >> 16);
}
static __device__ __forceinline__ float u2f(u16 u){
    union { unsigned u; float f; } a; a.u = ((unsigned)u) << 16;
    return a.f;
}
static __device__ __forceinline__ f32x4 mfma16(short8 a, short8 b, f32x4 c){
    return __builtin_amdgcn_mfma_f32_16x16x32_bf16(a, b, c, 0, 0, 0);
}
static __device__ __forceinline__ void glds16(const u16* g, u16* l){
    __builtin_amdgcn_global_load_lds((const __attribute__((address_space(1))) void*)g,
                                     (__attribute__((address_space(3))) void*)l, 16, 0, 0);
}
// fast GELU (tanh form): hw v_exp_f32 + v_rcp_f32 (no precise-divide sequence).
static __device__ __forceinline__ float fgelu(float x){
    float u = x * (1.f + 0.044715f * x * x);
    return x * __builtin_amdgcn_rcpf(1.f + exp2f(-2.3021193f * u));
}
static __device__ __forceinline__ float fsigm(float x){  // sigmoid via rcp
    return __builtin_amdgcn_rcpf(1.f + __expf(-x));
}

// ------------------------------------------------------------------
// gate + pool fused: XFcat[:,0:512]=bf16(0.2*x masked), XFcat[:,512:]=bf16(pool)
__global__ __launch_bounds__(256) void gatepool_kernel(
    const float* __restrict__ x, u16* __restrict__ xfcat)
{
    int idx = blockIdx.x*256 + threadIdx.x;
    int d = idx & 511, g = idx >> 9;
    int b = g >> 7, t0 = (g & 127) << 4;
    const float* xp = x + ((size_t)b*2048)*512 + d;
    float v[30];
    #pragma unroll
    for (int j = 0; j < 30; ++j){
        int u = t0 - 7 + j;
        v[j] = (u >= 0 && u < TL_) ? xp[(size_t)u*512] : 0.f;
    }
    float p[31]; p[0] = 0.f;
    #pragma unroll
    for (int j = 0; j < 30; ++j) p[j+1] = p[j] + v[j];
    u16* xc = xfcat + ((size_t)(b*2048 + t0))*1024 + d;
    #pragma unroll
    for (int i = 0; i < 16; ++i){
        int t = t0 + i;
        float sum = p[i+15] - p[i];                 // u in [t-7, t+7]
        int lo = t-7; if (lo < 0) lo = 0;
        int hi = t+7; if (hi > 2047) hi = 2047;
        xc[(size_t)i*1024]       = f2u((t < TL_) ? GATE*v[i+7] : 0.f);
        xc[(size_t)i*1024 + 512] = f2u(GATE * sum / (float)(hi - lo + 1));
    }
}

// ------------------------------------------------------------------
// batched transpose/plain convert: trans=1: dst[n*ldout+coloff+k]=bf16(s*src[k][n])
//                                  trans=0: dst[k*ldout+n]       =bf16(s*src[k][n])
struct TJob { const float* src; u16* dst; int K, N, ldout, coloff, tiles; float scale; int trans; };
struct TJobs { TJob j[14]; int n; };

__global__ __launch_bounds__(256) void tconv_all_kernel(TJobs JJ){
    __shared__ float t[32][33];
    int idx = blockIdx.x;
    int jb = 0;
    while (jb < JJ.n - 1 && idx >= JJ.j[jb].tiles){ idx -= JJ.j[jb].tiles; ++jb; }
    TJob J = JJ.j[jb];
    int tX = J.N >> 5;
    int k0 = (idx / tX) * 32, n0 = (idx % tX) * 32;
    int tx = threadIdx.x & 31, ty = threadIdx.x >> 5;
    if (J.trans){
        #pragma unroll
        for (int i = 0; i < 32; i += 8)
            t[ty+i][tx] = J.src[(size_t)(k0+ty+i)*J.N + n0+tx];
        __syncthreads();
        #pragma unroll
        for (int i = 0; i < 32; i += 8)
            J.dst[(size_t)(n0+ty+i)*J.ldout + J.coloff + k0+tx] = f2u(J.scale * t[tx][ty+i]);
    } else {
        #pragma unroll
        for (int i = 0; i < 32; i += 8){
            float v = J.src[(size_t)(k0+ty+i)*J.N + n0+tx];
            J.dst[(size_t)(k0+ty+i)*J.ldout + n0+tx] = f2u(J.scale * v);
        }
    }
}

// fubias[n] = fu_b[n] + sum_d mp_b[d] * fu_w[512+d][n]
__global__ __launch_bounds__(256) void biasfold_kernel(
    const float* __restrict__ fu_b, const float* __restrict__ mp_b,
    const float* __restrict__ fu_w, float* __restrict__ out)
{
    int n = blockIdx.x, tid = threadIdx.x;
    float s = mp_b[tid]*fu_w[(size_t)(512+tid)*512 + n]
            + mp_b[tid+256]*fu_w[(size_t)(768+tid)*512 + n];
    for (int off = 32; off; off >>= 1) s += __shfl_down(s, off);
    __shared__ float ws[4];
    if ((tid & 63) == 0) ws[tid >> 6] = s;
    __syncthreads();
    if (tid == 0) out[n] = fu_b[n] + ws[0]+ws[1]+ws[2]+ws[3];
}

// qkvbias[n] = sum_d fubias[d] * wqkvT[n][d]
__global__ __launch_bounds__(256) void qkvbias_kernel(
    const float* __restrict__ fubias, const u16* __restrict__ wqkvT,
    float* __restrict__ out)
{
    int n = blockIdx.x, tid = threadIdx.x;
    const u16* wp = wqkvT + (size_t)n*512;
    float s = fubias[tid]*u2f(wp[tid]) + fubias[tid+256]*u2f(wp[tid+256]);
    for (int off = 32; off; off >>= 1) s += __shfl_down(s, off);
    __shared__ float ws[4];
    if ((tid & 63) == 0) ws[tid >> 6] = s;
    __syncthreads();
    if (tid == 0) out[n] = ws[0]+ws[1]+ws[2]+ws[3];
}

// small fp32 GEMM x2 (z selects job), N=512, writes bf16 TRANSPOSED
__global__ __launch_bounds__(256) void sgemm2_kernel(const float* __restrict__ A,
    const float* __restrict__ B0, const float* __restrict__ B1,
    u16* __restrict__ d0, u16* __restrict__ d1, int K){
    __shared__ float As[16][65];
    __shared__ float Bs[16][65];
    const float* B = blockIdx.z ? B1 : B0;
    u16* dstT = blockIdx.z ? d1 : d0;
    int tid = threadIdx.x;
    int tx = tid & 15, ty = tid >> 4;
    int m0 = blockIdx.y*64, n0 = blockIdx.x*64;
    int arow = tid >> 2, akq = (tid & 3) * 4;
    int bk = tid >> 4, bn = (tid & 15) * 4;
    float acc[4][4] = {};
    for (int k0 = 0; k0 < K; k0 += 16){
        const float* Ap = A + (size_t)(m0+arow)*K + k0 + akq;
        As[akq+0][arow]=Ap[0]; As[akq+1][arow]=Ap[1];
        As[akq+2][arow]=Ap[2]; As[akq+3][arow]=Ap[3];
        const float* Bp = B + (size_t)(k0+bk)*512 + n0 + bn;
        Bs[bk][bn+0]=Bp[0]; Bs[bk][bn+1]=Bp[1];
        Bs[bk][bn+2]=Bp[2]; Bs[bk][bn+3]=Bp[3];
        __syncthreads();
        #pragma unroll
        for (int kk = 0; kk < 16; ++kk){
            float av[4], bv[4];
            #pragma unroll
            for (int i=0;i<4;++i) av[i]=As[kk][ty*4+i];
            #pragma unroll
            for (int j=0;j<4;++j) bv[j]=Bs[kk][tx*4+j];
            #pragma unroll
            for (int i=0;i<4;++i)
                #pragma unroll
                for (int j=0;j<4;++j) acc[i][j] += av[i]*bv[j];
        }
        __syncthreads();
    }
    #pragma unroll
    for (int i=0;i<4;++i)
        #pragma unroll
        for (int j=0;j<4;++j)
            dstT[(size_t)(n0+tx*4+j)*512 + m0+ty*4+i] = f2u(acc[i][j]);
}

// ------------------------------------------------------------------
// bf16 MFMA GEMM: legacy 2-barrier structure (small-workspace fallback only)
#define GF_GELU   1
#define GF_ACCUM  2
#define GF_RSCOL  4
#define GF_GLU    8
#define GF_F32OUT 16
#define GF_QKV    32

template<int MT>
__global__ __launch_bounds__(256) void mgemm_kernel(
    const u16* __restrict__ A, const u16* __restrict__ A2, int lda,
    const u16* __restrict__ Bt, int ldb,
    const float* __restrict__ bias, const float* __restrict__ rs,
    const u16* __restrict__ glu, void* __restrict__ Cp, void* __restrict__ CpB,
    int ldc, u16* __restrict__ Cp2, int K, int flags)
{
    constexpr int MI = MT/32;            // m-tiles per wave (16 rows each)
    __shared__ u16 As[MT*64];
    __shared__ u16 Bs[128*64];
    int tid = threadIdx.x;
    int wave = tid >> 6, lane = tid & 63;
    int n16 = lane & 15, quad = lane >> 4;
    int m0 = blockIdx.y * MT, n0 = blockIdx.x * 128;
    int wr = (wave >> 1) * (MT/2), wc = (wave & 1) * 64;

    f32x4 acc[MI][4] = {};

    for (int k0 = 0; k0 < K; k0 += 64){
        #pragma unroll
        for (int i = 0; i < MT/32; ++i){
            int s = i*256 + tid;
            int row = s >> 3, g = (s & 7) ^ (row & 7);
            int rg = m0 + row;
            const u16* Ap = (rg < MSPLIT) ? A + (size_t)rg*lda
                                          : A2 + (size_t)(rg - MSPLIT)*lda;
            glds16(Ap + k0 + g*8, As + (size_t)s*8);
        }
        #pragma unroll
        for (int i = 0; i < 4; ++i){
            int s = i*256 + tid;
            int row = s >> 3, g = (s & 7) ^ (row & 7);
            glds16(Bt + (size_t)(n0+row)*ldb + k0 + g*8, Bs + (size_t)s*8);
        }
        __syncthreads();
        #pragma unroll
        for (int ks = 0; ks < 2; ++ks){
            short8 af[MI], bf[4];
            #pragma unroll
            for (int mi = 0; mi < MI; ++mi){
                int row = wr + mi*16 + n16;
                int g = (ks*4 + quad) ^ (row & 7);
                af[mi] = *(const short8*)&As[row*64 + g*8];
            }
            #pragma unroll
            for (int ni = 0; ni < 4; ++ni){
                int row = wc + ni*16 + n16;
                int g = (ks*4 + quad) ^ (row & 7);
                bf[ni] = *(const short8*)&Bs[row*64 + g*8];
            }
            #pragma unroll
            for (int mi = 0; mi < MI; ++mi)
                #pragma unroll
                for (int ni = 0; ni < 4; ++ni)
                    acc[mi][ni] = mfma16(af[mi], bf[ni], acc[mi][ni]);
        }
        __syncthreads();
    }

    if ((flags & GF_QKV) && n0 >= 1024){
        #pragma unroll
        for (int mi = 0; mi < MI; ++mi){
            int row0 = m0 + wr + mi*16 + quad*4;
            #pragma unroll
            for (int ni = 0; ni < 4; ++ni){
                int col = n0 + wc + ni*16 + n16;
                float bb = bias[col];
                ushort4 h4;
                h4.x = f2u(acc[mi][ni][0] + bb); h4.y = f2u(acc[mi][ni][1] + bb);
                h4.z = f2u(acc[mi][ni][2] + bb); h4.w = f2u(acc[mi][ni][3] + bb);
                *(ushort4*)&Cp2[(size_t)(col-1024)*8192 + row0] = h4;
            }
        }
        return;
    }

    #pragma unroll
    for (int mi = 0; mi < MI; ++mi){
        #pragma unroll
        for (int reg = 0; reg < 4; ++reg){
            int row = m0 + wr + mi*16 + quad*4 + reg;
            void*  cb = (row < MSPLIT) ? Cp : CpB;
            size_t rr = (row < MSPLIT) ? row : row - MSPLIT;
            #pragma unroll
            for (int ni = 0; ni < 4; ++ni){
                int col = n0 + wc + ni*16 + n16;
                float v = acc[mi][ni][reg];
                if (bias) v += bias[col];
                if (flags & GF_GELU)  v = fgelu(v);
                if (flags & GF_GLU)   v = u2f(glu[(size_t)row*512 + col]) * fsigm(v);
                if (flags & GF_RSCOL) v *= rs[(size_t)row*4 + (col >> 10)];
                size_t ci = rr*ldc + col;
                if (flags & GF_ACCUM)       ((float*)cb)[ci] += v;
                else if (flags & GF_F32OUT) ((float*)cb)[ci]  = v;
                else                        ((u16*)cb)[ci]    = f2u(v);
            }
        }
    }
}

// ------------------------------------------------------------------
// 256x256-tile pipelined bf16 GEMM (w1), SINGLE-barrier counted loop + XCD
// swizzle.  Per K-step: vmcnt(0) -> barrier -> stage(next) -> ds_read+MFMA
// -> lgkmcnt(0).  bias+fgelu+rscol -> bf16 C.
__global__ __launch_bounds__(512, 2) void gemm256_kernel(
    const u16* __restrict__ A, int lda,
    const u16* __restrict__ Bt, int ldb,
    const float* __restrict__ bias, const float* __restrict__ rs,
    u16* __restrict__ C, int ldc, int K)
{
    __shared__ u16 As[2][256*64];
    __shared__ u16 Bs[2][256*64];
    int tid = threadIdx.x;
    int wave = tid >> 6, lane = tid & 63;
    int n16 = lane & 15, quad = lane >> 4;
    int D = blockIdx.y * gridDim.x + blockIdx.x;
    int nwg = gridDim.x * gridDim.y;
    int T = (D & 7) * (nwg >> 3) + (D >> 3);
    int m0 = (T / gridDim.x) * 256, n0 = (T % gridDim.x) * 256;
    int wm = wave >> 2, wn = wave & 3;        // 2 x 4 wave grid, wave tile 128x64

    f32x4 acc[8][4] = {};

    const u16* ga[4]; const u16* gb[4]; int sa[4];
    #pragma unroll
    for (int i = 0; i < 4; ++i){
        int s = i*512 + tid;
        int row = s >> 3, g = (s & 7) ^ (row & 7);
        ga[i] = A  + (size_t)(m0+row)*lda + g*8;
        gb[i] = Bt + (size_t)(n0+row)*ldb + g*8;
        sa[i] = s*8;
    }
    auto stage = [&](int slot, int k0){       // 8 glds16 per thread
        #pragma unroll
        for (int i = 0; i < 4; ++i) glds16(ga[i] + k0, &As[slot][sa[i]]);
        #pragma unroll
        for (int i = 0; i < 4; ++i) glds16(gb[i] + k0, &Bs[slot][sa[i]]);
    };

    int aoff[2][8], boff[2][4];
    #pragma unroll
    for (int ks = 0; ks < 2; ++ks){
        #pragma unroll
        for (int mi = 0; mi < 8; ++mi){
            int row = wm*128 + mi*16 + n16;
            aoff[ks][mi] = row*64 + (((ks*4 + quad) ^ (row & 7))*8);
        }
        #pragma unroll
        for (int ni = 0; ni < 4; ++ni){
            int row = wn*64 + ni*16 + n16;
            boff[ks][ni] = row*64 + (((ks*4 + quad) ^ (row & 7))*8);
        }
    }

    stage(0, 0);
    int NT = K >> 6;
    for (int t = 0; t < NT; ++t){
        int cur = t & 1;
        asm volatile("s_waitcnt vmcnt(0)" ::: "memory");   // own loads of slot cur
        __builtin_amdgcn_s_barrier();                      // slot cur complete for all
        if (t + 1 < NT) stage(cur ^ 1, (t+1)*64);          // safe: prev readers retired
        __builtin_amdgcn_s_setprio(1);
        #pragma unroll
        for (int ks = 0; ks < 2; ++ks){
            short8 af[8], bf[4];
            #pragma unroll
            for (int mi = 0; mi < 8; ++mi)
                af[mi] = *(const short8*)&As[cur][aoff[ks][mi]];
            #pragma unroll
            for (int ni = 0; ni < 4; ++ni)
                bf[ni] = *(const short8*)&Bs[cur][boff[ks][ni]];
            #pragma unroll
            for (int mi = 0; mi < 8; ++mi)
                #pragma unroll
                for (int ni = 0; ni < 4; ++ni)
                    acc[mi][ni] = mfma16(af[mi], bf[ni], acc[mi][ni]);
        }
        __builtin_amdgcn_s_setprio(0);
        asm volatile("s_waitcnt lgkmcnt(0)" ::: "memory"); // reads retired pre-barrier
    }

    float bb[4];
    #pragma unroll
    for (int ni = 0; ni < 4; ++ni)
        bb[ni] = bias ? bias[n0 + wn*64 + ni*16 + n16] : 0.f;

    int e = n0 >> 10;   // expert id; 256-tile never crosses a 1024 boundary
    #pragma unroll
    for (int mi = 0; mi < 8; ++mi){
        #pragma unroll
        for (int reg = 0; reg < 4; ++reg){
            int row = m0 + wm*128 + mi*16 + quad*4 + reg;
            float rv = rs[(size_t)row*4 + e];
            #pragma unroll
            for (int ni = 0; ni < 4; ++ni){
                int col = n0 + wn*64 + ni*16 + n16;
                float v = acc[mi][ni][reg] + bb[ni];
                v = fgelu(v) * rv;
                C[(size_t)row*ldc + col] = f2u(v);
            }
        }
    }
}

// ------------------------------------------------------------------
// 128x128-tile pipelined bf16 GEMM, SINGLE-barrier counted loop + XCD swizzle.
// EPI=0: (+bias) bf16 (prepass / generic).
// EPI=1: QKV (n0<1024: bias bf16 -> C; n0>=1024: bias + transpose -> C2).
template<int EPI>
__global__ __launch_bounds__(256, 2) void g128_kernel(
    const u16* __restrict__ A, int lda,
    const u16* __restrict__ Bt, int ldb,
    const float* __restrict__ bias, const float* __restrict__ rs,
    u16* __restrict__ C, int ldc, u16* __restrict__ C2, int K)
{
    __shared__ u16 As[2][128*64];
    __shared__ u16 Bs[2][128*64];
    int tid = threadIdx.x;
    int wave = tid >> 6, lane = tid & 63;
    int n16 = lane & 15, quad = lane >> 4;
    int D = blockIdx.y * gridDim.x + blockIdx.x;
    int nwg = gridDim.x * gridDim.y;
    int T = (nwg % 8 == 0) ? ((D & 7) * (nwg >> 3) + (D >> 3)) : D;
    int m0 = (T / gridDim.x) * 128, n0 = (T % gridDim.x) * 128;
    int wm = wave >> 1, wn = wave & 1;

    f32x4 acc[4][4] = {};

    const u16* ga[4]; const u16* gb[4]; int sa[4];
    #pragma unroll
    for (int i = 0; i < 4; ++i){
        int s = i*256 + tid;
        int row = s >> 3, g = (s & 7) ^ (row & 7);
        ga[i] = A  + (size_t)(m0+row)*lda + g*8;
        gb[i] = Bt + (size_t)(n0+row)*ldb + g*8;
        sa[i] = s*8;
    }
    auto stage = [&](int slot, int k0){       // 8 glds16 per thread
        #pragma unroll
        for (int i = 0; i < 4; ++i) glds16(ga[i] + k0, &As[slot][sa[i]]);
        #pragma unroll
        for (int i = 0; i < 4; ++i) glds16(gb[i] + k0, &Bs[slot][sa[i]]);
    };

    int aoff[2][4], boff[2][4];
    #pragma unroll
    for (int ks = 0; ks < 2; ++ks){
        #pragma unroll
        for (int mi = 0; mi < 4; ++mi){
            int row = wm*64 + mi*16 + n16;
            aoff[ks][mi] = row*64 + (((ks*4 + quad) ^ (row & 7))*8);
        }
        #pragma unroll
        for (int ni = 0; ni < 4; ++ni){
            int row = wn*64 + ni*16 + n16;
            boff[ks][ni] = row*64 + (((ks*4 + quad) ^ (row & 7))*8);
        }
    }

    stage(0, 0);
    int NT = K >> 6;
    for (int t = 0; t < NT; ++t){
        int cur = t & 1;
        asm volatile("s_waitcnt vmcnt(0)" ::: "memory");
        __builtin_amdgcn_s_barrier();
        if (t + 1 < NT) stage(cur ^ 1, (t+1)*64);
        __builtin_amdgcn_s_setprio(1);
        #pragma unroll
        for (int ks = 0; ks < 2; ++ks){
            short8 af[4], bf[4];
            #pragma unroll
            for (int mi = 0; mi < 4; ++mi)
                af[mi] = *(const short8*)&As[cur][aoff[ks][mi]];
            #pragma unroll
            for (int ni = 0; ni < 4; ++ni)
                bf[ni] = *(const short8*)&Bs[cur][boff[ks][ni]];
            #pragma unroll
            for (int mi = 0; mi < 4; ++mi)
                #pragma unroll
                for (int ni = 0; ni < 4; ++ni)
                    acc[mi][ni] = mfma16(af[mi], bf[ni], acc[mi][ni]);
        }
        __builtin_amdgcn_s_setprio(0);
        asm volatile("s_waitcnt lgkmcnt(0)" ::: "memory");
    }

    if (EPI == 1 && n0 >= 1024){
        #pragma unroll
        for (int mi = 0; mi < 4; ++mi){
            int row0 = m0 + wm*64 + mi*16 + quad*4;
            #pragma unroll
            for (int ni = 0; ni < 4; ++ni){
                int col = n0 + wn*64 + ni*16 + n16;
                float bb = bias[col];
                ushort4 h4;
                h4.x = f2u(acc[mi][ni][0] + bb); h4.y = f2u(acc[mi][ni][1] + bb);
                h4.z = f2u(acc[mi][ni][2] + bb); h4.w = f2u(acc[mi][ni][3] + bb);
                *(ushort4*)&C2[(size_t)(col-1024)*8192 + row0] = h4;
            }
        }
        return;
    }

    float bb[4];
    #pragma unroll
    for (int ni = 0; ni < 4; ++ni)
        bb[ni] = bias ? bias[n0 + wn*64 + ni*16 + n16] : 0.f;

    #pragma unroll
    for (int mi = 0; mi < 4; ++mi){
        #pragma unroll
        for (int reg = 0; reg < 4; ++reg){
            int row = m0 + wm*64 + mi*16 + quad*4 + reg;
            #pragma unroll
            for (int ni = 0; ni < 4; ++ni){
                int col = n0 + wn*64 + ni*16 + n16;
                float v = acc[mi][ni][reg] + bb[ni];
                C[(size_t)row*ldc + col] = f2u(v);
            }
        }
    }
}

// ------------------------------------------------------------------
// 64x128-tile pipelined bf16 GEMM, SINGLE-barrier counted loop + XCD swizzle.
// EPI=0: plain bf16 out (wo).  EPI=1: bias+GLU -> bf16 (wg).  EPI=2: fp32 (w2).
template<int EPI>
__global__ __launch_bounds__(256, 2) void gemm64p_kernel(
    const u16* __restrict__ A, int lda,
    const u16* __restrict__ Bt, int ldb,
    const float* __restrict__ bias, const u16* __restrict__ glu,
    void* __restrict__ C, int ldc, int K)
{
    __shared__ u16 As[2][64*64];
    __shared__ u16 Bs[2][128*64];
    int tid = threadIdx.x;
    int wave = tid >> 6, lane = tid & 63;
    int n16 = lane & 15, quad = lane >> 4;
    int D = blockIdx.y * gridDim.x + blockIdx.x;
    int nwg = gridDim.x * gridDim.y;
    int T = (D & 7) * (nwg >> 3) + (D >> 3);
    int m0 = (T / gridDim.x) * 64, n0 = (T % gridDim.x) * 128;
    int wm = wave >> 1, wn = wave & 1;

    f32x4 acc[2][4] = {};

    const u16* ga[2]; const u16* gb[4]; int sa[2], sb[4];
    #pragma unroll
    for (int i = 0; i < 2; ++i){
        int s = i*256 + tid;
        int row = s >> 3, g = (s & 7) ^ (row & 7);
        ga[i] = A + (size_t)(m0+row)*lda + g*8;
        sa[i] = s*8;
    }
    #pragma unroll
    for (int i = 0; i < 4; ++i){
        int s = i*256 + tid;
        int row = s >> 3, g = (s & 7) ^ (row & 7);
        gb[i] = Bt + (size_t)(n0+row)*ldb + g*8;
        sb[i] = s*8;
    }
    auto stage = [&](int slot, int k0){       // 6 glds16 per thread
        #pragma unroll
        for (int i = 0; i < 2; ++i) glds16(ga[i] + k0, &As[slot][sa[i]]);
        #pragma unroll
        for (int i = 0; i < 4; ++i) glds16(gb[i] + k0, &Bs[slot][sb[i]]);
    };

    int aoff[2][2], boff[2][4];
    #pragma unroll
    for (int ks = 0; ks < 2; ++ks){
        #pragma unroll
        for (int mi = 0; mi < 2; ++mi){
            int row = wm*32 + mi*16 + n16;
            aoff[ks][mi] = row*64 + (((ks*4 + quad) ^ (row & 7))*8);
        }
        #pragma unroll
        for (int ni = 0; ni < 4; ++ni){
            int row = wn*64 + ni*16 + n16;
            boff[ks][ni] = row*64 + (((ks*4 + quad) ^ (row & 7))*8);
        }
    }

    stage(0, 0);
    int NT = K >> 6;
    for (int t = 0; t < NT; ++t){
        int cur = t & 1;
        asm volatile("s_waitcnt vmcnt(0)" ::: "memory");
        __builtin_amdgcn_s_barrier();
        if (t + 1 < NT) stage(cur ^ 1, (t+1)*64);
        __builtin_amdgcn_s_setprio(1);
        #pragma unroll
        for (int ks = 0; ks < 2; ++ks){
            short8 af[2], bf[4];
            #pragma unroll
            for (int mi = 0; mi < 2; ++mi)
                af[mi] = *(const short8*)&As[cur][aoff[ks][mi]];
            #pragma unroll
            for (int ni = 0; ni < 4; ++ni)
                bf[ni] = *(const short8*)&Bs[cur][boff[ks][ni]];
            #pragma unroll
            for (int mi = 0; mi < 2; ++mi)
                #pragma unroll
                for (int ni = 0; ni < 4; ++ni)
                    acc[mi][ni] = mfma16(af[mi], bf[ni], acc[mi][ni]);
        }
        __builtin_amdgcn_s_setprio(0);
        asm volatile("s_waitcnt lgkmcnt(0)" ::: "memory");
    }

    #pragma unroll
    for (int mi = 0; mi < 2; ++mi){
        #pragma unroll
        for (int reg = 0; reg < 4; ++reg){
            int row = m0 + wm*32 + mi*16 + quad*4 + reg;
            #pragma unroll
            for (int ni = 0; ni < 4; ++ni){
                int col = n0 + wn*64 + ni*16 + n16;
                float v = acc[mi][ni][reg];
                if (bias) v += bias[col];
                if (EPI == 1) v = u2f(glu[(size_t)row*512 + col]) * fsigm(v);
                if (EPI == 2) ((float*)C)[(size_t)row*ldc + col] = v;
                else          ((u16*)C)[(size_t)row*ldc + col]  = f2u(v);
            }
        }
    }
}

// ------------------------------------------------------------------
// MFMA flash attention (S^T form), causal, dh=64, 8 heads.  PAIRED 64-row
// Q-tiles (qt = 31-p then p).  Double-buffered K/V LDS + async reg-staging,
// l via all-ones MFMA column, defer-max (THR=8, log2 domain).
__global__ __launch_bounds__(256) void flash_kernel(
    const u16* __restrict__ QK,   // [8192,1024]: cols 0..511 Q', 512..1023 K
    const u16* __restrict__ VT,   // [512,8192]
    u16* __restrict__ O)          // [8192,512]
{
    int bid = blockIdx.x;
    int p = bid >> 5;                  // 0..15
    int bh = bid & 31;
    int h = bh & 7, b = bh >> 3;
    __shared__ u16 Ks[2][64*64];
    __shared__ u16 Vt[2][64*64];
    __shared__ u16 Ps[4][16*64];
    int tid = threadIdx.x;
    int wave = tid >> 6, lane = tid & 63;
    int n16 = lane & 15, quad = lane >> 4;
    size_t btok = (size_t)b*2048;
    int r = tid >> 2;
    int g0 = (tid & 3) * 2;
    const short8 ones8 = {0x3F80,0x3F80,0x3F80,0x3F80,0x3F80,0x3F80,0x3F80,0x3F80};

    uint4 ka, kb, va, vb;              // in-flight K/V registers
    auto loadKV = [&](int kt){
        const uint4* kp = (const uint4*)&QK[(btok + kt*64 + r)*1024 + 512 + h*64 + g0*8];
        ka = kp[0]; kb = kp[1];
        const uint4* vp = (const uint4*)&VT[(size_t)(h*64 + r)*8192 + btok + kt*64 + g0*8];
        va = vp[0]; vb = vp[1];
    };
    auto writeKV = [&](int s){         // compiler inserts vmcnt wait (data dep)
        *(uint4*)&Ks[s][r*64 + ((g0  ) ^ (r&7))*8] = ka;
        *(uint4*)&Ks[s][r*64 + ((g0+1) ^ (r&7))*8] = kb;
        *(uint4*)&Vt[s][r*64 + ((g0  ) ^ (r&7))*8] = va;
        *(uint4*)&Vt[s][r*64 + ((g0+1) ^ (r&7))*8] = vb;
    };

    for (int ph = 0; ph < 2; ++ph){
        int qt = ph ? p : (31 - p);
        size_t tok0 = btok + qt*64;
        short8 qf[2];
        #pragma unroll
        for (int ks = 0; ks < 2; ++ks)
            qf[ks] = *(const short8*)&QK[(tok0 + wave*16 + n16)*1024
                                         + h*64 + ks*32 + quad*8];
        int qrow = qt*64 + wave*16 + n16;
        float m_st = -3.0e38f;
        f32x4 ov[5] = {};              // [0..3]=O accum, [4]=row-sum (l) accum

        loadKV(0);
        __syncthreads();               // prior ph's readers done with LDS
        writeKV(0);
        __syncthreads();               // slot 0 visible to all waves

        for (int kt = 0; kt <= qt; ++kt){
            int cur = kt & 1;
            if (kt < qt) loadKV(kt+1);         // issue early; lands under compute

            f32x4 st[4];
            #pragma unroll
            for (int ct = 0; ct < 4; ++ct){
                f32x4 a = {};
                #pragma unroll
                for (int ks = 0; ks < 2; ++ks){
                    short8 kf = *(const short8*)&Ks[cur][(ct*16+n16)*64 + (((ks*4+quad) ^ (n16&7))*8)];
                    a = mfma16(kf, qf[ks], a);
                }
                st[ct] = a;
            }
            if (kt == qt){                 // diagonal: causal mask
                #pragma unroll
                for (int ct = 0; ct < 4; ++ct){
                    int kb0 = kt*64 + ct*16 + quad*4;
                    #pragma unroll
                    for (int r4 = 0; r4 < 4; ++r4)
                        if (kb0 + r4 > qrow) st[ct][r4] = -3.0e38f;
                }
            }
            float mx = -3.0e38f;
            #pragma unroll
            for (int ct = 0; ct < 4; ++ct)
                #pragma unroll
                for (int r4 = 0; r4 < 4; ++r4) mx = fmaxf(mx, st[ct][r4]);
            mx = fmaxf(mx, __shfl_xor(mx, 16));
            mx = fmaxf(mx, __shfl_xor(mx, 32));
            // defer-max: only rescale when some row's max grew past the slack
            if (!__all(mx <= m_st + 8.f)){
                float mn = fmaxf(m_st, mx);
                float al = exp2f(m_st - mn);
                m_st = mn;
                #pragma unroll
                for (int r4 = 0; r4 < 4; ++r4){
                    float aa = __shfl(al, quad*4 + r4);
                    #pragma unroll
                    for (int dt = 0; dt < 5; ++dt) ov[dt][r4] *= aa;
                }
            }
            #pragma unroll
            for (int ct = 0; ct < 4; ++ct)
                #pragma unroll
                for (int r4 = 0; r4 < 4; ++r4)
                    st[ct][r4] = exp2f(st[ct][r4] - m_st);   // bounded by 2^8
            // P store: q-major rows (q = n16), packed b64, truncating cvt
            #pragma unroll
            for (int ct = 0; ct < 4; ++ct){
                ushort4 h4;
                h4.x = f2u_t(st[ct][0]); h4.y = f2u_t(st[ct][1]);
                h4.z = f2u_t(st[ct][2]); h4.w = f2u_t(st[ct][3]);
                int goff = ct*2 + (quad >> 1);
                *(ushort4*)&Ps[wave][n16*64 + ((goff ^ (n16&7))*8) + (quad&1)*4] = h4;
            }
            // O += P V ; l += P @ 1  (same-wave LDS write->read, program order)
            short8 ap[2];
            #pragma unroll
            for (int ks = 0; ks < 2; ++ks)
                ap[ks] = *(const short8*)&Ps[wave][n16*64 + (((ks*4+quad) ^ (n16&7))*8)];
            #pragma unroll
            for (int dt = 0; dt < 4; ++dt)
                #pragma unroll
                for (int ks = 0; ks < 2; ++ks){
                    short8 bv = *(const short8*)&Vt[cur][(dt*16+n16)*64 + (((ks*4+quad) ^ (n16&7))*8)];
                    ov[dt] = mfma16(ap[ks], bv, ov[dt]);
                }
            #pragma unroll
            for (int ks = 0; ks < 2; ++ks)
                ov[4] = mfma16(ap[ks], ones8, ov[4]);

            if (kt < qt) writeKV(cur ^ 1);     // vmcnt wait here, hidden by compute
            __syncthreads();                   // single barrier per k-tile
        }
        #pragma unroll
        for (int r4 = 0; r4 < 4; ++r4){
            float inv = __builtin_amdgcn_rcpf(ov[4][r4]);   // l in output-row layout
            size_t row = tok0 + wave*16 + quad*4 + r4;
            #pragma unroll
            for (int dt = 0; dt < 4; ++dt)
                O[row*512 + h*64 + dt*16 + n16] = f2u(ov[dt][r4] * inv);
        }
    }
}

// ------------------------------------------------------------------
// x1h = bf16( rmsnorm(x + y_bf16) * scale )  +  fused router softmax.
// Router consumes the BIT-IDENTICAL bf16 values being stored (re-decoded),
// so results match the previous separate router kernel.
__global__ __launch_bounds__(256) void rmsnorm_router_kernel(
    const float* __restrict__ x, const u16* __restrict__ y,
    const float* __restrict__ scale,
    const float* __restrict__ wr, const float* __restrict__ br,
    u16* __restrict__ out, float* __restrict__ rout)
{
    int tok = blockIdx.x, tid = threadIdx.x;
    size_t base = (size_t)tok * 512;
    float v0 = x[base+tid]     + u2f(y[base+tid]);
    float v1 = x[base+tid+256] + u2f(y[base+tid+256]);
    float ss = v0*v0 + v1*v1;
    for (int off = 32; off; off >>= 1) ss += __shfl_down(ss, off);
    __shared__ float ws[4];
    if ((tid & 63) == 0) ws[tid >> 6] = ss;
    __syncthreads();
    float rstd = rsqrtf((ws[0]+ws[1]+ws[2]+ws[3])*(1.f/512.f) + 1e-6f);
    u16 h0 = f2u(scale[tid]     * v0 * rstd);
    u16 h1 = f2u(scale[tid+256] * v1 * rstd);
    out[base+tid]     = h0;
    out[base+tid+256] = h1;
    // router: p[e] = sum_d x1h[d]*wr[d][e] + br[e]
    float xv0 = u2f(h0), xv1 = u2f(h1);
    float4 wr0 = *(const float4*)&wr[(size_t)tid*4];
    float4 wr1 = *(const float4*)&wr[(size_t)(tid+256)*4];
    float p0 = xv0*wr0.x + xv1*wr1.x;
    float p1 = xv0*wr0.y + xv1*wr1.y;
    float p2 = xv0*wr0.z + xv1*wr1.z;
    float p3 = xv0*wr0.w + xv1*wr1.w;
    for (int off = 32; off; off >>= 1){
        p0 += __shfl_down(p0,off); p1 += __shfl_down(p1,off);
        p2 += __shfl_down(p2,off); p3 += __shfl_down(p3,off);
    }
    __shared__ float pr[4][4];
    if ((tid & 63) == 0){
        int w = tid >> 6;
        pr[w][0]=p0; pr[w][1]=p1; pr[w][2]=p2; pr[w][3]=p3;
    }
    __syncthreads();
    if (tid == 0){
        float q0 = pr[0][0]+pr[1][0]+pr[2][0]+pr[3][0] + br[0];
        float q1 = pr[0][1]+pr[1][1]+pr[2][1]+pr[3][1] + br[1];
        float q2 = pr[0][2]+pr[1][2]+pr[2][2]+pr[3][2] + br[2];
        float q3 = pr[0][3]+pr[1][3]+pr[2][3]+pr[3][3] + br[3];
        float mx = fmaxf(fmaxf(q0,q1), fmaxf(q2,q3));
        float e0=__expf(q0-mx), e1=__expf(q1-mx), e2=__expf(q2-mx), e3=__expf(q3-mx);
        float inv = 1.f/(e0+e1+e2+e3);
        rout[tok*4+0]=e0*inv; rout[tok*4+1]=e1*inv;
        rout[tok*4+2]=e2*inv; rout[tok*4+3]=e3*inv;
    }
}

// out_fp32 = rmsnorm(x1h + moe_f32 + ROUT@b2) * scale
__global__ __launch_bounds__(256) void final_kernel(
    const u16* __restrict__ x1, const float* __restrict__ moe,
    const float* __restrict__ rout, const float* __restrict__ b2,
    const float* __restrict__ scale, float* __restrict__ out)
{
    int tok = blockIdx.x, tid = threadIdx.x;
    size_t base = (size_t)tok * 512;
    float r0 = rout[tok*4+0], r1 = rout[tok*4+1], r2 = rout[tok*4+2], r3 = rout[tok*4+3];
    float bb0 = r0*b2[tid]     + r1*b2[512+tid]     + r2*b2[1024+tid]     + r3*b2[1536+tid];
    float bb1 = r0*b2[tid+256] + r1*b2[768+tid]     + r2*b2[1280+tid]     + r3*b2[1792+tid];
    float v0 = u2f(x1[base+tid])     + moe[base+tid]     + bb0;
    float v1 = u2f(x1[base+tid+256]) + moe[base+tid+256] + bb1;
    float ss = v0*v0 + v1*v1;
    for (int off = 32; off; off >>= 1) ss += __shfl_down(ss, off);
    __shared__ float ws[4];
    if ((tid & 63) == 0) ws[tid >> 6] = ss;
    __syncthreads();
    float rstd = rsqrtf((ws[0]+ws[1]+ws[2]+ws[3])*(1.f/512.f) + 1e-6f);
    out[base+tid]     = scale[tid]     * v0 * rstd;
    out[base+tid+256] = scale[tid+256] * v1 * rstd;
}

// ------------------------------------------------------------------
extern "C" void kernel_launch(void* const* d_in, const int* in_sizes, int n_in,
                              void* d_out, int out_size, void* d_ws, size_t ws_size,
                              hipStream_t stream)
{
    const float* x    = (const float*)d_in[0];
    const float* mp_w = (const float*)d_in[3];
    const float* mp_b = (const float*)d_in[4];
    const float* fu_w = (const float*)d_in[5];
    const float* fu_b = (const float*)d_in[6];
    const float* wc   = (const float*)d_in[7];
    const float* wk   = (const float*)d_in[8];
    const float* wv   = (const float*)d_in[9];
    const float* wq   = (const float*)d_in[10];
    const float* wo   = (const float*)d_in[11];
    const float* s1   = (const float*)d_in[12];
    const float* s2   = (const float*)d_in[13];
    const float* wr   = (const float*)d_in[14];
    const float* br   = (const float*)d_in[15];
    const float* wg   = (const float*)d_in[16];
    const float* bg   = (const float*)d_in[17];
    const float* w1   = (const float*)d_in[18];
    const float* b1   = (const float*)d_in[19];
    const float* w2   = (const float*)d_in[20];
    const float* b2   = (const float*)d_in[21];

    char* wsb = (char*)d_ws;
    const size_t MB = 1024*1024;
    // persistent weights (0..12.3 MB)
    u16*   WqkvC  = (u16*)(wsb + 0);                 // [1536,1024]
    u16*   woT    = (u16*)(wsb + 3*MB);              // [512,512]
    u16*   wgT    = (u16*)(wsb + 3*MB + 512*1024);   // [512,512]
    u16*   w1T    = (u16*)(wsb + 4*MB);              // [4096,512]
    u16*   w2Ts   = (u16*)(wsb + 8*MB);              // [512,4096]
    float* fubias = (float*)(wsb + 12*MB);           // 512
    float* qkvbias= (float*)(wsb + 12*MB + 8192);    // 1536
    float* ROUT   = (float*)(wsb + 12*MB + 32768);   // 8192x4 (128 KB)
    // prepass scratch (dead before gatepool)
    u16*   wqkvT  = (u16*)(wsb + 12*MB + 512*1024);  // [1536,512] 12.5-14
    u16*   fuBT   = (u16*)(wsb + 16*MB);             // [512,512]
    u16*   mp_wB  = (u16*)(wsb + 16*MB + 512*1024);  // [512,512]
    u16*   WfuBF  = (u16*)(wsb + 17*MB);             // [1024,512]
    // rotating big buffers
    u16*   x1h   = (u16*)(wsb + 14*MB);              // 14-22, live till final
    u16*   XFcat = (u16*)(wsb + 16*MB);              // 16-32, dead after QKV
    u16*   XG    = (u16*)(wsb + 22*MB);              // 22-30, live through w1
    u16*   S3    = (u16*)(wsb + 24*MB);              // 24-32, dead after rmsnorm
    u16*   QKb   = (u16*)(wsb + 32*MB);              // 32-48, dead after flash
    float* MOE   = (float*)(wsb + 32*MB);            // 32-48 fp32 (MoE phase)
    u16*   VbT   = (u16*)(wsb + 48*MB);              // 48-56, dead after flash
    u16*   ATT   = (u16*)(wsb + 56*MB);              // 56-64, dead after wo
    u16*   Hb    = (u16*)(wsb + 48*MB);              // 48-112 contiguous [8192,4096] (MoE, big)
    u16*   HbA   = (u16*)(wsb + 48*MB);              // fallback path
    bool big = ws_size >= (size_t)112*MB;

    auto mg128 = [&](const u16* A, const u16* A2, int lda, const u16* Bt, int ldb,
                     const float* bias, const float* rs, const u16* glu,
                     void* C, void* CB, int ldc, u16* C2, int M, int N, int K, int flags){
        dim3 g(N/128, M/128);
        mgemm_kernel<128><<<g, 256, 0, stream>>>(A, A2, lda, Bt, ldb, bias, rs, glu,
                                                 C, CB, ldc, C2, K, flags);
    };
    auto mg64 = [&](const u16* A, const u16* A2, int lda, const u16* Bt, int ldb,
                    const float* bias, const float* rs, const u16* glu,
                    void* C, void* CB, int ldc, u16* C2, int M, int N, int K, int flags){
        dim3 g(N/128, M/64);
        mgemm_kernel<64><<<g, 256, 0, stream>>>(A, A2, lda, Bt, ldb, bias, rs, glu,
                                                C, CB, ldc, C2, K, flags);
    };

    // ---- prepass (re-run every call)
    TJobs JJ; JJ.n = 14;
    auto setj = [&](int i, const float* src, u16* dst, int K, int N, int ldout,
                    int coloff, float scale, int trans){
        JJ.j[i] = TJob{src, dst, K, N, ldout, coloff, (K/32)*(N/32), scale, trans};
    };
    setj(0, wq,            wqkvT, 512,  512,  512, 0, QSCALE, 1);  // Q' = wq*0.125*log2e
    setj(1, wo,            woT,   512,  512,  512, 0, 1.f, 1);
    setj(2, wg,            wgT,   512,  512,  512, 0, 1.f, 1);
    setj(3, fu_w + 512*512,fuBT,  512,  512,  512, 0, 1.f, 1);     // fuB^T
    for (int e = 0; e < 4; ++e){
        setj(4+e, w1 + (size_t)e*512*1024, w1T + (size_t)e*1024*512, 512, 1024, 512, 0, 1.f, 1);
        setj(8+e, w2 + (size_t)e*1024*512, w2Ts + (size_t)e*1024, 1024, 512, 4096, 0, 1.f, 1);
    }
    setj(12, mp_w, mp_wB, 512, 512, 512, 0, 1.f, 0);               // plain converts
    setj(13, fu_w, WfuBF, 512, 512, 512, 0, 1.f, 0);               // fuA rows 0..511
    int nt = 4*256 + 8*512 + 2*256;
    tconv_all_kernel<<<nt, 256, 0, stream>>>(JJ);
    sgemm2_kernel<<<dim3(8,8,2), 256, 0, stream>>>(
        wc, wk, wv, wqkvT + 512*512, wqkvT + 1024*512, 32);        // Wck^T, Wcv^T
    biasfold_kernel<<<512, 256, 0, stream>>>(fu_b, mp_b, fu_w, fubias);
    qkvbias_kernel<<<1536, 256, 0, stream>>>(fubias, wqkvT, qkvbias);
    // F1 = mp_w @ fuB -> WfuBF rows 512..1023 (row-major bf16).  16 blocks.
    g128_kernel<0><<<dim3(4, 4), 256, 0, stream>>>(
        mp_wB, 512, fuBT, 512, nullptr, nullptr, WfuBF + 512*512, 512, nullptr, 512);
    // Combined: WqkvC[1536,1024] = wqkvT[1536,512] @ WfuBF[1024,512]^T.  96 blocks.
    g128_kernel<0><<<dim3(8, 12), 256, 0, stream>>>(
        wqkvT, 512, WfuBF, 512, nullptr, nullptr, WqkvC, 1024, nullptr, 512);

    // ---- main pipeline
    gatepool_kernel<<<(TOK/16)*512/256, 256, 0, stream>>>(x, XFcat);
    // QKV from XFcat (xfu folded): Q'|K -> QKb, V^T -> VbT.  768 blocks, 2/CU.
    g128_kernel<1><<<dim3(12, 64), 256, 0, stream>>>(
        XFcat, 1024, WqkvC, 1024, qkvbias, nullptr, QKb, 1024, VbT, 1024);
    flash_kernel<<<512, 256, 0, stream>>>(QKb, VbT, ATT);
    // attn@wo: 64x128 pipelined, 512 blocks
    gemm64p_kernel<0><<<dim3(4, 128), 256, 0, stream>>>(
        ATT, 512, woT, 512, nullptr, nullptr, S3, 512, 512);
    // x1 + fused router
    rmsnorm_router_kernel<<<TOK, 256, 0, stream>>>(x, S3, s1, wr, br, x1h, ROUT);
    // xg = x1h * sigmoid(x1h@wg+bg): 64x128 pipelined
    gemm64p_kernel<1><<<dim3(4, 128), 256, 0, stream>>>(
        x1h, 512, wgT, 512, bg, x1h, XG, 512, 512);
    if (big){
        // w1: 256^2 single-barrier pipelined, M=8192, N=4096, K=512.  512 blocks.
        gemm256_kernel<<<dim3(16, 32), 512, 0, stream>>>(
            XG, 512, w1T, 512, b1, ROUT, Hb, 4096, 512);
        // w2: 64x128 pipelined, M=8192, N=512, K=4096.  512 blocks.
        gemm64p_kernel<2><<<dim3(4, 128), 256, 0, stream>>>(
            Hb, 4096, w2Ts, 4096, nullptr, nullptr, MOE, 512, 4096);
    } else {
        // fallback (r6 structure): pairwise experts, Hb = HbA [8192,2048]
        for (int p = 0; p < 2; ++p){
            mg128(XG, XG + (size_t)MSPLIT*512, 512, w1T + (size_t)p*2048*512, 512,
                  b1 + p*2048, ROUT + p*2, 0,
                  HbA, HbA + (size_t)MSPLIT*2048, 2048, 0,
                  TOK, 2048, 512, GF_GELU | GF_RSCOL);
            mg64 (HbA, HbA + (size_t)MSPLIT*2048, 2048, w2Ts + p*2048, 4096, 0, 0, 0,
                  MOE, (float*)MOE + (size_t)MSPLIT*512, 512, 0,
                  TOK, 512, 2048, p ? GF_ACCUM : GF_F32OUT);
        }
    }
    final_kernel<<<TOK, 256, 0, stream>>>(x1h, MOE, ROUT, b2, s2, (float*)d_out);
}

// Round 13
// 403.904 us; speedup vs baseline: 1.5285x; 1.0048x over previous
//
#include <hip/hip_runtime.h>
#include <math.h>

#define B_   4
#define T_   2048
#define D_   512
#define TOK  (B_*T_)      // 8192 tokens
#define TL_  2045         // N_BLOCKS*(T//N_BLOCKS) = 5*409
#define GATE 0.2f         // softmax(...).mean(-1) over same axis == 1/5
#define QSCALE 0.18033688011112043f   // 0.125 * log2(e): S in log2 domain
#define MSPLIT 4096

typedef unsigned short u16;
typedef __attribute__((ext_vector_type(8))) short short8;   // 8 bf16 = 4 VGPRs
typedef __attribute__((ext_vector_type(4))) float f32x4;

static __device__ __forceinline__ u16 f2u(float f){      // fp32 -> bf16 (RNE)
    union { float f; unsigned u; } a; a.f = f;
    unsigned r = a.u + 0x7fffu + ((a.u >> 16) & 1u);
    return (u16)(r >> 16);
}
static __device__ __forceinline__ u16 f2u_t(float f){    // truncating (P >= 0)
    return (u16)(__float_as_uint(f) >> 16);
}
static __device__ __forceinline__ float u2f(u16 u){
    union { unsigned u; float f; } a; a.u = ((unsigned)u) << 16;
    return a.f;
}
static __device__ __forceinline__ f32x4 mfma16(short8 a, short8 b, f32x4 c){
    return __builtin_amdgcn_mfma_f32_16x16x32_bf16(a, b, c, 0, 0, 0);
}
static __device__ __forceinline__ void glds16(const u16* g, u16* l){
    __builtin_amdgcn_global_load_lds((const __attribute__((address_space(1))) void*)g,
                                     (__attribute__((address_space(3))) void*)l, 16, 0, 0);
}
// fast GELU (tanh form): hw v_exp_f32 + v_rcp_f32 (no precise-divide sequence).
static __device__ __forceinline__ float fgelu(float x){
    float u = x * (1.f + 0.044715f * x * x);
    return x * __builtin_amdgcn_rcpf(1.f + exp2f(-2.3021193f * u));
}
static __device__ __forceinline__ float fsigm(float x){  // sigmoid via rcp
    return __builtin_amdgcn_rcpf(1.f + __expf(-x));
}

// ------------------------------------------------------------------
// gate + pool fused: XFcat[:,0:512]=bf16(0.2*x masked), XFcat[:,512:]=bf16(pool)
__global__ __launch_bounds__(256) void gatepool_kernel(
    const float* __restrict__ x, u16* __restrict__ xfcat)
{
    int idx = blockIdx.x*256 + threadIdx.x;
    int d = idx & 511, g = idx >> 9;
    int b = g >> 7, t0 = (g & 127) << 4;
    const float* xp = x + ((size_t)b*2048)*512 + d;
    float v[30];
    #pragma unroll
    for (int j = 0; j < 30; ++j){
        int u = t0 - 7 + j;
        v[j] = (u >= 0 && u < TL_) ? xp[(size_t)u*512] : 0.f;
    }
    float p[31]; p[0] = 0.f;
    #pragma unroll
    for (int j = 0; j < 30; ++j) p[j+1] = p[j] + v[j];
    u16* xc = xfcat + ((size_t)(b*2048 + t0))*1024 + d;
    #pragma unroll
    for (int i = 0; i < 16; ++i){
        int t = t0 + i;
        float sum = p[i+15] - p[i];                 // u in [t-7, t+7]
        int lo = t-7; if (lo < 0) lo = 0;
        int hi = t+7; if (hi > 2047) hi = 2047;
        xc[(size_t)i*1024]       = f2u((t < TL_) ? GATE*v[i+7] : 0.f);
        xc[(size_t)i*1024 + 512] = f2u(GATE * sum / (float)(hi - lo + 1));
    }
}

// ------------------------------------------------------------------
// batched transpose/plain convert: trans=1: dst[n*ldout+coloff+k]=bf16(s*src[k][n])
//                                  trans=0: dst[k*ldout+n]       =bf16(s*src[k][n])
struct TJob { const float* src; u16* dst; int K, N, ldout, coloff, tiles; float scale; int trans; };
struct TJobs { TJob j[14]; int n; };

__global__ __launch_bounds__(256) void tconv_all_kernel(TJobs JJ){
    __shared__ float t[32][33];
    int idx = blockIdx.x;
    int jb = 0;
    while (jb < JJ.n - 1 && idx >= JJ.j[jb].tiles){ idx -= JJ.j[jb].tiles; ++jb; }
    TJob J = JJ.j[jb];
    int tX = J.N >> 5;
    int k0 = (idx / tX) * 32, n0 = (idx % tX) * 32;
    int tx = threadIdx.x & 31, ty = threadIdx.x >> 5;
    if (J.trans){
        #pragma unroll
        for (int i = 0; i < 32; i += 8)
            t[ty+i][tx] = J.src[(size_t)(k0+ty+i)*J.N + n0+tx];
        __syncthreads();
        #pragma unroll
        for (int i = 0; i < 32; i += 8)
            J.dst[(size_t)(n0+ty+i)*J.ldout + J.coloff + k0+tx] = f2u(J.scale * t[tx][ty+i]);
    } else {
        #pragma unroll
        for (int i = 0; i < 32; i += 8){
            float v = J.src[(size_t)(k0+ty+i)*J.N + n0+tx];
            J.dst[(size_t)(k0+ty+i)*J.ldout + n0+tx] = f2u(J.scale * v);
        }
    }
}

// fubias[n] = fu_b[n] + sum_d mp_b[d] * fu_w[512+d][n]
__global__ __launch_bounds__(256) void biasfold_kernel(
    const float* __restrict__ fu_b, const float* __restrict__ mp_b,
    const float* __restrict__ fu_w, float* __restrict__ out)
{
    int n = blockIdx.x, tid = threadIdx.x;
    float s = mp_b[tid]*fu_w[(size_t)(512+tid)*512 + n]
            + mp_b[tid+256]*fu_w[(size_t)(768+tid)*512 + n];
    for (int off = 32; off; off >>= 1) s += __shfl_down(s, off);
    __shared__ float ws[4];
    if ((tid & 63) == 0) ws[tid >> 6] = s;
    __syncthreads();
    if (tid == 0) out[n] = fu_b[n] + ws[0]+ws[1]+ws[2]+ws[3];
}

// qkvbias[n] = sum_d fubias[d] * wqkvT[n][d]
__global__ __launch_bounds__(256) void qkvbias_kernel(
    const float* __restrict__ fubias, const u16* __restrict__ wqkvT,
    float* __restrict__ out)
{
    int n = blockIdx.x, tid = threadIdx.x;
    const u16* wp = wqkvT + (size_t)n*512;
    float s = fubias[tid]*u2f(wp[tid]) + fubias[tid+256]*u2f(wp[tid+256]);
    for (int off = 32; off; off >>= 1) s += __shfl_down(s, off);
    __shared__ float ws[4];
    if ((tid & 63) == 0) ws[tid >> 6] = s;
    __syncthreads();
    if (tid == 0) out[n] = ws[0]+ws[1]+ws[2]+ws[3];
}

// small fp32 GEMM x2 (z selects job), N=512, writes bf16 TRANSPOSED
__global__ __launch_bounds__(256) void sgemm2_kernel(const float* __restrict__ A,
    const float* __restrict__ B0, const float* __restrict__ B1,
    u16* __restrict__ d0, u16* __restrict__ d1, int K){
    __shared__ float As[16][65];
    __shared__ float Bs[16][65];
    const float* B = blockIdx.z ? B1 : B0;
    u16* dstT = blockIdx.z ? d1 : d0;
    int tid = threadIdx.x;
    int tx = tid & 15, ty = tid >> 4;
    int m0 = blockIdx.y*64, n0 = blockIdx.x*64;
    int arow = tid >> 2, akq = (tid & 3) * 4;
    int bk = tid >> 4, bn = (tid & 15) * 4;
    float acc[4][4] = {};
    for (int k0 = 0; k0 < K; k0 += 16){
        const float* Ap = A + (size_t)(m0+arow)*K + k0 + akq;
        As[akq+0][arow]=Ap[0]; As[akq+1][arow]=Ap[1];
        As[akq+2][arow]=Ap[2]; As[akq+3][arow]=Ap[3];
        const float* Bp = B + (size_t)(k0+bk)*512 + n0 + bn;
        Bs[bk][bn+0]=Bp[0]; Bs[bk][bn+1]=Bp[1];
        Bs[bk][bn+2]=Bp[2]; Bs[bk][bn+3]=Bp[3];
        __syncthreads();
        #pragma unroll
        for (int kk = 0; kk < 16; ++kk){
            float av[4], bv[4];
            #pragma unroll
            for (int i=0;i<4;++i) av[i]=As[kk][ty*4+i];
            #pragma unroll
            for (int j=0;j<4;++j) bv[j]=Bs[kk][tx*4+j];
            #pragma unroll
            for (int i=0;i<4;++i)
                #pragma unroll
                for (int j=0;j<4;++j) acc[i][j] += av[i]*bv[j];
        }
        __syncthreads();
    }
    #pragma unroll
    for (int i=0;i<4;++i)
        #pragma unroll
        for (int j=0;j<4;++j)
            dstT[(size_t)(n0+tx*4+j)*512 + m0+ty*4+i] = f2u(acc[i][j]);
}

// ------------------------------------------------------------------
// bf16 MFMA GEMM: legacy 2-barrier structure (small-workspace fallback only)
#define GF_GELU   1
#define GF_ACCUM  2
#define GF_RSCOL  4
#define GF_GLU    8
#define GF_F32OUT 16
#define GF_QKV    32

template<int MT>
__global__ __launch_bounds__(256) void mgemm_kernel(
    const u16* __restrict__ A, const u16* __restrict__ A2, int lda,
    const u16* __restrict__ Bt, int ldb,
    const float* __restrict__ bias, const float* __restrict__ rs,
    const u16* __restrict__ glu, void* __restrict__ Cp, void* __restrict__ CpB,
    int ldc, u16* __restrict__ Cp2, int K, int flags)
{
    constexpr int MI = MT/32;            // m-tiles per wave (16 rows each)
    __shared__ u16 As[MT*64];
    __shared__ u16 Bs[128*64];
    int tid = threadIdx.x;
    int wave = tid >> 6, lane = tid & 63;
    int n16 = lane & 15, quad = lane >> 4;
    int m0 = blockIdx.y * MT, n0 = blockIdx.x * 128;
    int wr = (wave >> 1) * (MT/2), wc = (wave & 1) * 64;

    f32x4 acc[MI][4] = {};

    for (int k0 = 0; k0 < K; k0 += 64){
        #pragma unroll
        for (int i = 0; i < MT/32; ++i){
            int s = i*256 + tid;
            int row = s >> 3, g = (s & 7) ^ (row & 7);
            int rg = m0 + row;
            const u16* Ap = (rg < MSPLIT) ? A + (size_t)rg*lda
                                          : A2 + (size_t)(rg - MSPLIT)*lda;
            glds16(Ap + k0 + g*8, As + (size_t)s*8);
        }
        #pragma unroll
        for (int i = 0; i < 4; ++i){
            int s = i*256 + tid;
            int row = s >> 3, g = (s & 7) ^ (row & 7);
            glds16(Bt + (size_t)(n0+row)*ldb + k0 + g*8, Bs + (size_t)s*8);
        }
        __syncthreads();
        #pragma unroll
        for (int ks = 0; ks < 2; ++ks){
            short8 af[MI], bf[4];
            #pragma unroll
            for (int mi = 0; mi < MI; ++mi){
                int row = wr + mi*16 + n16;
                int g = (ks*4 + quad) ^ (row & 7);
                af[mi] = *(const short8*)&As[row*64 + g*8];
            }
            #pragma unroll
            for (int ni = 0; ni < 4; ++ni){
                int row = wc + ni*16 + n16;
                int g = (ks*4 + quad) ^ (row & 7);
                bf[ni] = *(const short8*)&Bs[row*64 + g*8];
            }
            #pragma unroll
            for (int mi = 0; mi < MI; ++mi)
                #pragma unroll
                for (int ni = 0; ni < 4; ++ni)
                    acc[mi][ni] = mfma16(af[mi], bf[ni], acc[mi][ni]);
        }
        __syncthreads();
    }

    if ((flags & GF_QKV) && n0 >= 1024){
        #pragma unroll
        for (int mi = 0; mi < MI; ++mi){
            int row0 = m0 + wr + mi*16 + quad*4;
            #pragma unroll
            for (int ni = 0; ni < 4; ++ni){
                int col = n0 + wc + ni*16 + n16;
                float bb = bias[col];
                ushort4 h4;
                h4.x = f2u(acc[mi][ni][0] + bb); h4.y = f2u(acc[mi][ni][1] + bb);
                h4.z = f2u(acc[mi][ni][2] + bb); h4.w = f2u(acc[mi][ni][3] + bb);
                *(ushort4*)&Cp2[(size_t)(col-1024)*8192 + row0] = h4;
            }
        }
        return;
    }

    #pragma unroll
    for (int mi = 0; mi < MI; ++mi){
        #pragma unroll
        for (int reg = 0; reg < 4; ++reg){
            int row = m0 + wr + mi*16 + quad*4 + reg;
            void*  cb = (row < MSPLIT) ? Cp : CpB;
            size_t rr = (row < MSPLIT) ? row : row - MSPLIT;
            #pragma unroll
            for (int ni = 0; ni < 4; ++ni){
                int col = n0 + wc + ni*16 + n16;
                float v = acc[mi][ni][reg];
                if (bias) v += bias[col];
                if (flags & GF_GELU)  v = fgelu(v);
                if (flags & GF_GLU)   v = u2f(glu[(size_t)row*512 + col]) * fsigm(v);
                if (flags & GF_RSCOL) v *= rs[(size_t)row*4 + (col >> 10)];
                size_t ci = rr*ldc + col;
                if (flags & GF_ACCUM)       ((float*)cb)[ci] += v;
                else if (flags & GF_F32OUT) ((float*)cb)[ci]  = v;
                else                        ((u16*)cb)[ci]    = f2u(v);
            }
        }
    }
}

// ------------------------------------------------------------------
// 256x256-tile pipelined bf16 GEMM (w1), SINGLE-barrier counted loop + XCD
// swizzle.  Per K-step: vmcnt(0) -> barrier -> stage(next) -> ds_read+MFMA
// -> lgkmcnt(0).  bias+fgelu+rscol -> bf16 C.
__global__ __launch_bounds__(512, 2) void gemm256_kernel(
    const u16* __restrict__ A, int lda,
    const u16* __restrict__ Bt, int ldb,
    const float* __restrict__ bias, const float* __restrict__ rs,
    u16* __restrict__ C, int ldc, int K)
{
    __shared__ u16 As[2][256*64];
    __shared__ u16 Bs[2][256*64];
    int tid = threadIdx.x;
    int wave = tid >> 6, lane = tid & 63;
    int n16 = lane & 15, quad = lane >> 4;
    int D = blockIdx.y * gridDim.x + blockIdx.x;
    int nwg = gridDim.x * gridDim.y;
    int T = (D & 7) * (nwg >> 3) + (D >> 3);
    int m0 = (T / gridDim.x) * 256, n0 = (T % gridDim.x) * 256;
    int wm = wave >> 2, wn = wave & 3;        // 2 x 4 wave grid, wave tile 128x64

    f32x4 acc[8][4] = {};

    const u16* ga[4]; const u16* gb[4]; int sa[4];
    #pragma unroll
    for (int i = 0; i < 4; ++i){
        int s = i*512 + tid;
        int row = s >> 3, g = (s & 7) ^ (row & 7);
        ga[i] = A  + (size_t)(m0+row)*lda + g*8;
        gb[i] = Bt + (size_t)(n0+row)*ldb + g*8;
        sa[i] = s*8;
    }
    auto stage = [&](int slot, int k0){       // 8 glds16 per thread
        #pragma unroll
        for (int i = 0; i < 4; ++i) glds16(ga[i] + k0, &As[slot][sa[i]]);
        #pragma unroll
        for (int i = 0; i < 4; ++i) glds16(gb[i] + k0, &Bs[slot][sa[i]]);
    };

    int aoff[2][8], boff[2][4];
    #pragma unroll
    for (int ks = 0; ks < 2; ++ks){
        #pragma unroll
        for (int mi = 0; mi < 8; ++mi){
            int row = wm*128 + mi*16 + n16;
            aoff[ks][mi] = row*64 + (((ks*4 + quad) ^ (row & 7))*8);
        }
        #pragma unroll
        for (int ni = 0; ni < 4; ++ni){
            int row = wn*64 + ni*16 + n16;
            boff[ks][ni] = row*64 + (((ks*4 + quad) ^ (row & 7))*8);
        }
    }

    stage(0, 0);
    int NT = K >> 6;
    for (int t = 0; t < NT; ++t){
        int cur = t & 1;
        asm volatile("s_waitcnt vmcnt(0)" ::: "memory");   // own loads of slot cur
        __builtin_amdgcn_s_barrier();                      // slot cur complete for all
        if (t + 1 < NT) stage(cur ^ 1, (t+1)*64);          // safe: prev readers retired
        __builtin_amdgcn_s_setprio(1);
        #pragma unroll
        for (int ks = 0; ks < 2; ++ks){
            short8 af[8], bf[4];
            #pragma unroll
            for (int mi = 0; mi < 8; ++mi)
                af[mi] = *(const short8*)&As[cur][aoff[ks][mi]];
            #pragma unroll
            for (int ni = 0; ni < 4; ++ni)
                bf[ni] = *(const short8*)&Bs[cur][boff[ks][ni]];
            #pragma unroll
            for (int mi = 0; mi < 8; ++mi)
                #pragma unroll
                for (int ni = 0; ni < 4; ++ni)
                    acc[mi][ni] = mfma16(af[mi], bf[ni], acc[mi][ni]);
        }
        __builtin_amdgcn_s_setprio(0);
        asm volatile("s_waitcnt lgkmcnt(0)" ::: "memory"); // reads retired pre-barrier
    }

    float bb[4];
    #pragma unroll
    for (int ni = 0; ni < 4; ++ni)
        bb[ni] = bias ? bias[n0 + wn*64 + ni*16 + n16] : 0.f;

    int e = n0 >> 10;   // expert id; 256-tile never crosses a 1024 boundary
    #pragma unroll
    for (int mi = 0; mi < 8; ++mi){
        #pragma unroll
        for (int reg = 0; reg < 4; ++reg){
            int row = m0 + wm*128 + mi*16 + quad*4 + reg;
            float rv = rs[(size_t)row*4 + e];
            #pragma unroll
            for (int ni = 0; ni < 4; ++ni){
                int col = n0 + wn*64 + ni*16 + n16;
                float v = acc[mi][ni][reg] + bb[ni];
                v = fgelu(v) * rv;
                C[(size_t)row*ldc + col] = f2u(v);
            }
        }
    }
}

// ------------------------------------------------------------------
// 128x128-tile pipelined bf16 GEMM, SINGLE-barrier counted loop + XCD swizzle.
// EPI=0: (+bias) bf16 (prepass / generic).
// EPI=1: QKV (n0<1024: bias bf16 -> C; n0>=1024: bias + transpose -> C2).
template<int EPI>
__global__ __launch_bounds__(256, 2) void g128_kernel(
    const u16* __restrict__ A, int lda,
    const u16* __restrict__ Bt, int ldb,
    const float* __restrict__ bias, const float* __restrict__ rs,
    u16* __restrict__ C, int ldc, u16* __restrict__ C2, int K)
{
    __shared__ u16 As[2][128*64];
    __shared__ u16 Bs[2][128*64];
    int tid = threadIdx.x;
    int wave = tid >> 6, lane = tid & 63;
    int n16 = lane & 15, quad = lane >> 4;
    int D = blockIdx.y * gridDim.x + blockIdx.x;
    int nwg = gridDim.x * gridDim.y;
    int T = (nwg % 8 == 0) ? ((D & 7) * (nwg >> 3) + (D >> 3)) : D;
    int m0 = (T / gridDim.x) * 128, n0 = (T % gridDim.x) * 128;
    int wm = wave >> 1, wn = wave & 1;

    f32x4 acc[4][4] = {};

    const u16* ga[4]; const u16* gb[4]; int sa[4];
    #pragma unroll
    for (int i = 0; i < 4; ++i){
        int s = i*256 + tid;
        int row = s >> 3, g = (s & 7) ^ (row & 7);
        ga[i] = A  + (size_t)(m0+row)*lda + g*8;
        gb[i] = Bt + (size_t)(n0+row)*ldb + g*8;
        sa[i] = s*8;
    }
    auto stage = [&](int slot, int k0){       // 8 glds16 per thread
        #pragma unroll
        for (int i = 0; i < 4; ++i) glds16(ga[i] + k0, &As[slot][sa[i]]);
        #pragma unroll
        for (int i = 0; i < 4; ++i) glds16(gb[i] + k0, &Bs[slot][sa[i]]);
    };

    int aoff[2][4], boff[2][4];
    #pragma unroll
    for (int ks = 0; ks < 2; ++ks){
        #pragma unroll
        for (int mi = 0; mi < 4; ++mi){
            int row = wm*64 + mi*16 + n16;
            aoff[ks][mi] = row*64 + (((ks*4 + quad) ^ (row & 7))*8);
        }
        #pragma unroll
        for (int ni = 0; ni < 4; ++ni){
            int row = wn*64 + ni*16 + n16;
            boff[ks][ni] = row*64 + (((ks*4 + quad) ^ (row & 7))*8);
        }
    }

    stage(0, 0);
    int NT = K >> 6;
    for (int t = 0; t < NT; ++t){
        int cur = t & 1;
        asm volatile("s_waitcnt vmcnt(0)" ::: "memory");
        __builtin_amdgcn_s_barrier();
        if (t + 1 < NT) stage(cur ^ 1, (t+1)*64);
        __builtin_amdgcn_s_setprio(1);
        #pragma unroll
        for (int ks = 0; ks < 2; ++ks){
            short8 af[4], bf[4];
            #pragma unroll
            for (int mi = 0; mi < 4; ++mi)
                af[mi] = *(const short8*)&As[cur][aoff[ks][mi]];
            #pragma unroll
            for (int ni = 0; ni < 4; ++ni)
                bf[ni] = *(const short8*)&Bs[cur][boff[ks][ni]];
            #pragma unroll
            for (int mi = 0; mi < 4; ++mi)
                #pragma unroll
                for (int ni = 0; ni < 4; ++ni)
                    acc[mi][ni] = mfma16(af[mi], bf[ni], acc[mi][ni]);
        }
        __builtin_amdgcn_s_setprio(0);
        asm volatile("s_waitcnt lgkmcnt(0)" ::: "memory");
    }

    if (EPI == 1 && n0 >= 1024){
        #pragma unroll
        for (int mi = 0; mi < 4; ++mi){
            int row0 = m0 + wm*64 + mi*16 + quad*4;
            #pragma unroll
            for (int ni = 0; ni < 4; ++ni){
                int col = n0 + wn*64 + ni*16 + n16;
                float bb = bias[col];
                ushort4 h4;
                h4.x = f2u(acc[mi][ni][0] + bb); h4.y = f2u(acc[mi][ni][1] + bb);
                h4.z = f2u(acc[mi][ni][2] + bb); h4.w = f2u(acc[mi][ni][3] + bb);
                *(ushort4*)&C2[(size_t)(col-1024)*8192 + row0] = h4;
            }
        }
        return;
    }

    float bb[4];
    #pragma unroll
    for (int ni = 0; ni < 4; ++ni)
        bb[ni] = bias ? bias[n0 + wn*64 + ni*16 + n16] : 0.f;

    #pragma unroll
    for (int mi = 0; mi < 4; ++mi){
        #pragma unroll
        for (int reg = 0; reg < 4; ++reg){
            int row = m0 + wm*64 + mi*16 + quad*4 + reg;
            #pragma unroll
            for (int ni = 0; ni < 4; ++ni){
                int col = n0 + wn*64 + ni*16 + n16;
                float v = acc[mi][ni][reg] + bb[ni];
                C[(size_t)row*ldc + col] = f2u(v);
            }
        }
    }
}

// ------------------------------------------------------------------
// 64x128-tile pipelined bf16 GEMM, SINGLE-barrier counted loop + XCD swizzle.
// LDS 48 KiB -> 3 blocks/CU co-resident (VGPR cap 170 >> 88 used): at grid
// 512 all blocks resident, vmcnt waits covered by co-resident blocks.
// EPI=0: plain bf16 out (wo).  EPI=1: bias+GLU -> bf16 (wg).  EPI=2: fp32 (w2).
template<int EPI>
__global__ __launch_bounds__(256, 3) void gemm64p_kernel(
    const u16* __restrict__ A, int lda,
    const u16* __restrict__ Bt, int ldb,
    const float* __restrict__ bias, const u16* __restrict__ glu,
    void* __restrict__ C, int ldc, int K)
{
    __shared__ u16 As[2][64*64];
    __shared__ u16 Bs[2][128*64];
    int tid = threadIdx.x;
    int wave = tid >> 6, lane = tid & 63;
    int n16 = lane & 15, quad = lane >> 4;
    int D = blockIdx.y * gridDim.x + blockIdx.x;
    int nwg = gridDim.x * gridDim.y;
    int T = (D & 7) * (nwg >> 3) + (D >> 3);
    int m0 = (T / gridDim.x) * 64, n0 = (T % gridDim.x) * 128;
    int wm = wave >> 1, wn = wave & 1;

    f32x4 acc[2][4] = {};

    const u16* ga[2]; const u16* gb[4]; int sa[2], sb[4];
    #pragma unroll
    for (int i = 0; i < 2; ++i){
        int s = i*256 + tid;
        int row = s >> 3, g = (s & 7) ^ (row & 7);
        ga[i] = A + (size_t)(m0+row)*lda + g*8;
        sa[i] = s*8;
    }
    #pragma unroll
    for (int i = 0; i < 4; ++i){
        int s = i*256 + tid;
        int row = s >> 3, g = (s & 7) ^ (row & 7);
        gb[i] = Bt + (size_t)(n0+row)*ldb + g*8;
        sb[i] = s*8;
    }
    auto stage = [&](int slot, int k0){       // 6 glds16 per thread
        #pragma unroll
        for (int i = 0; i < 2; ++i) glds16(ga[i] + k0, &As[slot][sa[i]]);
        #pragma unroll
        for (int i = 0; i < 4; ++i) glds16(gb[i] + k0, &Bs[slot][sb[i]]);
    };

    int aoff[2][2], boff[2][4];
    #pragma unroll
    for (int ks = 0; ks < 2; ++ks){
        #pragma unroll
        for (int mi = 0; mi < 2; ++mi){
            int row = wm*32 + mi*16 + n16;
            aoff[ks][mi] = row*64 + (((ks*4 + quad) ^ (row & 7))*8);
        }
        #pragma unroll
        for (int ni = 0; ni < 4; ++ni){
            int row = wn*64 + ni*16 + n16;
            boff[ks][ni] = row*64 + (((ks*4 + quad) ^ (row & 7))*8);
        }
    }

    stage(0, 0);
    int NT = K >> 6;
    for (int t = 0; t < NT; ++t){
        int cur = t & 1;
        asm volatile("s_waitcnt vmcnt(0)" ::: "memory");
        __builtin_amdgcn_s_barrier();
        if (t + 1 < NT) stage(cur ^ 1, (t+1)*64);
        __builtin_amdgcn_s_setprio(1);
        #pragma unroll
        for (int ks = 0; ks < 2; ++ks){
            short8 af[2], bf[4];
            #pragma unroll
            for (int mi = 0; mi < 2; ++mi)
                af[mi] = *(const short8*)&As[cur][aoff[ks][mi]];
            #pragma unroll
            for (int ni = 0; ni < 4; ++ni)
                bf[ni] = *(const short8*)&Bs[cur][boff[ks][ni]];
            #pragma unroll
            for (int mi = 0; mi < 2; ++mi)
                #pragma unroll
                for (int ni = 0; ni < 4; ++ni)
                    acc[mi][ni] = mfma16(af[mi], bf[ni], acc[mi][ni]);
        }
        __builtin_amdgcn_s_setprio(0);
        asm volatile("s_waitcnt lgkmcnt(0)" ::: "memory");
    }

    #pragma unroll
    for (int mi = 0; mi < 2; ++mi){
        #pragma unroll
        for (int reg = 0; reg < 4; ++reg){
            int row = m0 + wm*32 + mi*16 + quad*4 + reg;
            #pragma unroll
            for (int ni = 0; ni < 4; ++ni){
                int col = n0 + wn*64 + ni*16 + n16;
                float v = acc[mi][ni][reg];
                if (bias) v += bias[col];
                if (EPI == 1) v = u2f(glu[(size_t)row*512 + col]) * fsigm(v);
                if (EPI == 2) ((float*)C)[(size_t)row*ldc + col] = v;
                else          ((u16*)C)[(size_t)row*ldc + col]  = f2u(v);
            }
        }
    }
}

// ------------------------------------------------------------------
// MFMA flash attention (S^T form), causal, dh=64, 8 heads.  PAIRED 64-row
// Q-tiles (qt = 31-p then p).  Double-buffered K/V LDS + async reg-staging,
// l via all-ones MFMA column, defer-max (THR=8, log2 domain).
__global__ __launch_bounds__(256) void flash_kernel(
    const u16* __restrict__ QK,   // [8192,1024]: cols 0..511 Q', 512..1023 K
    const u16* __restrict__ VT,   // [512,8192]
    u16* __restrict__ O)          // [8192,512]
{
    int bid = blockIdx.x;
    int p = bid >> 5;                  // 0..15
    int bh = bid & 31;
    int h = bh & 7, b = bh >> 3;
    __shared__ u16 Ks[2][64*64];
    __shared__ u16 Vt[2][64*64];
    __shared__ u16 Ps[4][16*64];
    int tid = threadIdx.x;
    int wave = tid >> 6, lane = tid & 63;
    int n16 = lane & 15, quad = lane >> 4;
    size_t btok = (size_t)b*2048;
    int r = tid >> 2;
    int g0 = (tid & 3) * 2;
    const short8 ones8 = {0x3F80,0x3F80,0x3F80,0x3F80,0x3F80,0x3F80,0x3F80,0x3F80};

    uint4 ka, kb, va, vb;              // in-flight K/V registers
    auto loadKV = [&](int kt){
        const uint4* kp = (const uint4*)&QK[(btok + kt*64 + r)*1024 + 512 + h*64 + g0*8];
        ka = kp[0]; kb = kp[1];
        const uint4* vp = (const uint4*)&VT[(size_t)(h*64 + r)*8192 + btok + kt*64 + g0*8];
        va = vp[0]; vb = vp[1];
    };
    auto writeKV = [&](int s){         // compiler inserts vmcnt wait (data dep)
        *(uint4*)&Ks[s][r*64 + ((g0  ) ^ (r&7))*8] = ka;
        *(uint4*)&Ks[s][r*64 + ((g0+1) ^ (r&7))*8] = kb;
        *(uint4*)&Vt[s][r*64 + ((g0  ) ^ (r&7))*8] = va;
        *(uint4*)&Vt[s][r*64 + ((g0+1) ^ (r&7))*8] = vb;
    };

    for (int ph = 0; ph < 2; ++ph){
        int qt = ph ? p : (31 - p);
        size_t tok0 = btok + qt*64;
        short8 qf[2];
        #pragma unroll
        for (int ks = 0; ks < 2; ++ks)
            qf[ks] = *(const short8*)&QK[(tok0 + wave*16 + n16)*1024
                                         + h*64 + ks*32 + quad*8];
        int qrow = qt*64 + wave*16 + n16;
        float m_st = -3.0e38f;
        f32x4 ov[5] = {};              // [0..3]=O accum, [4]=row-sum (l) accum

        loadKV(0);
        __syncthreads();               // prior ph's readers done with LDS
        writeKV(0);
        __syncthreads();               // slot 0 visible to all waves

        for (int kt = 0; kt <= qt; ++kt){
            int cur = kt & 1;
            if (kt < qt) loadKV(kt+1);         // issue early; lands under compute

            f32x4 st[4];
            #pragma unroll
            for (int ct = 0; ct < 4; ++ct){
                f32x4 a = {};
                #pragma unroll
                for (int ks = 0; ks < 2; ++ks){
                    short8 kf = *(const short8*)&Ks[cur][(ct*16+n16)*64 + (((ks*4+quad) ^ (n16&7))*8)];
                    a = mfma16(kf, qf[ks], a);
                }
                st[ct] = a;
            }
            if (kt == qt){                 // diagonal: causal mask
                #pragma unroll
                for (int ct = 0; ct < 4; ++ct){
                    int kb0 = kt*64 + ct*16 + quad*4;
                    #pragma unroll
                    for (int r4 = 0; r4 < 4; ++r4)
                        if (kb0 + r4 > qrow) st[ct][r4] = -3.0e38f;
                }
            }
            float mx = -3.0e38f;
            #pragma unroll
            for (int ct = 0; ct < 4; ++ct)
                #pragma unroll
                for (int r4 = 0; r4 < 4; ++r4) mx = fmaxf(mx, st[ct][r4]);
            mx = fmaxf(mx, __shfl_xor(mx, 16));
            mx = fmaxf(mx, __shfl_xor(mx, 32));
            // defer-max: only rescale when some row's max grew past the slack
            if (!__all(mx <= m_st + 8.f)){
                float mn = fmaxf(m_st, mx);
                float al = exp2f(m_st - mn);
                m_st = mn;
                #pragma unroll
                for (int r4 = 0; r4 < 4; ++r4){
                    float aa = __shfl(al, quad*4 + r4);
                    #pragma unroll
                    for (int dt = 0; dt < 5; ++dt) ov[dt][r4] *= aa;
                }
            }
            #pragma unroll
            for (int ct = 0; ct < 4; ++ct)
                #pragma unroll
                for (int r4 = 0; r4 < 4; ++r4)
                    st[ct][r4] = exp2f(st[ct][r4] - m_st);   // bounded by 2^8
            // P store: q-major rows (q = n16), packed b64, truncating cvt
            #pragma unroll
            for (int ct = 0; ct < 4; ++ct){
                ushort4 h4;
                h4.x = f2u_t(st[ct][0]); h4.y = f2u_t(st[ct][1]);
                h4.z = f2u_t(st[ct][2]); h4.w = f2u_t(st[ct][3]);
                int goff = ct*2 + (quad >> 1);
                *(ushort4*)&Ps[wave][n16*64 + ((goff ^ (n16&7))*8) + (quad&1)*4] = h4;
            }
            // O += P V ; l += P @ 1  (same-wave LDS write->read, program order)
            short8 ap[2];
            #pragma unroll
            for (int ks = 0; ks < 2; ++ks)
                ap[ks] = *(const short8*)&Ps[wave][n16*64 + (((ks*4+quad) ^ (n16&7))*8)];
            #pragma unroll
            for (int dt = 0; dt < 4; ++dt)
                #pragma unroll
                for (int ks = 0; ks < 2; ++ks){
                    short8 bv = *(const short8*)&Vt[cur][(dt*16+n16)*64 + (((ks*4+quad) ^ (n16&7))*8)];
                    ov[dt] = mfma16(ap[ks], bv, ov[dt]);
                }
            #pragma unroll
            for (int ks = 0; ks < 2; ++ks)
                ov[4] = mfma16(ap[ks], ones8, ov[4]);

            if (kt < qt) writeKV(cur ^ 1);     // vmcnt wait here, hidden by compute
            __syncthreads();                   // single barrier per k-tile
        }
        #pragma unroll
        for (int r4 = 0; r4 < 4; ++r4){
            float inv = __builtin_amdgcn_rcpf(ov[4][r4]);   // l in output-row layout
            size_t row = tok0 + wave*16 + quad*4 + r4;
            #pragma unroll
            for (int dt = 0; dt < 4; ++dt)
                O[row*512 + h*64 + dt*16 + n16] = f2u(ov[dt][r4] * inv);
        }
    }
}

// ------------------------------------------------------------------
// x1h = bf16( rmsnorm(x + y_bf16) * scale )  +  fused router softmax.
// Router consumes the BIT-IDENTICAL bf16 values being stored (re-decoded),
// so results match the previous separate router kernel.
__global__ __launch_bounds__(256) void rmsnorm_router_kernel(
    const float* __restrict__ x, const u16* __restrict__ y,
    const float* __restrict__ scale,
    const float* __restrict__ wr, const float* __restrict__ br,
    u16* __restrict__ out, float* __restrict__ rout)
{
    int tok = blockIdx.x, tid = threadIdx.x;
    size_t base = (size_t)tok * 512;
    float v0 = x[base+tid]     + u2f(y[base+tid]);
    float v1 = x[base+tid+256] + u2f(y[base+tid+256]);
    float ss = v0*v0 + v1*v1;
    for (int off = 32; off; off >>= 1) ss += __shfl_down(ss, off);
    __shared__ float ws[4];
    if ((tid & 63) == 0) ws[tid >> 6] = ss;
    __syncthreads();
    float rstd = rsqrtf((ws[0]+ws[1]+ws[2]+ws[3])*(1.f/512.f) + 1e-6f);
    u16 h0 = f2u(scale[tid]     * v0 * rstd);
    u16 h1 = f2u(scale[tid+256] * v1 * rstd);
    out[base+tid]     = h0;
    out[base+tid+256] = h1;
    // router: p[e] = sum_d x1h[d]*wr[d][e] + br[e]
    float xv0 = u2f(h0), xv1 = u2f(h1);
    float4 wr0 = *(const float4*)&wr[(size_t)tid*4];
    float4 wr1 = *(const float4*)&wr[(size_t)(tid+256)*4];
    float p0 = xv0*wr0.x + xv1*wr1.x;
    float p1 = xv0*wr0.y + xv1*wr1.y;
    float p2 = xv0*wr0.z + xv1*wr1.z;
    float p3 = xv0*wr0.w + xv1*wr1.w;
    for (int off = 32; off; off >>= 1){
        p0 += __shfl_down(p0,off); p1 += __shfl_down(p1,off);
        p2 += __shfl_down(p2,off); p3 += __shfl_down(p3,off);
    }
    __shared__ float pr[4][4];
    if ((tid & 63) == 0){
        int w = tid >> 6;
        pr[w][0]=p0; pr[w][1]=p1; pr[w][2]=p2; pr[w][3]=p3;
    }
    __syncthreads();
    if (tid == 0){
        float q0 = pr[0][0]+pr[1][0]+pr[2][0]+pr[3][0] + br[0];
        float q1 = pr[0][1]+pr[1][1]+pr[2][1]+pr[3][1] + br[1];
        float q2 = pr[0][2]+pr[1][2]+pr[2][2]+pr[3][2] + br[2];
        float q3 = pr[0][3]+pr[1][3]+pr[2][3]+pr[3][3] + br[3];
        float mx = fmaxf(fmaxf(q0,q1), fmaxf(q2,q3));
        float e0=__expf(q0-mx), e1=__expf(q1-mx), e2=__expf(q2-mx), e3=__expf(q3-mx);
        float inv = 1.f/(e0+e1+e2+e3);
        rout[tok*4+0]=e0*inv; rout[tok*4+1]=e1*inv;
        rout[tok*4+2]=e2*inv; rout[tok*4+3]=e3*inv;
    }
}

// out_fp32 = rmsnorm(x1h + moe_f32 + ROUT@b2) * scale
__global__ __launch_bounds__(256) void final_kernel(
    const u16* __restrict__ x1, const float* __restrict__ moe,
    const float* __restrict__ rout, const float* __restrict__ b2,
    const float* __restrict__ scale, float* __restrict__ out)
{
    int tok = blockIdx.x, tid = threadIdx.x;
    size_t base = (size_t)tok * 512;
    float r0 = rout[tok*4+0], r1 = rout[tok*4+1], r2 = rout[tok*4+2], r3 = rout[tok*4+3];
    float bb0 = r0*b2[tid]     + r1*b2[512+tid]     + r2*b2[1024+tid]     + r3*b2[1536+tid];
    float bb1 = r0*b2[tid+256] + r1*b2[768+tid]     + r2*b2[1280+tid]     + r3*b2[1792+tid];
    float v0 = u2f(x1[base+tid])     + moe[base+tid]     + bb0;
    float v1 = u2f(x1[base+tid+256]) + moe[base+tid+256] + bb1;
    float ss = v0*v0 + v1*v1;
    for (int off = 32; off; off >>= 1) ss += __shfl_down(ss, off);
    __shared__ float ws[4];
    if ((tid & 63) == 0) ws[tid >> 6] = ss;
    __syncthreads();
    float rstd = rsqrtf((ws[0]+ws[1]+ws[2]+ws[3])*(1.f/512.f) + 1e-6f);
    out[base+tid]     = scale[tid]     * v0 * rstd;
    out[base+tid+256] = scale[tid+256] * v1 * rstd;
}

// ------------------------------------------------------------------
extern "C" void kernel_launch(void* const* d_in, const int* in_sizes, int n_in,
                              void* d_out, int out_size, void* d_ws, size_t ws_size,
                              hipStream_t stream)
{
    const float* x    = (const float*)d_in[0];
    const float* mp_w = (const float*)d_in[3];
    const float* mp_b = (const float*)d_in[4];
    const float* fu_w = (const float*)d_in[5];
    const float* fu_b = (const float*)d_in[6];
    const float* wc   = (const float*)d_in[7];
    const float* wk   = (const float*)d_in[8];
    const float* wv   = (const float*)d_in[9];
    const float* wq   = (const float*)d_in[10];
    const float* wo   = (const float*)d_in[11];
    const float* s1   = (const float*)d_in[12];
    const float* s2   = (const float*)d_in[13];
    const float* wr   = (const float*)d_in[14];
    const float* br   = (const float*)d_in[15];
    const float* wg   = (const float*)d_in[16];
    const float* bg   = (const float*)d_in[17];
    const float* w1   = (const float*)d_in[18];
    const float* b1   = (const float*)d_in[19];
    const float* w2   = (const float*)d_in[20];
    const float* b2   = (const float*)d_in[21];

    char* wsb = (char*)d_ws;
    const size_t MB = 1024*1024;
    // persistent weights (0..12.3 MB)
    u16*   WqkvC  = (u16*)(wsb + 0);                 // [1536,1024]
    u16*   woT    = (u16*)(wsb + 3*MB);              // [512,512]
    u16*   wgT    = (u16*)(wsb + 3*MB + 512*1024);   // [512,512]
    u16*   w1T    = (u16*)(wsb + 4*MB);              // [4096,512]
    u16*   w2Ts   = (u16*)(wsb + 8*MB);              // [512,4096]
    float* fubias = (float*)(wsb + 12*MB);           // 512
    float* qkvbias= (float*)(wsb + 12*MB + 8192);    // 1536
    float* ROUT   = (float*)(wsb + 12*MB + 32768);   // 8192x4 (128 KB)
    // prepass scratch (dead before gatepool)
    u16*   wqkvT  = (u16*)(wsb + 12*MB + 512*1024);  // [1536,512] 12.5-14
    u16*   fuBT   = (u16*)(wsb + 16*MB);             // [512,512]
    u16*   mp_wB  = (u16*)(wsb + 16*MB + 512*1024);  // [512,512]
    u16*   WfuBF  = (u16*)(wsb + 17*MB);             // [1024,512]
    // rotating big buffers
    u16*   x1h   = (u16*)(wsb + 14*MB);              // 14-22, live till final
    u16*   XFcat = (u16*)(wsb + 16*MB);              // 16-32, dead after QKV
    u16*   XG    = (u16*)(wsb + 22*MB);              // 22-30, live through w1
    u16*   S3    = (u16*)(wsb + 24*MB);              // 24-32, dead after rmsnorm
    u16*   QKb   = (u16*)(wsb + 32*MB);              // 32-48, dead after flash
    float* MOE   = (float*)(wsb + 32*MB);            // 32-48 fp32 (MoE phase)
    u16*   VbT   = (u16*)(wsb + 48*MB);              // 48-56, dead after flash
    u16*   ATT   = (u16*)(wsb + 56*MB);              // 56-64, dead after wo
    u16*   Hb    = (u16*)(wsb + 48*MB);              // 48-112 contiguous [8192,4096] (MoE, big)
    u16*   HbA   = (u16*)(wsb + 48*MB);              // fallback path
    bool big = ws_size >= (size_t)112*MB;

    auto mg128 = [&](const u16* A, const u16* A2, int lda, const u16* Bt, int ldb,
                     const float* bias, const float* rs, const u16* glu,
                     void* C, void* CB, int ldc, u16* C2, int M, int N, int K, int flags){
        dim3 g(N/128, M/128);
        mgemm_kernel<128><<<g, 256, 0, stream>>>(A, A2, lda, Bt, ldb, bias, rs, glu,
                                                 C, CB, ldc, C2, K, flags);
    };
    auto mg64 = [&](const u16* A, const u16* A2, int lda, const u16* Bt, int ldb,
                    const float* bias, const float* rs, const u16* glu,
                    void* C, void* CB, int ldc, u16* C2, int M, int N, int K, int flags){
        dim3 g(N/128, M/64);
        mgemm_kernel<64><<<g, 256, 0, stream>>>(A, A2, lda, Bt, ldb, bias, rs, glu,
                                                C, CB, ldc, C2, K, flags);
    };

    // ---- prepass (re-run every call)
    TJobs JJ; JJ.n = 14;
    auto setj = [&](int i, const float* src, u16* dst, int K, int N, int ldout,
                    int coloff, float scale, int trans){
        JJ.j[i] = TJob{src, dst, K, N, ldout, coloff, (K/32)*(N/32), scale, trans};
    };
    setj(0, wq,            wqkvT, 512,  512,  512, 0, QSCALE, 1);  // Q' = wq*0.125*log2e
    setj(1, wo,            woT,   512,  512,  512, 0, 1.f, 1);
    setj(2, wg,            wgT,   512,  512,  512, 0, 1.f, 1);
    setj(3, fu_w + 512*512,fuBT,  512,  512,  512, 0, 1.f, 1);     // fuB^T
    for (int e = 0; e < 4; ++e){
        setj(4+e, w1 + (size_t)e*512*1024, w1T + (size_t)e*1024*512, 512, 1024, 512, 0, 1.f, 1);
        setj(8+e, w2 + (size_t)e*1024*512, w2Ts + (size_t)e*1024, 1024, 512, 4096, 0, 1.f, 1);
    }
    setj(12, mp_w, mp_wB, 512, 512, 512, 0, 1.f, 0);               // plain converts
    setj(13, fu_w, WfuBF, 512, 512, 512, 0, 1.f, 0);               // fuA rows 0..511
    int nt = 4*256 + 8*512 + 2*256;
    tconv_all_kernel<<<nt, 256, 0, stream>>>(JJ);
    sgemm2_kernel<<<dim3(8,8,2), 256, 0, stream>>>(
        wc, wk, wv, wqkvT + 512*512, wqkvT + 1024*512, 32);        // Wck^T, Wcv^T
    biasfold_kernel<<<512, 256, 0, stream>>>(fu_b, mp_b, fu_w, fubias);
    qkvbias_kernel<<<1536, 256, 0, stream>>>(fubias, wqkvT, qkvbias);
    // F1 = mp_w @ fuB -> WfuBF rows 512..1023 (row-major bf16).  16 blocks.
    g128_kernel<0><<<dim3(4, 4), 256, 0, stream>>>(
        mp_wB, 512, fuBT, 512, nullptr, nullptr, WfuBF + 512*512, 512, nullptr, 512);
    // Combined: WqkvC[1536,1024] = wqkvT[1536,512] @ WfuBF[1024,512]^T.  96 blocks.
    g128_kernel<0><<<dim3(8, 12), 256, 0, stream>>>(
        wqkvT, 512, WfuBF, 512, nullptr, nullptr, WqkvC, 1024, nullptr, 512);

    // ---- main pipeline
    gatepool_kernel<<<(TOK/16)*512/256, 256, 0, stream>>>(x, XFcat);
    // QKV from XFcat (xfu folded): Q'|K -> QKb, V^T -> VbT.  768 blocks, 2/CU.
    g128_kernel<1><<<dim3(12, 64), 256, 0, stream>>>(
        XFcat, 1024, WqkvC, 1024, qkvbias, nullptr, QKb, 1024, VbT, 1024);
    flash_kernel<<<512, 256, 0, stream>>>(QKb, VbT, ATT);
    // attn@wo: 64x128 pipelined, 512 blocks, 3/CU (all co-resident)
    gemm64p_kernel<0><<<dim3(4, 128), 256, 0, stream>>>(
        ATT, 512, woT, 512, nullptr, nullptr, S3, 512, 512);
    // x1 + fused router
    rmsnorm_router_kernel<<<TOK, 256, 0, stream>>>(x, S3, s1, wr, br, x1h, ROUT);
    // xg = x1h * sigmoid(x1h@wg+bg): 64x128 pipelined
    gemm64p_kernel<1><<<dim3(4, 128), 256, 0, stream>>>(
        x1h, 512, wgT, 512, bg, x1h, XG, 512, 512);
    if (big){
        // w1: 256^2 single-barrier pipelined, M=8192, N=4096, K=512.  512 blocks.
        gemm256_kernel<<<dim3(16, 32), 512, 0, stream>>>(
            XG, 512, w1T, 512, b1, ROUT, Hb, 4096, 512);
        // w2: 64x128 pipelined, M=8192, N=512, K=4096.  512 blocks, 3/CU.
        gemm64p_kernel<2><<<dim3(4, 128), 256, 0, stream>>>(
            Hb, 4096, w2Ts, 4096, nullptr, nullptr, MOE, 512, 4096);
    } else {
        // fallback (r6 structure): pairwise experts, Hb = HbA [8192,2048]
        for (int p = 0; p < 2; ++p){
            mg128(XG, XG + (size_t)MSPLIT*512, 512, w1T + (size_t)p*2048*512, 512,
                  b1 + p*2048, ROUT + p*2, 0,
                  HbA, HbA + (size_t)MSPLIT*2048, 2048, 0,
                  TOK, 2048, 512, GF_GELU | GF_RSCOL);
            mg64 (HbA, HbA + (size_t)MSPLIT*2048, 2048, w2Ts + p*2048, 4096, 0, 0, 0,
                  MOE, (float*)MOE + (size_t)MSPLIT*512, 512, 0,
                  TOK, 512, 2048, p ? GF_ACCUM : GF_F32OUT);
        }
    }
    final_kernel<<<TOK, 256, 0, stream>>>(x1h, MOE, ROUT, b2, s2, (float*)d_out);
}